// Round 1
// baseline (3155.580 us; speedup 1.0000x reference)
//
#include <hip/hip_runtime.h>
#include <hip/hip_bf16.h>
#include <math.h>

#define Bn 2
#define Ln 4096
#define Dn 1024
#define Hn 4
#define DKn 256
#define DVn 256
#define NCHn 128  // L/32 chunks

__device__ __forceinline__ float sigmoidf_(float x) { return 1.f / (1.f + __expf(-x)); }

// ---------------------------------------------------------------------------
// Generic fp32 GEMM: C[M,N] = A[M,K] @ B[K,N], M%64==0, N%64==0, K%16==0
// ---------------------------------------------------------------------------
__global__ __launch_bounds__(256) void gemm_f32(const float* __restrict__ A,
                                                const float* __restrict__ Bm,
                                                float* __restrict__ C,
                                                int M, int N, int K) {
  __shared__ __align__(16) float As[16][64];
  __shared__ __align__(16) float Bs[16][64];
  const int tid = threadIdx.x;
  const int row0 = blockIdx.y * 64;
  const int col0 = blockIdx.x * 64;
  const int tx = tid & 15, ty = tid >> 4;
  float acc[4][4] = {{0.f, 0.f, 0.f, 0.f}, {0.f, 0.f, 0.f, 0.f},
                     {0.f, 0.f, 0.f, 0.f}, {0.f, 0.f, 0.f, 0.f}};
  for (int k0 = 0; k0 < K; k0 += 16) {
    {
      const int m = tid >> 2;
      const int k4 = (tid & 3) << 2;
      const float4 a = *(const float4*)&A[(size_t)(row0 + m) * K + k0 + k4];
      As[k4 + 0][m] = a.x; As[k4 + 1][m] = a.y;
      As[k4 + 2][m] = a.z; As[k4 + 3][m] = a.w;
      const int kk = tid >> 4;
      const int n4 = (tid & 15) << 2;
      *(float4*)&Bs[kk][n4] = *(const float4*)&Bm[(size_t)(k0 + kk) * N + col0 + n4];
    }
    __syncthreads();
#pragma unroll
    for (int kk = 0; kk < 16; ++kk) {
      const float4 ar = *(const float4*)&As[kk][ty << 2];
      const float4 br = *(const float4*)&Bs[kk][tx << 2];
      const float a_[4] = {ar.x, ar.y, ar.z, ar.w};
      const float b_[4] = {br.x, br.y, br.z, br.w};
#pragma unroll
      for (int i = 0; i < 4; ++i)
#pragma unroll
        for (int j = 0; j < 4; ++j) acc[i][j] = fmaf(a_[i], b_[j], acc[i][j]);
    }
    __syncthreads();
  }
#pragma unroll
  for (int i = 0; i < 4; ++i) {
    const float4 o = make_float4(acc[i][0], acc[i][1], acc[i][2], acc[i][3]);
    *(float4*)&C[(size_t)(row0 + (ty << 2) + i) * N + col0 + (tx << 2)] = o;
  }
}

// ---------------------------------------------------------------------------
// Gate projections: beta = sigmoid(x@Wb), wg = sigmoid(x@Wg+bg),
// p = softmax((x@Wl+bl)/exp(log_temp)). One wave per row (4 rows/block).
// beta written [B,H,L]; wg [B*L,4]; p [B*L,12].
// ---------------------------------------------------------------------------
__global__ __launch_bounds__(256) void gates_kernel(
    const float* __restrict__ x, const float* __restrict__ Wb,
    const float* __restrict__ Wg, const float* __restrict__ bg,
    const float* __restrict__ Wl, const float* __restrict__ bl,
    const float* __restrict__ log_temp, float* __restrict__ beta,
    float* __restrict__ wgl, float* __restrict__ pmix) {
  const int wave = threadIdx.x >> 6, lane = threadIdx.x & 63;
  const int row = (blockIdx.x << 2) + wave;
  if (row >= Bn * Ln) return;
  const float* xr = x + (size_t)row * Dn;
  float acc[20];
#pragma unroll
  for (int c = 0; c < 20; ++c) acc[c] = 0.f;
#pragma unroll
  for (int i = 0; i < 4; ++i) {
    const float4 xv = *(const float4*)&xr[(lane << 2) + (i << 8)];
    const float xa[4] = {xv.x, xv.y, xv.z, xv.w};
#pragma unroll
    for (int j = 0; j < 4; ++j) {
      const int kk = (i << 8) + (lane << 2) + j;
      const float xx = xa[j];
#pragma unroll
      for (int h = 0; h < 4; ++h) acc[h] = fmaf(xx, Wb[kk * 4 + h], acc[h]);
#pragma unroll
      for (int h = 0; h < 4; ++h) acc[4 + h] = fmaf(xx, Wg[kk * 4 + h], acc[4 + h]);
#pragma unroll
      for (int c = 0; c < 12; ++c) acc[8 + c] = fmaf(xx, Wl[kk * 12 + c], acc[8 + c]);
    }
  }
#pragma unroll
  for (int c = 0; c < 20; ++c)
    for (int off = 32; off; off >>= 1) acc[c] += __shfl_down(acc[c], off);
  if (lane == 0) {
    const int b = row >> 12, l = row & (Ln - 1);
#pragma unroll
    for (int h = 0; h < 4; ++h)
      beta[((size_t)(b * Hn + h) << 12) + l] = sigmoidf_(acc[h]);
#pragma unroll
    for (int h = 0; h < 4; ++h) wgl[row * 4 + h] = sigmoidf_(acc[4 + h] + bg[h]);
#pragma unroll
    for (int h = 0; h < 4; ++h) {
      const float it = 1.f / __expf(log_temp[h]);
      const float l0 = (acc[8 + h * 3 + 0] + bl[h * 3 + 0]) * it;
      const float l1 = (acc[8 + h * 3 + 1] + bl[h * 3 + 1]) * it;
      const float l2 = (acc[8 + h * 3 + 2] + bl[h * 3 + 2]) * it;
      const float mx = fmaxf(l0, fmaxf(l1, l2));
      const float e0 = __expf(l0 - mx), e1 = __expf(l1 - mx), e2 = __expf(l2 - mx);
      const float is = 1.f / (e0 + e1 + e2);
      pmix[row * 12 + h * 3 + 0] = e0 * is;
      pmix[row * 12 + h * 3 + 1] = e1 * is;
      pmix[row * 12 + h * 3 + 2] = e2 * is;
    }
  }
}

// ---------------------------------------------------------------------------
// Causal depthwise conv (K=4) + SiLU (+ optional per-head l2norm).
// raw [B*L,1024] -> out [B,H,L,256]. One block per (b,l).
// ---------------------------------------------------------------------------
template <int DO_L2>
__global__ __launch_bounds__(256) void conv_act_kernel(
    const float* __restrict__ raw, const float* __restrict__ cw,
    float* __restrict__ out) {
  const int blk = blockIdx.x;
  const int b = blk >> 12, l = blk & (Ln - 1);
  const int t = threadIdx.x;
  float vals[4];
#pragma unroll
  for (int g = 0; g < 4; ++g) {
    const int c = (g << 8) + t;
    float a = 0.f;
#pragma unroll
    for (int j = 0; j < 4; ++j) {
      const int ls = l - 3 + j;
      if (ls >= 0) a = fmaf(cw[c * 4 + j], raw[(((size_t)b << 12) + ls) * 1024 + c], a);
    }
    vals[g] = a * sigmoidf_(a);
  }
  if (DO_L2) {
    __shared__ float red[4][4];
    float ss[4];
#pragma unroll
    for (int g = 0; g < 4; ++g) ss[g] = vals[g] * vals[g];
#pragma unroll
    for (int g = 0; g < 4; ++g)
      for (int off = 32; off; off >>= 1) ss[g] += __shfl_down(ss[g], off);
    const int wave = t >> 6, lane = t & 63;
    if (lane == 0) {
#pragma unroll
      for (int g = 0; g < 4; ++g) red[wave][g] = ss[g];
    }
    __syncthreads();
#pragma unroll
    for (int g = 0; g < 4; ++g) {
      const float s = red[0][g] + red[1][g] + red[2][g] + red[3][g];
      vals[g] *= rsqrtf(s + 1e-6f);
    }
  }
#pragma unroll
  for (int g = 0; g < 4; ++g)
    out[((((size_t)(b * Hn + g)) << 12) + l) * 256 + t] = vals[g];
}

// ---------------------------------------------------------------------------
// Per-chunk precompute: A, T=(I+tril(A,-1))^-1, u0=T@(v*beta), w=(T.beta)@k,
// masked attn. One block per (bh, chunk): grid 8*128.
// ---------------------------------------------------------------------------
__global__ __launch_bounds__(256) void precomp_kernel(
    const float* __restrict__ q, const float* __restrict__ k,
    const float* __restrict__ v, const float* __restrict__ beta,
    float* __restrict__ w_out, float* __restrict__ u0_out,
    float* __restrict__ attn_out) {
  const int blk = blockIdx.x;
  const int n = blk & 127, bh = blk >> 7;
  const size_t base = (((size_t)bh << 12) + (n << 5)) * 256;
  __shared__ __align__(16) float qs[32][260];
  __shared__ __align__(16) float ks[32][260];
  __shared__ __align__(16) float vb[32][260];
  __shared__ float Am[32][33], Tm[32][33], bet[32];
  const int t = threadIdx.x;
  if (t < 32) bet[t] = beta[((size_t)bh << 12) + (n << 5) + t];
  __syncthreads();
  for (int idx = t; idx < 32 * 64; idx += 256) {
    const int r = idx >> 6, fi = (idx & 63) << 2;
    *(float4*)&qs[r][fi] = *(const float4*)&q[base + r * 256 + fi];
    *(float4*)&ks[r][fi] = *(const float4*)&k[base + r * 256 + fi];
    float4 vv = *(const float4*)&v[base + r * 256 + fi];
    const float bm = bet[r];
    vv.x *= bm; vv.y *= bm; vv.z *= bm; vv.w *= bm;
    *(float4*)&vb[r][fi] = vv;
  }
  __syncthreads();
  {
    const int i = t >> 3, j0 = t & 7;
    float dq[4] = {0.f, 0.f, 0.f, 0.f}, dk2[4] = {0.f, 0.f, 0.f, 0.f};
    for (int d = 0; d < 256; d += 4) {
      const float4 qi = *(const float4*)&qs[i][d];
      const float4 ki = *(const float4*)&ks[i][d];
#pragma unroll
      for (int jj = 0; jj < 4; ++jj) {
        const float4 kj = *(const float4*)&ks[j0 + (jj << 3)][d];
        dq[jj] = fmaf(qi.x, kj.x, dq[jj]);
        dq[jj] = fmaf(qi.y, kj.y, dq[jj]);
        dq[jj] = fmaf(qi.z, kj.z, dq[jj]);
        dq[jj] = fmaf(qi.w, kj.w, dq[jj]);
        dk2[jj] = fmaf(ki.x, kj.x, dk2[jj]);
        dk2[jj] = fmaf(ki.y, kj.y, dk2[jj]);
        dk2[jj] = fmaf(ki.z, kj.z, dk2[jj]);
        dk2[jj] = fmaf(ki.w, kj.w, dk2[jj]);
      }
    }
    const float bi = bet[i];
#pragma unroll
    for (int jj = 0; jj < 4; ++jj) {
      const int j = j0 + (jj << 3);
      Am[i][j] = bi * dk2[jj];
      attn_out[((size_t)blk << 10) + (i << 5) + j] = (j <= i) ? dq[jj] : 0.f;
    }
  }
  for (int idx = t; idx < 1024; idx += 256)
    Tm[idx >> 5][idx & 31] = ((idx >> 5) == (idx & 31)) ? 1.f : 0.f;
  __syncthreads();
  // forward substitution: T[i,:] = e_i - sum_{m<i} A[i,m] T[m,:]
  for (int i = 1; i < 32; ++i) {
    if (t < 32) {
      float s = 0.f;
      for (int m = 0; m < i; ++m) s = fmaf(Am[i][m], Tm[m][t], s);
      Tm[i][t] = ((i == t) ? 1.f : 0.f) - s;
    }
    __syncthreads();
  }
  {
    const int i = t >> 3;
    const int dj = (t & 7) << 2;
    float4 ua[8], wa[8];
#pragma unroll
    for (int s = 0; s < 8; ++s) {
      ua[s] = make_float4(0.f, 0.f, 0.f, 0.f);
      wa[s] = make_float4(0.f, 0.f, 0.f, 0.f);
    }
    for (int m = 0; m < 32; ++m) {
      const float tim = Tm[i][m];
      const float t2m = tim * bet[m];
#pragma unroll
      for (int s = 0; s < 8; ++s) {
        const int d = dj + (s << 5);
        const float4 vv = *(const float4*)&vb[m][d];
        const float4 kk = *(const float4*)&ks[m][d];
        ua[s].x = fmaf(tim, vv.x, ua[s].x);
        ua[s].y = fmaf(tim, vv.y, ua[s].y);
        ua[s].z = fmaf(tim, vv.z, ua[s].z);
        ua[s].w = fmaf(tim, vv.w, ua[s].w);
        wa[s].x = fmaf(t2m, kk.x, wa[s].x);
        wa[s].y = fmaf(t2m, kk.y, wa[s].y);
        wa[s].z = fmaf(t2m, kk.z, wa[s].z);
        wa[s].w = fmaf(t2m, kk.w, wa[s].w);
      }
    }
#pragma unroll
    for (int s = 0; s < 8; ++s) {
      const int d = dj + (s << 5);
      *(float4*)&u0_out[base + i * 256 + d] = ua[s];
      *(float4*)&w_out[base + i * 256 + d] = wa[s];
    }
  }
}

// ---------------------------------------------------------------------------
// Sequential chunk scan, parallel over dv-slices of 8.
// grid = 8 bh * 32 slices = 256 blocks, 256 threads.
// ---------------------------------------------------------------------------
__global__ __launch_bounds__(256) void scan_kernel(
    const float* __restrict__ q, const float* __restrict__ k,
    const float* __restrict__ w, const float* __restrict__ u0,
    const float* __restrict__ attn, float* __restrict__ dout) {
  const int bh = blockIdx.x >> 5;
  const int j0 = (blockIdx.x & 31) << 3;
  __shared__ __align__(16) float ws_[32][260];
  __shared__ __align__(16) float qs_[32][260];
  __shared__ __align__(16) float ks_[32][260];
  __shared__ __align__(16) float Sm[8][260];
  __shared__ __align__(16) float um[32][8];
  __shared__ __align__(16) float u0m[32][8];
  __shared__ float am[32][32];
  const int t = threadIdx.x;
  for (int idx = t; idx < 8 * 260; idx += 256) ((float*)Sm)[idx] = 0.f;
  const size_t bhb = ((size_t)bh << 12) * 256;
  const int c = t >> 3, jj = t & 7;
  const int jj2 = t >> 5, dkr = (t & 31) << 3;
  __syncthreads();
  for (int n = 0; n < NCHn; ++n) {
    const size_t cb = bhb + ((size_t)n << 5) * 256;
    for (int idx = t; idx < 32 * 64; idx += 256) {
      const int r = idx >> 6, fi = (idx & 63) << 2;
      *(float4*)&ws_[r][fi] = *(const float4*)&w[cb + r * 256 + fi];
      *(float4*)&qs_[r][fi] = *(const float4*)&q[cb + r * 256 + fi];
      *(float4*)&ks_[r][fi] = *(const float4*)&k[cb + r * 256 + fi];
    }
    if (t < 32) {
      *(float4*)&u0m[t][0] = *(const float4*)&u0[cb + t * 256 + j0];
      *(float4*)&u0m[t][4] = *(const float4*)&u0[cb + t * 256 + j0 + 4];
    }
    for (int idx = t; idx < 1024; idx += 256)
      ((float*)am)[idx] = attn[((size_t)(bh * NCHn + n) << 10) + idx];
    __syncthreads();
    // u_i = u0_i - w_i @ S   (S stored [dv][dk])
    float d0 = 0.f, d1 = 0.f, d2 = 0.f, d3 = 0.f;
    for (int d = 0; d < 256; d += 4) {
      const float4 wv = *(const float4*)&ws_[c][d];
      const float4 sv = *(const float4*)&Sm[jj][d];
      d0 = fmaf(wv.x, sv.x, d0);
      d1 = fmaf(wv.y, sv.y, d1);
      d2 = fmaf(wv.z, sv.z, d2);
      d3 = fmaf(wv.w, sv.w, d3);
    }
    um[c][jj] = u0m[c][jj] - ((d0 + d1) + (d2 + d3));
    __syncthreads();
    // o_i = q_i @ S + attn @ u_i
    float o0 = 0.f, o1 = 0.f, o2 = 0.f, o3 = 0.f;
    for (int d = 0; d < 256; d += 4) {
      const float4 qv = *(const float4*)&qs_[c][d];
      const float4 sv = *(const float4*)&Sm[jj][d];
      o0 = fmaf(qv.x, sv.x, o0);
      o1 = fmaf(qv.y, sv.y, o1);
      o2 = fmaf(qv.z, sv.z, o2);
      o3 = fmaf(qv.w, sv.w, o3);
    }
    float o = (o0 + o1) + (o2 + o3);
    float oa = 0.f, ob = 0.f;
#pragma unroll
    for (int m = 0; m < 32; m += 2) {
      oa = fmaf(am[c][m], um[m][jj], oa);
      ob = fmaf(am[c][m + 1], um[m + 1][jj], ob);
    }
    o += oa + ob;
    dout[cb + c * 256 + j0 + jj] = o;
    __syncthreads();
    // S += k_i^T @ u_i
    float4 s0 = *(const float4*)&Sm[jj2][dkr];
    float4 s1 = *(const float4*)&Sm[jj2][dkr + 4];
    for (int m = 0; m < 32; ++m) {
      const float uu = um[m][jj2];
      const float4 k0 = *(const float4*)&ks_[m][dkr];
      const float4 k1 = *(const float4*)&ks_[m][dkr + 4];
      s0.x = fmaf(uu, k0.x, s0.x);
      s0.y = fmaf(uu, k0.y, s0.y);
      s0.z = fmaf(uu, k0.z, s0.z);
      s0.w = fmaf(uu, k0.w, s0.w);
      s1.x = fmaf(uu, k1.x, s1.x);
      s1.y = fmaf(uu, k1.y, s1.y);
      s1.z = fmaf(uu, k1.z, s1.z);
      s1.w = fmaf(uu, k1.w, s1.w);
    }
    *(float4*)&Sm[jj2][dkr] = s0;
    *(float4*)&Sm[jj2][dkr + 4] = s1;
    __syncthreads();
  }
}

// ---------------------------------------------------------------------------
// FIR(3/31) local paths + hierarchical gating + per-head RMSNorm.
// One block per (b,l). out [B*L, 1024] ready for final GEMM.
// ---------------------------------------------------------------------------
__global__ __launch_bounds__(256) void mix_kernel(
    const float* __restrict__ v, const float* __restrict__ delta,
    const float* __restrict__ wgl, const float* __restrict__ pmix,
    const float* __restrict__ firs, const float* __restrict__ firl,
    const float* __restrict__ rms_w, float* __restrict__ out) {
  const int blk = blockIdx.x;
  const int b = blk >> 12, l = blk & (Ln - 1);
  const int t = threadIdx.x;
  float ov[4], ss[4];
#pragma unroll
  for (int g = 0; g < 4; ++g) {
    const size_t colbase = ((((size_t)(b * Hn + g)) << 12)) * 256 + t;
    const float vcur = v[colbase + (size_t)l * 256];
    float sh = 0.f;
#pragma unroll
    for (int j = 0; j < 3; ++j) {
      const int ls = l - 2 + j;
      if (ls >= 0) sh = fmaf(firs[((g << 8) + t) * 3 + j], v[colbase + (size_t)ls * 256], sh);
    }
    float lo = 0.f;
#pragma unroll
    for (int j = 0; j < 31; ++j) {
      const int ls = l - 30 + j;
      if (ls >= 0) lo = fmaf(firl[((g << 8) + t) * 31 + j], v[colbase + (size_t)ls * 256], lo);
    }
    const float p0 = pmix[blk * 12 + g * 3 + 0];
    const float p1 = pmix[blk * 12 + g * 3 + 1];
    const float p2 = pmix[blk * 12 + g * 3 + 2];
    const float wg = wgl[blk * 4 + g];
    const float mixv = p0 * vcur + p1 * sh + p2 * lo;
    const float o = wg * delta[colbase + (size_t)l * 256] + (1.f - wg) * mixv;
    ov[g] = o;
    ss[g] = o * o;
  }
  __shared__ float red[4][4];
#pragma unroll
  for (int g = 0; g < 4; ++g)
    for (int off = 32; off; off >>= 1) ss[g] += __shfl_down(ss[g], off);
  const int wave = t >> 6, lane = t & 63;
  if (lane == 0) {
#pragma unroll
    for (int g = 0; g < 4; ++g) red[wave][g] = ss[g];
  }
  __syncthreads();
#pragma unroll
  for (int g = 0; g < 4; ++g) {
    const float msq = (red[0][g] + red[1][g] + red[2][g] + red[3][g]) * (1.f / 256.f);
    out[(size_t)blk * 1024 + (g << 8) + t] = ov[g] * rsqrtf(msq + 1e-5f) * rms_w[t];
  }
}

// ---------------------------------------------------------------------------
extern "C" void kernel_launch(void* const* d_in, const int* in_sizes, int n_in,
                              void* d_out, int out_size, void* d_ws, size_t ws_size,
                              hipStream_t stream) {
  const float* x = (const float*)d_in[0];
  const float* Wq = (const float*)d_in[1];
  const float* Wk = (const float*)d_in[2];
  const float* Wv = (const float*)d_in[3];
  const float* cq = (const float*)d_in[4];
  const float* ck = (const float*)d_in[5];
  const float* cv = (const float*)d_in[6];
  const float* Wb = (const float*)d_in[7];
  const float* firs = (const float*)d_in[8];
  const float* firl = (const float*)d_in[9];
  const float* Wg = (const float*)d_in[10];
  const float* bg = (const float*)d_in[11];
  const float* Wl = (const float*)d_in[12];
  const float* bl = (const float*)d_in[13];
  const float* ltemp = (const float*)d_in[14];
  const float* rmsw = (const float*)d_in[15];
  const float* Wo = (const float*)d_in[16];

  float* ws = (float*)d_ws;
  const size_t NE = (size_t)Bn * Ln * 1024;  // 8.39M floats per [B,L,1024] buffer
  float* qraw = ws;
  float* kraw = ws + NE;
  float* vraw = ws + 2 * NE;
  float* qn = ws + 3 * NE;
  float* kn = ws + 4 * NE;
  float* vn = ws + 5 * NE;
  float* beta = ws + 6 * NE;
  float* wgl = beta + (size_t)Bn * Hn * Ln;
  float* pmix = wgl + (size_t)Bn * Ln * Hn;
  float* attn = pmix + (size_t)Bn * Ln * Hn * 3;
  // reuse raw buffers once convs are done:
  float* wbuf = qraw;
  float* u0buf = kraw;
  float* dbuf = vraw;
  float* normed = qn;  // reuse q after scan

  const dim3 gg(16, 128);  // N/64, M/64
  gemm_f32<<<gg, 256, 0, stream>>>(x, Wq, qraw, Bn * Ln, 1024, 1024);
  gemm_f32<<<gg, 256, 0, stream>>>(x, Wk, kraw, Bn * Ln, 1024, 1024);
  gemm_f32<<<gg, 256, 0, stream>>>(x, Wv, vraw, Bn * Ln, 1024, 1024);
  gates_kernel<<<Bn * Ln / 4, 256, 0, stream>>>(x, Wb, Wg, bg, Wl, bl, ltemp,
                                                beta, wgl, pmix);
  conv_act_kernel<1><<<Bn * Ln, 256, 0, stream>>>(qraw, cq, qn);
  conv_act_kernel<1><<<Bn * Ln, 256, 0, stream>>>(kraw, ck, kn);
  conv_act_kernel<0><<<Bn * Ln, 256, 0, stream>>>(vraw, cv, vn);
  precomp_kernel<<<Bn * Hn * NCHn, 256, 0, stream>>>(qn, kn, vn, beta, wbuf,
                                                     u0buf, attn);
  scan_kernel<<<Bn * Hn * 32, 256, 0, stream>>>(qn, kn, wbuf, u0buf, attn, dbuf);
  mix_kernel<<<Bn * Ln, 256, 0, stream>>>(vn, dbuf, wgl, pmix, firs, firl,
                                          rmsw, normed);
  gemm_f32<<<gg, 256, 0, stream>>>(normed, Wo, (float*)d_out, Bn * Ln, 1024, 1024);
}

// Round 2
// 2139.073 us; speedup vs baseline: 1.4752x; 1.4752x over previous
//
#include <hip/hip_runtime.h>
#include <hip/hip_bf16.h>
#include <math.h>

#define Bn 2
#define Ln 4096
#define Dn 1024
#define Hn 4
#define DKn 256
#define DVn 256
#define NCHn 128  // L/32 chunks

typedef __attribute__((ext_vector_type(8))) short short8;
typedef __attribute__((ext_vector_type(4))) float f32x4;

__device__ __forceinline__ float sigmoidf_(float x) { return 1.f / (1.f + __expf(-x)); }

__device__ __forceinline__ unsigned short f2bf(float f) {
  union { float f; unsigned u; } v; v.f = f;
  unsigned r = v.u + 0x7FFFu + ((v.u >> 16) & 1u);
  return (unsigned short)(r >> 16);
}

__device__ __forceinline__ void gl2lds16(const void* g, void* l) {
  __builtin_amdgcn_global_load_lds((const __attribute__((address_space(1))) unsigned int*)g,
                                   (__attribute__((address_space(3))) unsigned int*)l, 16, 0, 0);
}

// ---------------------------------------------------------------------------
// Weight transpose + bf16 convert: Wt[n][k] = bf16(W[k][n]), K=N=1024.
// ---------------------------------------------------------------------------
__global__ __launch_bounds__(256) void wt_kernel(const float* __restrict__ W,
                                                 unsigned short* __restrict__ Wt,
                                                 int K, int N) {
  __shared__ float tile[32][33];
  const int bx = blockIdx.x * 32;  // n
  const int by = blockIdx.y * 32;  // k
  const int tx = threadIdx.x & 31, ty4 = (threadIdx.x >> 5) * 4;
#pragma unroll
  for (int r = 0; r < 4; ++r)
    tile[ty4 + r][tx] = W[(size_t)(by + ty4 + r) * N + bx + tx];
  __syncthreads();
#pragma unroll
  for (int r = 0; r < 4; ++r)
    Wt[(size_t)(bx + ty4 + r) * K + by + tx] = f2bf(tile[tx][ty4 + r]);
}

// ---------------------------------------------------------------------------
// fp32 -> bf16 elementwise, n % 1024 == 0
// ---------------------------------------------------------------------------
__global__ __launch_bounds__(256) void f2bf_kernel(const float* __restrict__ in,
                                                   unsigned short* __restrict__ out,
                                                   int n) {
  const int i4 = (blockIdx.x * 256 + threadIdx.x) * 4;
  if (i4 >= n) return;
  const float4 v = *(const float4*)&in[i4];
  ushort4 o;
  o.x = f2bf(v.x); o.y = f2bf(v.y); o.z = f2bf(v.z); o.w = f2bf(v.w);
  *(ushort4*)&out[i4] = o;
}

// ---------------------------------------------------------------------------
// bf16 MFMA GEMM: C[M,N] f32 = A[M,K]bf16 @ Bt[N,K]bf16^T. 128x128 tile, BK=32.
// 256 thr = 4 waves; wave (wr,wc) in 2x2, each 64x64 via 4x4 frags of 16x16x32.
// ---------------------------------------------------------------------------
__global__ __launch_bounds__(256, 2) void gemm_bf16(const unsigned short* __restrict__ A,
                                                    const unsigned short* __restrict__ Bt,
                                                    float* __restrict__ C,
                                                    int M, int N, int K) {
  __shared__ __align__(16) unsigned short As[128 * 32];
  __shared__ __align__(16) unsigned short Bs[128 * 32];
  const int tid = threadIdx.x;
  const int wid = tid >> 6, lane = tid & 63;
  const int row0 = blockIdx.y * 128, col0 = blockIdx.x * 128;
  const int wr64 = (wid >> 1) * 64, wc64 = (wid & 1) * 64;
  const int fr = lane & 15, fg = lane >> 4;
  f32x4 acc[4][4];
#pragma unroll
  for (int i = 0; i < 4; ++i)
#pragma unroll
    for (int j = 0; j < 4; ++j) acc[i][j] = (f32x4){0.f, 0.f, 0.f, 0.f};
  for (int k0 = 0; k0 < K; k0 += 32) {
#pragma unroll
    for (int i = 0; i < 2; ++i) {
      const int off = wid * 2048 + i * 1024 + (lane << 4);  // LDS byte offset
      const int r = off >> 6;                               // tile row
      const int kb = off & 63;                              // byte within row
      gl2lds16((const char*)A + ((size_t)(row0 + r) * K + k0) * 2 + kb, (char*)As + off);
      gl2lds16((const char*)Bt + ((size_t)(col0 + r) * K + k0) * 2 + kb, (char*)Bs + off);
    }
    __syncthreads();
    short8 a[4], b[4];
#pragma unroll
    for (int mi = 0; mi < 4; ++mi)
      a[mi] = *(const short8*)&As[(wr64 + mi * 16 + fr) * 32 + fg * 8];
#pragma unroll
    for (int ni = 0; ni < 4; ++ni)
      b[ni] = *(const short8*)&Bs[(wc64 + ni * 16 + fr) * 32 + fg * 8];
#pragma unroll
    for (int mi = 0; mi < 4; ++mi)
#pragma unroll
      for (int ni = 0; ni < 4; ++ni)
        acc[mi][ni] = __builtin_amdgcn_mfma_f32_16x16x32_bf16(a[mi], b[ni], acc[mi][ni], 0, 0, 0);
    __syncthreads();
  }
#pragma unroll
  for (int mi = 0; mi < 4; ++mi) {
    const int orow = row0 + wr64 + mi * 16 + fg * 4;
#pragma unroll
    for (int ni = 0; ni < 4; ++ni) {
      const int ocol = col0 + wc64 + ni * 16 + fr;
#pragma unroll
      for (int r = 0; r < 4; ++r)
        C[(size_t)(orow + r) * N + ocol] = acc[mi][ni][r];
    }
  }
}

// ---------------------------------------------------------------------------
// Gate projections (unchanged from round 1)
// ---------------------------------------------------------------------------
__global__ __launch_bounds__(256) void gates_kernel(
    const float* __restrict__ x, const float* __restrict__ Wb,
    const float* __restrict__ Wg, const float* __restrict__ bg,
    const float* __restrict__ Wl, const float* __restrict__ bl,
    const float* __restrict__ log_temp, float* __restrict__ beta,
    float* __restrict__ wgl, float* __restrict__ pmix) {
  const int wave = threadIdx.x >> 6, lane = threadIdx.x & 63;
  const int row = (blockIdx.x << 2) + wave;
  if (row >= Bn * Ln) return;
  const float* xr = x + (size_t)row * Dn;
  float acc[20];
#pragma unroll
  for (int c = 0; c < 20; ++c) acc[c] = 0.f;
#pragma unroll
  for (int i = 0; i < 4; ++i) {
    const float4 xv = *(const float4*)&xr[(lane << 2) + (i << 8)];
    const float xa[4] = {xv.x, xv.y, xv.z, xv.w};
#pragma unroll
    for (int j = 0; j < 4; ++j) {
      const int kk = (i << 8) + (lane << 2) + j;
      const float xx = xa[j];
#pragma unroll
      for (int h = 0; h < 4; ++h) acc[h] = fmaf(xx, Wb[kk * 4 + h], acc[h]);
#pragma unroll
      for (int h = 0; h < 4; ++h) acc[4 + h] = fmaf(xx, Wg[kk * 4 + h], acc[4 + h]);
#pragma unroll
      for (int c = 0; c < 12; ++c) acc[8 + c] = fmaf(xx, Wl[kk * 12 + c], acc[8 + c]);
    }
  }
#pragma unroll
  for (int c = 0; c < 20; ++c)
    for (int off = 32; off; off >>= 1) acc[c] += __shfl_down(acc[c], off);
  if (lane == 0) {
    const int b = row >> 12, l = row & (Ln - 1);
#pragma unroll
    for (int h = 0; h < 4; ++h)
      beta[((size_t)(b * Hn + h) << 12) + l] = sigmoidf_(acc[h]);
#pragma unroll
    for (int h = 0; h < 4; ++h) wgl[row * 4 + h] = sigmoidf_(acc[4 + h] + bg[h]);
#pragma unroll
    for (int h = 0; h < 4; ++h) {
      const float it = 1.f / __expf(log_temp[h]);
      const float l0 = (acc[8 + h * 3 + 0] + bl[h * 3 + 0]) * it;
      const float l1 = (acc[8 + h * 3 + 1] + bl[h * 3 + 1]) * it;
      const float l2 = (acc[8 + h * 3 + 2] + bl[h * 3 + 2]) * it;
      const float mx = fmaxf(l0, fmaxf(l1, l2));
      const float e0 = __expf(l0 - mx), e1 = __expf(l1 - mx), e2 = __expf(l2 - mx);
      const float is = 1.f / (e0 + e1 + e2);
      pmix[row * 12 + h * 3 + 0] = e0 * is;
      pmix[row * 12 + h * 3 + 1] = e1 * is;
      pmix[row * 12 + h * 3 + 2] = e2 * is;
    }
  }
}

// ---------------------------------------------------------------------------
// Causal depthwise conv (K=4) + SiLU (+ optional l2norm). (unchanged)
// ---------------------------------------------------------------------------
template <int DO_L2>
__global__ __launch_bounds__(256) void conv_act_kernel(
    const float* __restrict__ raw, const float* __restrict__ cw,
    float* __restrict__ out) {
  const int blk = blockIdx.x;
  const int b = blk >> 12, l = blk & (Ln - 1);
  const int t = threadIdx.x;
  float vals[4];
#pragma unroll
  for (int g = 0; g < 4; ++g) {
    const int c = (g << 8) + t;
    float a = 0.f;
#pragma unroll
    for (int j = 0; j < 4; ++j) {
      const int ls = l - 3 + j;
      if (ls >= 0) a = fmaf(cw[c * 4 + j], raw[(((size_t)b << 12) + ls) * 1024 + c], a);
    }
    vals[g] = a * sigmoidf_(a);
  }
  if (DO_L2) {
    __shared__ float red[4][4];
    float ss[4];
#pragma unroll
    for (int g = 0; g < 4; ++g) ss[g] = vals[g] * vals[g];
#pragma unroll
    for (int g = 0; g < 4; ++g)
      for (int off = 32; off; off >>= 1) ss[g] += __shfl_down(ss[g], off);
    const int wave = t >> 6, lane = t & 63;
    if (lane == 0) {
#pragma unroll
      for (int g = 0; g < 4; ++g) red[wave][g] = ss[g];
    }
    __syncthreads();
#pragma unroll
    for (int g = 0; g < 4; ++g) {
      const float s = red[0][g] + red[1][g] + red[2][g] + red[3][g];
      vals[g] *= rsqrtf(s + 1e-6f);
    }
  }
#pragma unroll
  for (int g = 0; g < 4; ++g)
    out[((((size_t)(b * Hn + g)) << 12) + l) * 256 + t] = vals[g];
}

// ---------------------------------------------------------------------------
// Per-chunk precompute (unchanged)
// ---------------------------------------------------------------------------
__global__ __launch_bounds__(256) void precomp_kernel(
    const float* __restrict__ q, const float* __restrict__ k,
    const float* __restrict__ v, const float* __restrict__ beta,
    float* __restrict__ w_out, float* __restrict__ u0_out,
    float* __restrict__ attn_out) {
  const int blk = blockIdx.x;
  const int n = blk & 127, bh = blk >> 7;
  const size_t base = (((size_t)bh << 12) + (n << 5)) * 256;
  __shared__ __align__(16) float qs[32][260];
  __shared__ __align__(16) float ks[32][260];
  __shared__ __align__(16) float vb[32][260];
  __shared__ float Am[32][33], Tm[32][33], bet[32];
  const int t = threadIdx.x;
  if (t < 32) bet[t] = beta[((size_t)bh << 12) + (n << 5) + t];
  __syncthreads();
  for (int idx = t; idx < 32 * 64; idx += 256) {
    const int r = idx >> 6, fi = (idx & 63) << 2;
    *(float4*)&qs[r][fi] = *(const float4*)&q[base + r * 256 + fi];
    *(float4*)&ks[r][fi] = *(const float4*)&k[base + r * 256 + fi];
    float4 vv = *(const float4*)&v[base + r * 256 + fi];
    const float bm = bet[r];
    vv.x *= bm; vv.y *= bm; vv.z *= bm; vv.w *= bm;
    *(float4*)&vb[r][fi] = vv;
  }
  __syncthreads();
  {
    const int i = t >> 3, j0 = t & 7;
    float dq[4] = {0.f, 0.f, 0.f, 0.f}, dk2[4] = {0.f, 0.f, 0.f, 0.f};
    for (int d = 0; d < 256; d += 4) {
      const float4 qi = *(const float4*)&qs[i][d];
      const float4 ki = *(const float4*)&ks[i][d];
#pragma unroll
      for (int jj = 0; jj < 4; ++jj) {
        const float4 kj = *(const float4*)&ks[j0 + (jj << 3)][d];
        dq[jj] = fmaf(qi.x, kj.x, dq[jj]);
        dq[jj] = fmaf(qi.y, kj.y, dq[jj]);
        dq[jj] = fmaf(qi.z, kj.z, dq[jj]);
        dq[jj] = fmaf(qi.w, kj.w, dq[jj]);
        dk2[jj] = fmaf(ki.x, kj.x, dk2[jj]);
        dk2[jj] = fmaf(ki.y, kj.y, dk2[jj]);
        dk2[jj] = fmaf(ki.z, kj.z, dk2[jj]);
        dk2[jj] = fmaf(ki.w, kj.w, dk2[jj]);
      }
    }
    const float bi = bet[i];
#pragma unroll
    for (int jj = 0; jj < 4; ++jj) {
      const int j = j0 + (jj << 3);
      Am[i][j] = bi * dk2[jj];
      attn_out[((size_t)blk << 10) + (i << 5) + j] = (j <= i) ? dq[jj] : 0.f;
    }
  }
  for (int idx = t; idx < 1024; idx += 256)
    Tm[idx >> 5][idx & 31] = ((idx >> 5) == (idx & 31)) ? 1.f : 0.f;
  __syncthreads();
  for (int i = 1; i < 32; ++i) {
    if (t < 32) {
      float s = 0.f;
      for (int m = 0; m < i; ++m) s = fmaf(Am[i][m], Tm[m][t], s);
      Tm[i][t] = ((i == t) ? 1.f : 0.f) - s;
    }
    __syncthreads();
  }
  {
    const int i = t >> 3;
    const int dj = (t & 7) << 2;
    float4 ua[8], wa[8];
#pragma unroll
    for (int s = 0; s < 8; ++s) {
      ua[s] = make_float4(0.f, 0.f, 0.f, 0.f);
      wa[s] = make_float4(0.f, 0.f, 0.f, 0.f);
    }
    for (int m = 0; m < 32; ++m) {
      const float tim = Tm[i][m];
      const float t2m = tim * bet[m];
#pragma unroll
      for (int s = 0; s < 8; ++s) {
        const int d = dj + (s << 5);
        const float4 vv = *(const float4*)&vb[m][d];
        const float4 kk = *(const float4*)&ks[m][d];
        ua[s].x = fmaf(tim, vv.x, ua[s].x);
        ua[s].y = fmaf(tim, vv.y, ua[s].y);
        ua[s].z = fmaf(tim, vv.z, ua[s].z);
        ua[s].w = fmaf(tim, vv.w, ua[s].w);
        wa[s].x = fmaf(t2m, kk.x, wa[s].x);
        wa[s].y = fmaf(t2m, kk.y, wa[s].y);
        wa[s].z = fmaf(t2m, kk.z, wa[s].z);
        wa[s].w = fmaf(t2m, kk.w, wa[s].w);
      }
    }
#pragma unroll
    for (int s = 0; s < 8; ++s) {
      const int d = dj + (s << 5);
      *(float4*)&u0_out[base + i * 256 + d] = ua[s];
      *(float4*)&w_out[base + i * 256 + d] = wa[s];
    }
  }
}

// ---------------------------------------------------------------------------
// Scan v2: S held in registers, LDS-broadcast operands.
// grid = 256: bh = blk & 7 (XCD-affine), dv-slice = (blk>>3)*8.
// Thread t: dg = cc = t>>3 (0..31), jj = t&7. Owns S[dg*8..+8][j0+jj].
// ---------------------------------------------------------------------------
__global__ __launch_bounds__(256, 1) void scan_kernel(
    const float* __restrict__ q, const float* __restrict__ k,
    const float* __restrict__ w, const float* __restrict__ u0,
    const float* __restrict__ attng, float* __restrict__ dout) {
  const int bh = blockIdx.x & 7;
  const int j0 = (blockIdx.x >> 3) << 3;
  __shared__ __align__(16) float wsm[32 * 256];
  __shared__ __align__(16) float qsm[32 * 256];
  __shared__ __align__(16) float ksm[32 * 256];
  __shared__ float attns[32 * 33];
  __shared__ float pu[4 * 32 * 9];
  __shared__ float po[4 * 32 * 9];
  __shared__ float um[256];
  const int t = threadIdx.x;
  const int cc = t >> 3, jj = t & 7;     // cc doubles as dg
  const int dg8 = cc << 3;
  const int wv = t >> 6;
  const size_t bhb = ((size_t)bh << 12) * 256;
  float s[8];
#pragma unroll
  for (int i = 0; i < 8; ++i) s[i] = 0.f;

  for (int n = 0; n < NCHn; ++n) {
    __syncthreads();  // protect LDS from previous chunk's readers
    const size_t cb = bhb + ((size_t)n << 5) * 256;
#pragma unroll
    for (int it = 0; it < 8; ++it) {
      const int off = it * 4096 + t * 16;  // bytes
      gl2lds16((const char*)(w + cb) + off, (char*)wsm + off);
      gl2lds16((const char*)(q + cb) + off, (char*)qsm + off);
      gl2lds16((const char*)(k + cb) + off, (char*)ksm + off);
    }
#pragma unroll
    for (int r4 = 0; r4 < 4; ++r4) {
      const int idx = t + r4 * 256;
      attns[(idx >> 5) * 33 + (idx & 31)] =
          attng[(((size_t)(bh * NCHn + n)) << 10) + idx];
    }
    const float u0v = u0[cb + cc * 256 + j0 + jj];
    __syncthreads();  // staging visible

    // phase A: partial u = w@S, partial o = q@S over this thread's dk slice
    float puv[32], pov[32];
#pragma unroll
    for (int c = 0; c < 32; ++c) {
      const float4 w0 = *(const float4*)&wsm[c * 256 + dg8];
      const float4 w1 = *(const float4*)&wsm[c * 256 + dg8 + 4];
      const float4 q0 = *(const float4*)&qsm[c * 256 + dg8];
      const float4 q1 = *(const float4*)&qsm[c * 256 + dg8 + 4];
      float a = w0.x * s[0];
      a = fmaf(w0.y, s[1], a); a = fmaf(w0.z, s[2], a); a = fmaf(w0.w, s[3], a);
      a = fmaf(w1.x, s[4], a); a = fmaf(w1.y, s[5], a);
      a = fmaf(w1.z, s[6], a); a = fmaf(w1.w, s[7], a);
      puv[c] = a;
      float b = q0.x * s[0];
      b = fmaf(q0.y, s[1], b); b = fmaf(q0.z, s[2], b); b = fmaf(q0.w, s[3], b);
      b = fmaf(q1.x, s[4], b); b = fmaf(q1.y, s[5], b);
      b = fmaf(q1.z, s[6], b); b = fmaf(q1.w, s[7], b);
      pov[c] = b;
    }
    // butterfly over the 8 dg-groups within each wave (t bits 3..5)
#pragma unroll
    for (int st = 8; st <= 32; st <<= 1) {
#pragma unroll
      for (int c = 0; c < 32; ++c) {
        puv[c] += __shfl_xor(puv[c], st);
        pov[c] += __shfl_xor(pov[c], st);
      }
    }
    if ((t & 56) == 0) {  // one dg-group per wave writes the wave partials
#pragma unroll
      for (int c = 0; c < 32; ++c) {
        pu[wv * 288 + c * 9 + jj] = puv[c];
        po[wv * 288 + c * 9 + jj] = pov[c];
      }
    }
    __syncthreads();

    // phase B: u = u0 - sum(wave partials); o partial likewise
    const float umv = u0v - (pu[cc * 9 + jj] + pu[288 + cc * 9 + jj] +
                             pu[576 + cc * 9 + jj] + pu[864 + cc * 9 + jj]);
    um[cc * 8 + jj] = umv;
    float ov = po[cc * 9 + jj] + po[288 + cc * 9 + jj] +
               po[576 + cc * 9 + jj] + po[864 + cc * 9 + jj];
    __syncthreads();

    // phase C: o += attn @ u ; write out
#pragma unroll
    for (int m = 0; m < 32; ++m)
      ov = fmaf(attns[cc * 33 + m], um[m * 8 + jj], ov);
    dout[cb + cc * 256 + j0 + jj] = ov;

    // phase C2: S += k^T @ u  (per-thread register update)
#pragma unroll
    for (int m = 0; m < 32; ++m) {
      const float uu = um[m * 8 + jj];
      const float4 k0 = *(const float4*)&ksm[m * 256 + dg8];
      const float4 k1 = *(const float4*)&ksm[m * 256 + dg8 + 4];
      s[0] = fmaf(uu, k0.x, s[0]); s[1] = fmaf(uu, k0.y, s[1]);
      s[2] = fmaf(uu, k0.z, s[2]); s[3] = fmaf(uu, k0.w, s[3]);
      s[4] = fmaf(uu, k1.x, s[4]); s[5] = fmaf(uu, k1.y, s[5]);
      s[6] = fmaf(uu, k1.z, s[6]); s[7] = fmaf(uu, k1.w, s[7]);
    }
  }
}

// ---------------------------------------------------------------------------
// FIR(3/31) + gating + per-head RMSNorm (unchanged)
// ---------------------------------------------------------------------------
__global__ __launch_bounds__(256) void mix_kernel(
    const float* __restrict__ v, const float* __restrict__ delta,
    const float* __restrict__ wgl, const float* __restrict__ pmix,
    const float* __restrict__ firs, const float* __restrict__ firl,
    const float* __restrict__ rms_w, float* __restrict__ out) {
  const int blk = blockIdx.x;
  const int b = blk >> 12, l = blk & (Ln - 1);
  const int t = threadIdx.x;
  float ov[4], ss[4];
#pragma unroll
  for (int g = 0; g < 4; ++g) {
    const size_t colbase = ((((size_t)(b * Hn + g)) << 12)) * 256 + t;
    const float vcur = v[colbase + (size_t)l * 256];
    float sh = 0.f;
#pragma unroll
    for (int j = 0; j < 3; ++j) {
      const int ls = l - 2 + j;
      if (ls >= 0) sh = fmaf(firs[((g << 8) + t) * 3 + j], v[colbase + (size_t)ls * 256], sh);
    }
    float lo = 0.f;
#pragma unroll
    for (int j = 0; j < 31; ++j) {
      const int ls = l - 30 + j;
      if (ls >= 0) lo = fmaf(firl[((g << 8) + t) * 31 + j], v[colbase + (size_t)ls * 256], lo);
    }
    const float p0 = pmix[blk * 12 + g * 3 + 0];
    const float p1 = pmix[blk * 12 + g * 3 + 1];
    const float p2 = pmix[blk * 12 + g * 3 + 2];
    const float wg = wgl[blk * 4 + g];
    const float mixv = p0 * vcur + p1 * sh + p2 * lo;
    const float o = wg * delta[colbase + (size_t)l * 256] + (1.f - wg) * mixv;
    ov[g] = o;
    ss[g] = o * o;
  }
  __shared__ float red[4][4];
#pragma unroll
  for (int g = 0; g < 4; ++g)
    for (int off = 32; off; off >>= 1) ss[g] += __shfl_down(ss[g], off);
  const int wave = t >> 6, lane = t & 63;
  if (lane == 0) {
#pragma unroll
    for (int g = 0; g < 4; ++g) red[wave][g] = ss[g];
  }
  __syncthreads();
#pragma unroll
  for (int g = 0; g < 4; ++g) {
    const float msq = (red[0][g] + red[1][g] + red[2][g] + red[3][g]) * (1.f / 256.f);
    out[(size_t)blk * 1024 + (g << 8) + t] = ov[g] * rsqrtf(msq + 1e-5f) * rms_w[t];
  }
}

// ---------------------------------------------------------------------------
extern "C" void kernel_launch(void* const* d_in, const int* in_sizes, int n_in,
                              void* d_out, int out_size, void* d_ws, size_t ws_size,
                              hipStream_t stream) {
  const float* x = (const float*)d_in[0];
  const float* Wq = (const float*)d_in[1];
  const float* Wk = (const float*)d_in[2];
  const float* Wv = (const float*)d_in[3];
  const float* cq = (const float*)d_in[4];
  const float* ck = (const float*)d_in[5];
  const float* cv = (const float*)d_in[6];
  const float* Wb = (const float*)d_in[7];
  const float* firs = (const float*)d_in[8];
  const float* firl = (const float*)d_in[9];
  const float* Wg = (const float*)d_in[10];
  const float* bg = (const float*)d_in[11];
  const float* Wl = (const float*)d_in[12];
  const float* bl = (const float*)d_in[13];
  const float* ltemp = (const float*)d_in[14];
  const float* rmsw = (const float*)d_in[15];
  const float* Wo = (const float*)d_in[16];

  float* ws = (float*)d_ws;
  const size_t NE = (size_t)Bn * Ln * 1024;  // 8.39M floats
  float* qraw = ws;
  float* kraw = ws + NE;
  float* vraw = ws + 2 * NE;
  float* qn = ws + 3 * NE;
  float* kn = ws + 4 * NE;
  float* vn = ws + 5 * NE;
  float* beta = ws + 6 * NE;
  float* wgl = beta + (size_t)Bn * Hn * Ln;                 // +32768
  float* pmix = wgl + (size_t)Bn * Ln * Hn;                 // +32768
  float* attn = pmix + (size_t)Bn * Ln * Hn * 3;            // +98304
  unsigned short* Wot = (unsigned short*)(attn + (size_t)Bn * Hn * NCHn * 1024);
  // bf16 staging overlapped into qn/kn slots (dead until convs / after scan):
  unsigned short* xb = (unsigned short*)qn;                 // 8.39M ushorts
  unsigned short* Wqt = (unsigned short*)(qn + 4194304);
  unsigned short* Wkt = Wqt + 1048576;
  unsigned short* Wvt = Wkt + 1048576;
  unsigned short* normed_bf = (unsigned short*)kn;          // kn dead after scan
  // post-conv reuse:
  float* wbuf = qraw;
  float* u0buf = kraw;
  float* dbuf = vraw;
  float* normed = qn;  // qn dead after scan

  const dim3 wtg(32, 32);
  wt_kernel<<<wtg, 256, 0, stream>>>(Wq, Wqt, 1024, 1024);
  wt_kernel<<<wtg, 256, 0, stream>>>(Wk, Wkt, 1024, 1024);
  wt_kernel<<<wtg, 256, 0, stream>>>(Wv, Wvt, 1024, 1024);
  wt_kernel<<<wtg, 256, 0, stream>>>(Wo, Wot, 1024, 1024);
  f2bf_kernel<<<(int)(NE / 1024), 256, 0, stream>>>(x, xb, (int)NE);

  const dim3 gg(8, 64);  // N/128, M/128
  gemm_bf16<<<gg, 256, 0, stream>>>(xb, Wqt, qraw, Bn * Ln, 1024, 1024);
  gemm_bf16<<<gg, 256, 0, stream>>>(xb, Wkt, kraw, Bn * Ln, 1024, 1024);
  gemm_bf16<<<gg, 256, 0, stream>>>(xb, Wvt, vraw, Bn * Ln, 1024, 1024);
  gates_kernel<<<Bn * Ln / 4, 256, 0, stream>>>(x, Wb, Wg, bg, Wl, bl, ltemp,
                                                beta, wgl, pmix);
  conv_act_kernel<1><<<Bn * Ln, 256, 0, stream>>>(qraw, cq, qn);
  conv_act_kernel<1><<<Bn * Ln, 256, 0, stream>>>(kraw, ck, kn);
  conv_act_kernel<0><<<Bn * Ln, 256, 0, stream>>>(vraw, cv, vn);
  precomp_kernel<<<Bn * Hn * NCHn, 256, 0, stream>>>(qn, kn, vn, beta, wbuf,
                                                     u0buf, attn);
  scan_kernel<<<Bn * Hn * 32, 256, 0, stream>>>(qn, kn, wbuf, u0buf, attn, dbuf);
  mix_kernel<<<Bn * Ln, 256, 0, stream>>>(vn, dbuf, wgl, pmix, firs, firl,
                                          rmsw, normed);
  f2bf_kernel<<<(int)(NE / 1024), 256, 0, stream>>>(normed, normed_bf, (int)NE);
  gemm_bf16<<<gg, 256, 0, stream>>>(normed_bf, Wot, (float*)d_out, Bn * Ln, 1024, 1024);
}

// Round 4
// 1381.257 us; speedup vs baseline: 2.2846x; 1.5486x over previous
//
#include <hip/hip_runtime.h>
#include <hip/hip_bf16.h>
#include <math.h>

#define Bn 2
#define Ln 4096
#define Dn 1024
#define Hn 4
#define DKn 256
#define DVn 256
#define NCHn 128  // L/32 chunks

typedef __attribute__((ext_vector_type(8))) short short8;
typedef __attribute__((ext_vector_type(4))) float f32x4;

__device__ __forceinline__ float sigmoidf_(float x) { return 1.f / (1.f + __expf(-x)); }

__device__ __forceinline__ unsigned short f2bf(float f) {
  union { float f; unsigned u; } v; v.f = f;
  unsigned r = v.u + 0x7FFFu + ((v.u >> 16) & 1u);
  return (unsigned short)(r >> 16);
}

__device__ __forceinline__ void gl2lds16(const void* g, void* l) {
  __builtin_amdgcn_global_load_lds((const __attribute__((address_space(1))) unsigned int*)g,
                                   (__attribute__((address_space(3))) unsigned int*)l, 16, 0, 0);
}

// ---------------------------------------------------------------------------
// Weight transpose + bf16 convert: Wt[n][k] = bf16(W[k][n]), K=N=1024.
// ---------------------------------------------------------------------------
__global__ __launch_bounds__(256) void wt_kernel(const float* __restrict__ W,
                                                 unsigned short* __restrict__ Wt,
                                                 int K, int N) {
  __shared__ float tile[32][33];
  const int bx = blockIdx.x * 32;  // n
  const int by = blockIdx.y * 32;  // k
  const int tx = threadIdx.x & 31, ty4 = (threadIdx.x >> 5) * 4;
#pragma unroll
  for (int r = 0; r < 4; ++r)
    tile[ty4 + r][tx] = W[(size_t)(by + ty4 + r) * N + bx + tx];
  __syncthreads();
#pragma unroll
  for (int r = 0; r < 4; ++r)
    Wt[(size_t)(bx + ty4 + r) * K + by + tx] = f2bf(tile[tx][ty4 + r]);
}

// ---------------------------------------------------------------------------
// fp32 -> bf16 elementwise, n % 1024 == 0
// ---------------------------------------------------------------------------
__global__ __launch_bounds__(256) void f2bf_kernel(const float* __restrict__ in,
                                                   unsigned short* __restrict__ out,
                                                   int n) {
  const int i4 = (blockIdx.x * 256 + threadIdx.x) * 4;
  if (i4 >= n) return;
  const float4 v = *(const float4*)&in[i4];
  ushort4 o;
  o.x = f2bf(v.x); o.y = f2bf(v.y); o.z = f2bf(v.z); o.w = f2bf(v.w);
  *(ushort4*)&out[i4] = o;
}

// ---------------------------------------------------------------------------
// bf16 MFMA GEMM: C[M,N] f32 = A[M,K]bf16 @ Bt[N,K]bf16^T. 128x128 tile, BK=32.
// ---------------------------------------------------------------------------
__global__ __launch_bounds__(256, 2) void gemm_bf16(const unsigned short* __restrict__ A,
                                                    const unsigned short* __restrict__ Bt,
                                                    float* __restrict__ C,
                                                    int M, int N, int K) {
  __shared__ __align__(16) unsigned short As[128 * 32];
  __shared__ __align__(16) unsigned short Bs[128 * 32];
  const int tid = threadIdx.x;
  const int wid = tid >> 6, lane = tid & 63;
  const int row0 = blockIdx.y * 128, col0 = blockIdx.x * 128;
  const int wr64 = (wid >> 1) * 64, wc64 = (wid & 1) * 64;
  const int fr = lane & 15, fg = lane >> 4;
  f32x4 acc[4][4];
#pragma unroll
  for (int i = 0; i < 4; ++i)
#pragma unroll
    for (int j = 0; j < 4; ++j) acc[i][j] = (f32x4){0.f, 0.f, 0.f, 0.f};
  for (int k0 = 0; k0 < K; k0 += 32) {
#pragma unroll
    for (int i = 0; i < 2; ++i) {
      const int off = wid * 2048 + i * 1024 + (lane << 4);  // LDS byte offset
      const int r = off >> 6;                               // tile row
      const int kb = off & 63;                              // byte within row
      gl2lds16((const char*)A + ((size_t)(row0 + r) * K + k0) * 2 + kb, (char*)As + off);
      gl2lds16((const char*)Bt + ((size_t)(col0 + r) * K + k0) * 2 + kb, (char*)Bs + off);
    }
    __syncthreads();
    short8 a[4], b[4];
#pragma unroll
    for (int mi = 0; mi < 4; ++mi)
      a[mi] = *(const short8*)&As[(wr64 + mi * 16 + fr) * 32 + fg * 8];
#pragma unroll
    for (int ni = 0; ni < 4; ++ni)
      b[ni] = *(const short8*)&Bs[(wc64 + ni * 16 + fr) * 32 + fg * 8];
#pragma unroll
    for (int mi = 0; mi < 4; ++mi)
#pragma unroll
      for (int ni = 0; ni < 4; ++ni)
        acc[mi][ni] = __builtin_amdgcn_mfma_f32_16x16x32_bf16(a[mi], b[ni], acc[mi][ni], 0, 0, 0);
    __syncthreads();
  }
#pragma unroll
  for (int mi = 0; mi < 4; ++mi) {
    const int orow = row0 + wr64 + mi * 16 + fg * 4;
#pragma unroll
    for (int ni = 0; ni < 4; ++ni) {
      const int ocol = col0 + wc64 + ni * 16 + fr;
#pragma unroll
      for (int r = 0; r < 4; ++r)
        C[(size_t)(orow + r) * N + ocol] = acc[mi][ni][r];
    }
  }
}

// ---------------------------------------------------------------------------
// Gate projections (unchanged)
// ---------------------------------------------------------------------------
__global__ __launch_bounds__(256) void gates_kernel(
    const float* __restrict__ x, const float* __restrict__ Wb,
    const float* __restrict__ Wg, const float* __restrict__ bg,
    const float* __restrict__ Wl, const float* __restrict__ bl,
    const float* __restrict__ log_temp, float* __restrict__ beta,
    float* __restrict__ wgl, float* __restrict__ pmix) {
  const int wave = threadIdx.x >> 6, lane = threadIdx.x & 63;
  const int row = (blockIdx.x << 2) + wave;
  if (row >= Bn * Ln) return;
  const float* xr = x + (size_t)row * Dn;
  float acc[20];
#pragma unroll
  for (int c = 0; c < 20; ++c) acc[c] = 0.f;
#pragma unroll
  for (int i = 0; i < 4; ++i) {
    const float4 xv = *(const float4*)&xr[(lane << 2) + (i << 8)];
    const float xa[4] = {xv.x, xv.y, xv.z, xv.w};
#pragma unroll
    for (int j = 0; j < 4; ++j) {
      const int kk = (i << 8) + (lane << 2) + j;
      const float xx = xa[j];
#pragma unroll
      for (int h = 0; h < 4; ++h) acc[h] = fmaf(xx, Wb[kk * 4 + h], acc[h]);
#pragma unroll
      for (int h = 0; h < 4; ++h) acc[4 + h] = fmaf(xx, Wg[kk * 4 + h], acc[4 + h]);
#pragma unroll
      for (int c = 0; c < 12; ++c) acc[8 + c] = fmaf(xx, Wl[kk * 12 + c], acc[8 + c]);
    }
  }
#pragma unroll
  for (int c = 0; c < 20; ++c)
    for (int off = 32; off; off >>= 1) acc[c] += __shfl_down(acc[c], off);
  if (lane == 0) {
    const int b = row >> 12, l = row & (Ln - 1);
#pragma unroll
    for (int h = 0; h < 4; ++h)
      beta[((size_t)(b * Hn + h) << 12) + l] = sigmoidf_(acc[h]);
#pragma unroll
    for (int h = 0; h < 4; ++h) wgl[row * 4 + h] = sigmoidf_(acc[4 + h] + bg[h]);
#pragma unroll
    for (int h = 0; h < 4; ++h) {
      const float it = 1.f / __expf(log_temp[h]);
      const float l0 = (acc[8 + h * 3 + 0] + bl[h * 3 + 0]) * it;
      const float l1 = (acc[8 + h * 3 + 1] + bl[h * 3 + 1]) * it;
      const float l2 = (acc[8 + h * 3 + 2] + bl[h * 3 + 2]) * it;
      const float mx = fmaxf(l0, fmaxf(l1, l2));
      const float e0 = __expf(l0 - mx), e1 = __expf(l1 - mx), e2 = __expf(l2 - mx);
      const float is = 1.f / (e0 + e1 + e2);
      pmix[row * 12 + h * 3 + 0] = e0 * is;
      pmix[row * 12 + h * 3 + 1] = e1 * is;
      pmix[row * 12 + h * 3 + 2] = e2 * is;
    }
  }
}

// ---------------------------------------------------------------------------
// Causal depthwise conv (K=4) + SiLU (+ optional l2norm). (unchanged)
// ---------------------------------------------------------------------------
template <int DO_L2>
__global__ __launch_bounds__(256) void conv_act_kernel(
    const float* __restrict__ raw, const float* __restrict__ cw,
    float* __restrict__ out) {
  const int blk = blockIdx.x;
  const int b = blk >> 12, l = blk & (Ln - 1);
  const int t = threadIdx.x;
  float vals[4];
#pragma unroll
  for (int g = 0; g < 4; ++g) {
    const int c = (g << 8) + t;
    float a = 0.f;
#pragma unroll
    for (int j = 0; j < 4; ++j) {
      const int ls = l - 3 + j;
      if (ls >= 0) a = fmaf(cw[c * 4 + j], raw[(((size_t)b << 12) + ls) * 1024 + c], a);
    }
    vals[g] = a * sigmoidf_(a);
  }
  if (DO_L2) {
    __shared__ float red[4][4];
    float ss[4];
#pragma unroll
    for (int g = 0; g < 4; ++g) ss[g] = vals[g] * vals[g];
#pragma unroll
    for (int g = 0; g < 4; ++g)
      for (int off = 32; off; off >>= 1) ss[g] += __shfl_down(ss[g], off);
    const int wave = t >> 6, lane = t & 63;
    if (lane == 0) {
#pragma unroll
      for (int g = 0; g < 4; ++g) red[wave][g] = ss[g];
    }
    __syncthreads();
#pragma unroll
    for (int g = 0; g < 4; ++g) {
      const float s = red[0][g] + red[1][g] + red[2][g] + red[3][g];
      vals[g] *= rsqrtf(s + 1e-6f);
    }
  }
#pragma unroll
  for (int g = 0; g < 4; ++g)
    out[((((size_t)(b * Hn + g)) << 12) + l) * 256 + t] = vals[g];
}

// ---------------------------------------------------------------------------
// Per-chunk precompute (unchanged)
// ---------------------------------------------------------------------------
__global__ __launch_bounds__(256) void precomp_kernel(
    const float* __restrict__ q, const float* __restrict__ k,
    const float* __restrict__ v, const float* __restrict__ beta,
    float* __restrict__ w_out, float* __restrict__ u0_out,
    float* __restrict__ attn_out) {
  const int blk = blockIdx.x;
  const int n = blk & 127, bh = blk >> 7;
  const size_t base = (((size_t)bh << 12) + (n << 5)) * 256;
  __shared__ __align__(16) float qs[32][260];
  __shared__ __align__(16) float ks[32][260];
  __shared__ __align__(16) float vb[32][260];
  __shared__ float Am[32][33], Tm[32][33], bet[32];
  const int t = threadIdx.x;
  if (t < 32) bet[t] = beta[((size_t)bh << 12) + (n << 5) + t];
  __syncthreads();
  for (int idx = t; idx < 32 * 64; idx += 256) {
    const int r = idx >> 6, fi = (idx & 63) << 2;
    *(float4*)&qs[r][fi] = *(const float4*)&q[base + r * 256 + fi];
    *(float4*)&ks[r][fi] = *(const float4*)&k[base + r * 256 + fi];
    float4 vv = *(const float4*)&v[base + r * 256 + fi];
    const float bm = bet[r];
    vv.x *= bm; vv.y *= bm; vv.z *= bm; vv.w *= bm;
    *(float4*)&vb[r][fi] = vv;
  }
  __syncthreads();
  {
    const int i = t >> 3, j0 = t & 7;
    float dq[4] = {0.f, 0.f, 0.f, 0.f}, dk2[4] = {0.f, 0.f, 0.f, 0.f};
    for (int d = 0; d < 256; d += 4) {
      const float4 qi = *(const float4*)&qs[i][d];
      const float4 ki = *(const float4*)&ks[i][d];
#pragma unroll
      for (int jj = 0; jj < 4; ++jj) {
        const float4 kj = *(const float4*)&ks[j0 + (jj << 3)][d];
        dq[jj] = fmaf(qi.x, kj.x, dq[jj]);
        dq[jj] = fmaf(qi.y, kj.y, dq[jj]);
        dq[jj] = fmaf(qi.z, kj.z, dq[jj]);
        dq[jj] = fmaf(qi.w, kj.w, dq[jj]);
        dk2[jj] = fmaf(ki.x, kj.x, dk2[jj]);
        dk2[jj] = fmaf(ki.y, kj.y, dk2[jj]);
        dk2[jj] = fmaf(ki.z, kj.z, dk2[jj]);
        dk2[jj] = fmaf(ki.w, kj.w, dk2[jj]);
      }
    }
    const float bi = bet[i];
#pragma unroll
    for (int jj = 0; jj < 4; ++jj) {
      const int j = j0 + (jj << 3);
      Am[i][j] = bi * dk2[jj];
      attn_out[((size_t)blk << 10) + (i << 5) + j] = (j <= i) ? dq[jj] : 0.f;
    }
  }
  for (int idx = t; idx < 1024; idx += 256)
    Tm[idx >> 5][idx & 31] = ((idx >> 5) == (idx & 31)) ? 1.f : 0.f;
  __syncthreads();
  for (int i = 1; i < 32; ++i) {
    if (t < 32) {
      float s = 0.f;
      for (int m = 0; m < i; ++m) s = fmaf(Am[i][m], Tm[m][t], s);
      Tm[i][t] = ((i == t) ? 1.f : 0.f) - s;
    }
    __syncthreads();
  }
  {
    const int i = t >> 3;
    const int dj = (t & 7) << 2;
    float4 ua[8], wa[8];
#pragma unroll
    for (int s = 0; s < 8; ++s) {
      ua[s] = make_float4(0.f, 0.f, 0.f, 0.f);
      wa[s] = make_float4(0.f, 0.f, 0.f, 0.f);
    }
    for (int m = 0; m < 32; ++m) {
      const float tim = Tm[i][m];
      const float t2m = tim * bet[m];
#pragma unroll
      for (int s = 0; s < 8; ++s) {
        const int d = dj + (s << 5);
        const float4 vv = *(const float4*)&vb[m][d];
        const float4 kk = *(const float4*)&ks[m][d];
        ua[s].x = fmaf(tim, vv.x, ua[s].x);
        ua[s].y = fmaf(tim, vv.y, ua[s].y);
        ua[s].z = fmaf(tim, vv.z, ua[s].z);
        ua[s].w = fmaf(tim, vv.w, ua[s].w);
        wa[s].x = fmaf(t2m, kk.x, wa[s].x);
        wa[s].y = fmaf(t2m, kk.y, wa[s].y);
        wa[s].z = fmaf(t2m, kk.z, wa[s].z);
        wa[s].w = fmaf(t2m, kk.w, wa[s].w);
      }
    }
#pragma unroll
    for (int s = 0; s < 8; ++s) {
      const int d = dj + (s << 5);
      *(float4*)&u0_out[base + i * 256 + d] = ua[s];
      *(float4*)&w_out[base + i * 256 + d] = wa[s];
    }
  }
}

// ---------------------------------------------------------------------------
// Scan v2 (unchanged)
// ---------------------------------------------------------------------------
__global__ __launch_bounds__(256, 1) void scan_kernel(
    const float* __restrict__ q, const float* __restrict__ k,
    const float* __restrict__ w, const float* __restrict__ u0,
    const float* __restrict__ attng, float* __restrict__ dout) {
  const int bh = blockIdx.x & 7;
  const int j0 = (blockIdx.x >> 3) << 3;
  __shared__ __align__(16) float wsm[32 * 256];
  __shared__ __align__(16) float qsm[32 * 256];
  __shared__ __align__(16) float ksm[32 * 256];
  __shared__ float attns[32 * 33];
  __shared__ float pu[4 * 32 * 9];
  __shared__ float po[4 * 32 * 9];
  __shared__ float um[256];
  const int t = threadIdx.x;
  const int cc = t >> 3, jj = t & 7;
  const int dg8 = cc << 3;
  const int wv = t >> 6;
  const size_t bhb = ((size_t)bh << 12) * 256;
  float s[8];
#pragma unroll
  for (int i = 0; i < 8; ++i) s[i] = 0.f;

  for (int n = 0; n < NCHn; ++n) {
    __syncthreads();
    const size_t cb = bhb + ((size_t)n << 5) * 256;
#pragma unroll
    for (int it = 0; it < 8; ++it) {
      const int off = it * 4096 + t * 16;
      gl2lds16((const char*)(w + cb) + off, (char*)wsm + off);
      gl2lds16((const char*)(q + cb) + off, (char*)qsm + off);
      gl2lds16((const char*)(k + cb) + off, (char*)ksm + off);
    }
#pragma unroll
    for (int r4 = 0; r4 < 4; ++r4) {
      const int idx = t + r4 * 256;
      attns[(idx >> 5) * 33 + (idx & 31)] =
          attng[(((size_t)(bh * NCHn + n)) << 10) + idx];
    }
    const float u0v = u0[cb + cc * 256 + j0 + jj];
    __syncthreads();

    float puv[32], pov[32];
#pragma unroll
    for (int c = 0; c < 32; ++c) {
      const float4 w0 = *(const float4*)&wsm[c * 256 + dg8];
      const float4 w1 = *(const float4*)&wsm[c * 256 + dg8 + 4];
      const float4 q0 = *(const float4*)&qsm[c * 256 + dg8];
      const float4 q1 = *(const float4*)&qsm[c * 256 + dg8 + 4];
      float a = w0.x * s[0];
      a = fmaf(w0.y, s[1], a); a = fmaf(w0.z, s[2], a); a = fmaf(w0.w, s[3], a);
      a = fmaf(w1.x, s[4], a); a = fmaf(w1.y, s[5], a);
      a = fmaf(w1.z, s[6], a); a = fmaf(w1.w, s[7], a);
      puv[c] = a;
      float b = q0.x * s[0];
      b = fmaf(q0.y, s[1], b); b = fmaf(q0.z, s[2], b); b = fmaf(q0.w, s[3], b);
      b = fmaf(q1.x, s[4], b); b = fmaf(q1.y, s[5], b);
      b = fmaf(q1.z, s[6], b); b = fmaf(q1.w, s[7], b);
      pov[c] = b;
    }
#pragma unroll
    for (int st = 8; st <= 32; st <<= 1) {
#pragma unroll
      for (int c = 0; c < 32; ++c) {
        puv[c] += __shfl_xor(puv[c], st);
        pov[c] += __shfl_xor(pov[c], st);
      }
    }
    if ((t & 56) == 0) {
#pragma unroll
      for (int c = 0; c < 32; ++c) {
        pu[wv * 288 + c * 9 + jj] = puv[c];
        po[wv * 288 + c * 9 + jj] = pov[c];
      }
    }
    __syncthreads();

    const float umv = u0v - (pu[cc * 9 + jj] + pu[288 + cc * 9 + jj] +
                             pu[576 + cc * 9 + jj] + pu[864 + cc * 9 + jj]);
    um[cc * 8 + jj] = umv;
    float ov = po[cc * 9 + jj] + po[288 + cc * 9 + jj] +
               po[576 + cc * 9 + jj] + po[864 + cc * 9 + jj];
    __syncthreads();

#pragma unroll
    for (int m = 0; m < 32; ++m)
      ov = fmaf(attns[cc * 33 + m], um[m * 8 + jj], ov);
    dout[cb + cc * 256 + j0 + jj] = ov;

#pragma unroll
    for (int m = 0; m < 32; ++m) {
      const float uu = um[m * 8 + jj];
      const float4 k0 = *(const float4*)&ksm[m * 256 + dg8];
      const float4 k1 = *(const float4*)&ksm[m * 256 + dg8 + 4];
      s[0] = fmaf(uu, k0.x, s[0]); s[1] = fmaf(uu, k0.y, s[1]);
      s[2] = fmaf(uu, k0.z, s[2]); s[3] = fmaf(uu, k0.w, s[3]);
      s[4] = fmaf(uu, k1.x, s[4]); s[5] = fmaf(uu, k1.y, s[5]);
      s[6] = fmaf(uu, k1.z, s[6]); s[7] = fmaf(uu, k1.w, s[7]);
    }
  }
}

// ---------------------------------------------------------------------------
// Mix v2: streaming FIR along l with register ring buffer.
// grid = 512 (XCD-chunk-swizzled): (b, h, lt) with Lt=64 rows per block.
// ---------------------------------------------------------------------------
#define MIX_LT 64
__global__ __launch_bounds__(256) void mix_kernel(
    const float* __restrict__ v, const float* __restrict__ delta,
    const float* __restrict__ wgl, const float* __restrict__ pmix,
    const float* __restrict__ firs, const float* __restrict__ firl,
    const float* __restrict__ rms_w, unsigned short* __restrict__ out) {
  const int wgid = ((int)blockIdx.x & 7) * 64 + ((int)blockIdx.x >> 3);
  const int b = wgid >> 8;
  const int h = (wgid >> 6) & 3;
  const int lt = wgid & 63;
  const int l0 = lt * MIX_LT;
  const int t = threadIdx.x;
  const int wv = t >> 6, lane = t & 63;
  const float* vcol = v + ((((size_t)(b * Hn + h)) << 12)) * 256 + t;
  const float* dcol = delta + ((((size_t)(b * Hn + h)) << 12)) * 256 + t;
  float fw[31], fs3[3];
#pragma unroll
  for (int j = 0; j < 31; ++j) fw[j] = firl[((h << 8) + t) * 31 + j];
#pragma unroll
  for (int j = 0; j < 3; ++j) fs3[j] = firs[((h << 8) + t) * 3 + j];
  const float rw = rms_w[t];
  float win[31];
#pragma unroll
  for (int j = 0; j < 30; ++j) {
    const int ls = l0 - 30 + j;
    win[j] = (ls >= 0) ? vcol[(size_t)ls * 256] : 0.f;
  }
  win[30] = 0.f;
  __shared__ float wred[MIX_LT * 4];
  float o[MIX_LT];
#pragma unroll
  for (int i = 0; i < MIX_LT; ++i) {
    const int l = l0 + i;
    const float vnew = vcol[(size_t)l * 256];
    float lo = fw[30] * vnew;
#pragma unroll
    for (int j = 0; j < 30; ++j) lo = fmaf(fw[j], win[(i + j) % 31], lo);
    float sh = fs3[2] * vnew;
    sh = fmaf(fs3[1], win[(i + 29) % 31], sh);
    sh = fmaf(fs3[0], win[(i + 28) % 31], sh);
    win[(i + 30) % 31] = vnew;
    const int row = (b << 12) + l;
    const float p0 = pmix[row * 12 + h * 3 + 0];
    const float p1 = pmix[row * 12 + h * 3 + 1];
    const float p2 = pmix[row * 12 + h * 3 + 2];
    const float wg = wgl[row * 4 + h];
    const float mixv = p0 * vnew + p1 * sh + p2 * lo;
    const float oo = wg * dcol[(size_t)l * 256] + (1.f - wg) * mixv;
    o[i] = oo;
    float ss = oo * oo;
#pragma unroll
    for (int m = 1; m < 64; m <<= 1) ss += __shfl_xor(ss, m);
    if (lane == 0) wred[i * 4 + wv] = ss;
  }
  __syncthreads();
#pragma unroll
  for (int i = 0; i < MIX_LT; ++i) {
    const float sum = wred[i * 4] + wred[i * 4 + 1] + wred[i * 4 + 2] + wred[i * 4 + 3];
    const float sc = rsqrtf(sum * (1.f / 256.f) + 1e-5f);
    const int l = l0 + i;
    out[(size_t)((b << 12) + l) * 1024 + (h << 8) + t] = f2bf(o[i] * sc * rw);
  }
}

// ---------------------------------------------------------------------------
extern "C" void kernel_launch(void* const* d_in, const int* in_sizes, int n_in,
                              void* d_out, int out_size, void* d_ws, size_t ws_size,
                              hipStream_t stream) {
  const float* x = (const float*)d_in[0];
  const float* Wq = (const float*)d_in[1];
  const float* Wk = (const float*)d_in[2];
  const float* Wv = (const float*)d_in[3];
  const float* cq = (const float*)d_in[4];
  const float* ck = (const float*)d_in[5];
  const float* cv = (const float*)d_in[6];
  const float* Wb = (const float*)d_in[7];
  const float* firs = (const float*)d_in[8];
  const float* firl = (const float*)d_in[9];
  const float* Wg = (const float*)d_in[10];
  const float* bg = (const float*)d_in[11];
  const float* Wl = (const float*)d_in[12];
  const float* bl = (const float*)d_in[13];
  const float* ltemp = (const float*)d_in[14];
  const float* rmsw = (const float*)d_in[15];
  const float* Wo = (const float*)d_in[16];

  float* ws = (float*)d_ws;
  const size_t NE = (size_t)Bn * Ln * 1024;  // 8.39M floats
  float* qraw = ws;
  float* kraw = ws + NE;
  float* vraw = ws + 2 * NE;
  float* qn = ws + 3 * NE;
  float* kn = ws + 4 * NE;
  float* vn = ws + 5 * NE;
  float* beta = ws + 6 * NE;
  float* wgl = beta + (size_t)Bn * Hn * Ln;
  float* pmix = wgl + (size_t)Bn * Ln * Hn;
  float* attn = pmix + (size_t)Bn * Ln * Hn * 3;
  unsigned short* Wot = (unsigned short*)(attn + (size_t)Bn * Hn * NCHn * 1024);
  unsigned short* xb = (unsigned short*)qn;
  unsigned short* Wqt = (unsigned short*)(qn + 4194304);
  unsigned short* Wkt = Wqt + 1048576;
  unsigned short* Wvt = Wkt + 1048576;
  unsigned short* normed_bf = (unsigned short*)kn;  // kn dead after scan
  float* wbuf = qraw;
  float* u0buf = kraw;
  float* dbuf = vraw;

  const dim3 wtg(32, 32);
  wt_kernel<<<wtg, 256, 0, stream>>>(Wq, Wqt, 1024, 1024);
  wt_kernel<<<wtg, 256, 0, stream>>>(Wk, Wkt, 1024, 1024);
  wt_kernel<<<wtg, 256, 0, stream>>>(Wv, Wvt, 1024, 1024);
  wt_kernel<<<wtg, 256, 0, stream>>>(Wo, Wot, 1024, 1024);
  f2bf_kernel<<<(int)(NE / 1024), 256, 0, stream>>>(x, xb, (int)NE);

  const dim3 gg(8, 64);  // N/128, M/128
  gemm_bf16<<<gg, 256, 0, stream>>>(xb, Wqt, qraw, Bn * Ln, 1024, 1024);
  gemm_bf16<<<gg, 256, 0, stream>>>(xb, Wkt, kraw, Bn * Ln, 1024, 1024);
  gemm_bf16<<<gg, 256, 0, stream>>>(xb, Wvt, vraw, Bn * Ln, 1024, 1024);
  gates_kernel<<<Bn * Ln / 4, 256, 0, stream>>>(x, Wb, Wg, bg, Wl, bl, ltemp,
                                                beta, wgl, pmix);
  conv_act_kernel<1><<<Bn * Ln, 256, 0, stream>>>(qraw, cq, qn);
  conv_act_kernel<1><<<Bn * Ln, 256, 0, stream>>>(kraw, ck, kn);
  conv_act_kernel<0><<<Bn * Ln, 256, 0, stream>>>(vraw, cv, vn);
  precomp_kernel<<<Bn * Hn * NCHn, 256, 0, stream>>>(qn, kn, vn, beta, wbuf,
                                                     u0buf, attn);
  scan_kernel<<<Bn * Hn * 32, 256, 0, stream>>>(qn, kn, wbuf, u0buf, attn, dbuf);
  mix_kernel<<<Bn * Hn * (Ln / MIX_LT), 256, 0, stream>>>(
      vn, dbuf, wgl, pmix, firs, firl, rmsw, normed_bf);
  gemm_bf16<<<gg, 256, 0, stream>>>(normed_bf, Wot, (float*)d_out, Bn * Ln, 1024, 1024);
}

// Round 5
// 886.315 us; speedup vs baseline: 3.5603x; 1.5584x over previous
//
#include <hip/hip_runtime.h>
#include <hip/hip_bf16.h>
#include <math.h>

#define Bn 2
#define Ln 4096
#define Dn 1024
#define Hn 4
#define DKn 256
#define DVn 256
#define NCHn 128  // L/32 chunks

typedef __attribute__((ext_vector_type(8))) short short8;
typedef __attribute__((ext_vector_type(4))) float f32x4;

__device__ __forceinline__ float sigmoidf_(float x) { return 1.f / (1.f + __expf(-x)); }

__device__ __forceinline__ unsigned short f2bf(float f) {
  union { float f; unsigned u; } v; v.f = f;
  unsigned r = v.u + 0x7FFFu + ((v.u >> 16) & 1u);
  return (unsigned short)(r >> 16);
}

__device__ __forceinline__ unsigned cvt_pk_bf16(float a, float b) {
  unsigned r;
  asm volatile("v_cvt_pk_bf16_f32 %0, %1, %2" : "=v"(r) : "v"(a), "v"(b));
  return r;
}

__device__ __forceinline__ void gl2lds16(const void* g, void* l) {
  __builtin_amdgcn_global_load_lds((const __attribute__((address_space(1))) unsigned int*)g,
                                   (__attribute__((address_space(3))) unsigned int*)l, 16, 0, 0);
}

// ---------------------------------------------------------------------------
// Weight transpose + bf16 convert: Wt[n][k] = bf16(W[k][n]), K=N=1024.
// ---------------------------------------------------------------------------
__global__ __launch_bounds__(256) void wt_kernel(const float* __restrict__ W,
                                                 unsigned short* __restrict__ Wt,
                                                 int K, int N) {
  __shared__ float tile[32][33];
  const int bx = blockIdx.x * 32;  // n
  const int by = blockIdx.y * 32;  // k
  const int tx = threadIdx.x & 31, ty4 = (threadIdx.x >> 5) * 4;
#pragma unroll
  for (int r = 0; r < 4; ++r)
    tile[ty4 + r][tx] = W[(size_t)(by + ty4 + r) * N + bx + tx];
  __syncthreads();
#pragma unroll
  for (int r = 0; r < 4; ++r)
    Wt[(size_t)(bx + ty4 + r) * K + by + tx] = f2bf(tile[tx][ty4 + r]);
}

// ---------------------------------------------------------------------------
// fp32 -> bf16 elementwise, n % 1024 == 0
// ---------------------------------------------------------------------------
__global__ __launch_bounds__(256) void f2bf_kernel(const float* __restrict__ in,
                                                   unsigned short* __restrict__ out,
                                                   int n) {
  const int i4 = (blockIdx.x * 256 + threadIdx.x) * 4;
  if (i4 >= n) return;
  const float4 v = *(const float4*)&in[i4];
  ushort4 o;
  o.x = f2bf(v.x); o.y = f2bf(v.y); o.z = f2bf(v.z); o.w = f2bf(v.w);
  *(ushort4*)&out[i4] = o;
}

// ---------------------------------------------------------------------------
// bf16 MFMA GEMM: C[M,N] f32 = A[M,K]bf16 @ Bt[N,K]bf16^T. 128x128 tile, BK=32.
// ---------------------------------------------------------------------------
__global__ __launch_bounds__(256, 2) void gemm_bf16(const unsigned short* __restrict__ A,
                                                    const unsigned short* __restrict__ Bt,
                                                    float* __restrict__ C,
                                                    int M, int N, int K) {
  __shared__ __align__(16) unsigned short As[128 * 32];
  __shared__ __align__(16) unsigned short Bs[128 * 32];
  const int tid = threadIdx.x;
  const int wid = tid >> 6, lane = tid & 63;
  const int row0 = blockIdx.y * 128, col0 = blockIdx.x * 128;
  const int wr64 = (wid >> 1) * 64, wc64 = (wid & 1) * 64;
  const int fr = lane & 15, fg = lane >> 4;
  f32x4 acc[4][4];
#pragma unroll
  for (int i = 0; i < 4; ++i)
#pragma unroll
    for (int j = 0; j < 4; ++j) acc[i][j] = (f32x4){0.f, 0.f, 0.f, 0.f};
  for (int k0 = 0; k0 < K; k0 += 32) {
#pragma unroll
    for (int i = 0; i < 2; ++i) {
      const int off = wid * 2048 + i * 1024 + (lane << 4);  // LDS byte offset
      const int r = off >> 6;                               // tile row
      const int kb = off & 63;                              // byte within row
      gl2lds16((const char*)A + ((size_t)(row0 + r) * K + k0) * 2 + kb, (char*)As + off);
      gl2lds16((const char*)Bt + ((size_t)(col0 + r) * K + k0) * 2 + kb, (char*)Bs + off);
    }
    __syncthreads();
    short8 a[4], b[4];
#pragma unroll
    for (int mi = 0; mi < 4; ++mi)
      a[mi] = *(const short8*)&As[(wr64 + mi * 16 + fr) * 32 + fg * 8];
#pragma unroll
    for (int ni = 0; ni < 4; ++ni)
      b[ni] = *(const short8*)&Bs[(wc64 + ni * 16 + fr) * 32 + fg * 8];
#pragma unroll
    for (int mi = 0; mi < 4; ++mi)
#pragma unroll
      for (int ni = 0; ni < 4; ++ni)
        acc[mi][ni] = __builtin_amdgcn_mfma_f32_16x16x32_bf16(a[mi], b[ni], acc[mi][ni], 0, 0, 0);
    __syncthreads();
  }
#pragma unroll
  for (int mi = 0; mi < 4; ++mi) {
    const int orow = row0 + wr64 + mi * 16 + fg * 4;
#pragma unroll
    for (int ni = 0; ni < 4; ++ni) {
      const int ocol = col0 + wc64 + ni * 16 + fr;
#pragma unroll
      for (int r = 0; r < 4; ++r)
        C[(size_t)(orow + r) * N + ocol] = acc[mi][ni][r];
    }
  }
}

// ---------------------------------------------------------------------------
// Gate projections (unchanged)
// ---------------------------------------------------------------------------
__global__ __launch_bounds__(256) void gates_kernel(
    const float* __restrict__ x, const float* __restrict__ Wb,
    const float* __restrict__ Wg, const float* __restrict__ bg,
    const float* __restrict__ Wl, const float* __restrict__ bl,
    const float* __restrict__ log_temp, float* __restrict__ beta,
    float* __restrict__ wgl, float* __restrict__ pmix) {
  const int wave = threadIdx.x >> 6, lane = threadIdx.x & 63;
  const int row = (blockIdx.x << 2) + wave;
  if (row >= Bn * Ln) return;
  const float* xr = x + (size_t)row * Dn;
  float acc[20];
#pragma unroll
  for (int c = 0; c < 20; ++c) acc[c] = 0.f;
#pragma unroll
  for (int i = 0; i < 4; ++i) {
    const float4 xv = *(const float4*)&xr[(lane << 2) + (i << 8)];
    const float xa[4] = {xv.x, xv.y, xv.z, xv.w};
#pragma unroll
    for (int j = 0; j < 4; ++j) {
      const int kk = (i << 8) + (lane << 2) + j;
      const float xx = xa[j];
#pragma unroll
      for (int h = 0; h < 4; ++h) acc[h] = fmaf(xx, Wb[kk * 4 + h], acc[h]);
#pragma unroll
      for (int h = 0; h < 4; ++h) acc[4 + h] = fmaf(xx, Wg[kk * 4 + h], acc[4 + h]);
#pragma unroll
      for (int c = 0; c < 12; ++c) acc[8 + c] = fmaf(xx, Wl[kk * 12 + c], acc[8 + c]);
    }
  }
#pragma unroll
  for (int c = 0; c < 20; ++c)
    for (int off = 32; off; off >>= 1) acc[c] += __shfl_down(acc[c], off);
  if (lane == 0) {
    const int b = row >> 12, l = row & (Ln - 1);
#pragma unroll
    for (int h = 0; h < 4; ++h)
      beta[((size_t)(b * Hn + h) << 12) + l] = sigmoidf_(acc[h]);
#pragma unroll
    for (int h = 0; h < 4; ++h) wgl[row * 4 + h] = sigmoidf_(acc[4 + h] + bg[h]);
#pragma unroll
    for (int h = 0; h < 4; ++h) {
      const float it = 1.f / __expf(log_temp[h]);
      const float l0 = (acc[8 + h * 3 + 0] + bl[h * 3 + 0]) * it;
      const float l1 = (acc[8 + h * 3 + 1] + bl[h * 3 + 1]) * it;
      const float l2 = (acc[8 + h * 3 + 2] + bl[h * 3 + 2]) * it;
      const float mx = fmaxf(l0, fmaxf(l1, l2));
      const float e0 = __expf(l0 - mx), e1 = __expf(l1 - mx), e2 = __expf(l2 - mx);
      const float is = 1.f / (e0 + e1 + e2);
      pmix[row * 12 + h * 3 + 0] = e0 * is;
      pmix[row * 12 + h * 3 + 1] = e1 * is;
      pmix[row * 12 + h * 3 + 2] = e2 * is;
    }
  }
}

// ---------------------------------------------------------------------------
// Causal depthwise conv (K=4) + SiLU (+ optional l2norm). (unchanged)
// ---------------------------------------------------------------------------
template <int DO_L2>
__global__ __launch_bounds__(256) void conv_act_kernel(
    const float* __restrict__ raw, const float* __restrict__ cw,
    float* __restrict__ out) {
  const int blk = blockIdx.x;
  const int b = blk >> 12, l = blk & (Ln - 1);
  const int t = threadIdx.x;
  float vals[4];
#pragma unroll
  for (int g = 0; g < 4; ++g) {
    const int c = (g << 8) + t;
    float a = 0.f;
#pragma unroll
    for (int j = 0; j < 4; ++j) {
      const int ls = l - 3 + j;
      if (ls >= 0) a = fmaf(cw[c * 4 + j], raw[(((size_t)b << 12) + ls) * 1024 + c], a);
    }
    vals[g] = a * sigmoidf_(a);
  }
  if (DO_L2) {
    __shared__ float red[4][4];
    float ss[4];
#pragma unroll
    for (int g = 0; g < 4; ++g) ss[g] = vals[g] * vals[g];
#pragma unroll
    for (int g = 0; g < 4; ++g)
      for (int off = 32; off; off >>= 1) ss[g] += __shfl_down(ss[g], off);
    const int wave = t >> 6, lane = t & 63;
    if (lane == 0) {
#pragma unroll
      for (int g = 0; g < 4; ++g) red[wave][g] = ss[g];
    }
    __syncthreads();
#pragma unroll
    for (int g = 0; g < 4; ++g) {
      const float s = red[0][g] + red[1][g] + red[2][g] + red[3][g];
      vals[g] *= rsqrtf(s + 1e-6f);
    }
  }
#pragma unroll
  for (int g = 0; g < 4; ++g)
    out[((((size_t)(b * Hn + g)) << 12) + l) * 256 + t] = vals[g];
}

// ---------------------------------------------------------------------------
// Per-chunk precompute. Now emits MFMA-fragment-ready global layouts:
//  wfrag/qfrag: [cid][mi2*kw8=16 units][lane64][8] bf16  (A-frags of w,q)
//  ktfrag:     [cid][mi16][lane64][8] bf16              (A-frags of k^T)
//  afrag:      [cid][mi2][lane64][8] bf16               (A-frags of attn)
//  u0frag:     [cid][dvs16*mi2=32 units][lane64][4] f32 (C-frag order)
// ---------------------------------------------------------------------------
__global__ __launch_bounds__(256) void precomp_kernel(
    const float* __restrict__ q, const float* __restrict__ k,
    const float* __restrict__ v, const float* __restrict__ beta,
    unsigned short* __restrict__ wfrag, unsigned short* __restrict__ qfrag,
    unsigned short* __restrict__ ktfrag, unsigned short* __restrict__ afrag,
    float* __restrict__ u0frag) {
  const int blk = blockIdx.x;
  const int n = blk & 127, bh = blk >> 7;
  const size_t base = (((size_t)bh << 12) + (n << 5)) * 256;
  const size_t cid = (size_t)(bh * NCHn + n);
  __shared__ __align__(16) float qs[32][260];
  __shared__ __align__(16) float ks[32][260];
  __shared__ __align__(16) float vb[32][260];   // v*beta; later reused for w
  __shared__ __align__(16) float u0l[32][260];
  __shared__ float Am[32][33], Tm[32][33], bet[32];
  __shared__ __align__(16) float attn_l[32][36];
  const int t = threadIdx.x;
  if (t < 32) bet[t] = beta[((size_t)bh << 12) + (n << 5) + t];
  __syncthreads();
  for (int idx = t; idx < 32 * 64; idx += 256) {
    const int r = idx >> 6, fi = (idx & 63) << 2;
    *(float4*)&qs[r][fi] = *(const float4*)&q[base + r * 256 + fi];
    *(float4*)&ks[r][fi] = *(const float4*)&k[base + r * 256 + fi];
    float4 vv = *(const float4*)&v[base + r * 256 + fi];
    const float bm = bet[r];
    vv.x *= bm; vv.y *= bm; vv.z *= bm; vv.w *= bm;
    *(float4*)&vb[r][fi] = vv;
  }
  __syncthreads();
  {
    const int i = t >> 3, j0 = t & 7;
    float dq[4] = {0.f, 0.f, 0.f, 0.f}, dk2[4] = {0.f, 0.f, 0.f, 0.f};
    for (int d = 0; d < 256; d += 4) {
      const float4 qi = *(const float4*)&qs[i][d];
      const float4 ki = *(const float4*)&ks[i][d];
#pragma unroll
      for (int jj = 0; jj < 4; ++jj) {
        const float4 kj = *(const float4*)&ks[j0 + (jj << 3)][d];
        dq[jj] = fmaf(qi.x, kj.x, dq[jj]);
        dq[jj] = fmaf(qi.y, kj.y, dq[jj]);
        dq[jj] = fmaf(qi.z, kj.z, dq[jj]);
        dq[jj] = fmaf(qi.w, kj.w, dq[jj]);
        dk2[jj] = fmaf(ki.x, kj.x, dk2[jj]);
        dk2[jj] = fmaf(ki.y, kj.y, dk2[jj]);
        dk2[jj] = fmaf(ki.z, kj.z, dk2[jj]);
        dk2[jj] = fmaf(ki.w, kj.w, dk2[jj]);
      }
    }
    const float bi = bet[i];
#pragma unroll
    for (int jj = 0; jj < 4; ++jj) {
      const int j = j0 + (jj << 3);
      Am[i][j] = bi * dk2[jj];
      attn_l[i][j] = (j <= i) ? dq[jj] : 0.f;
    }
  }
  for (int idx = t; idx < 1024; idx += 256)
    Tm[idx >> 5][idx & 31] = ((idx >> 5) == (idx & 31)) ? 1.f : 0.f;
  __syncthreads();
  for (int i = 1; i < 32; ++i) {
    if (t < 32) {
      float s = 0.f;
      for (int m = 0; m < i; ++m) s = fmaf(Am[i][m], Tm[m][t], s);
      Tm[i][t] = ((i == t) ? 1.f : 0.f) - s;
    }
    __syncthreads();
  }
  {
    const int i = t >> 3;
    const int dj = (t & 7) << 2;
    float4 ua[8], wa[8];
#pragma unroll
    for (int s = 0; s < 8; ++s) {
      ua[s] = make_float4(0.f, 0.f, 0.f, 0.f);
      wa[s] = make_float4(0.f, 0.f, 0.f, 0.f);
    }
    for (int m = 0; m < 32; ++m) {
      const float tim = Tm[i][m];
      const float t2m = tim * bet[m];
#pragma unroll
      for (int s = 0; s < 8; ++s) {
        const int d = dj + (s << 5);
        const float4 vv = *(const float4*)&vb[m][d];
        const float4 kk = *(const float4*)&ks[m][d];
        ua[s].x = fmaf(tim, vv.x, ua[s].x);
        ua[s].y = fmaf(tim, vv.y, ua[s].y);
        ua[s].z = fmaf(tim, vv.z, ua[s].z);
        ua[s].w = fmaf(tim, vv.w, ua[s].w);
        wa[s].x = fmaf(t2m, kk.x, wa[s].x);
        wa[s].y = fmaf(t2m, kk.y, wa[s].y);
        wa[s].z = fmaf(t2m, kk.z, wa[s].z);
        wa[s].w = fmaf(t2m, kk.w, wa[s].w);
      }
    }
    __syncthreads();  // all reads of vb done before overwrite
#pragma unroll
    for (int s = 0; s < 8; ++s) {
      const int d = dj + (s << 5);
      *(float4*)&u0l[i][d] = ua[s];
      *(float4*)&vb[i][d] = wa[s];   // vb now holds w
    }
  }
  __syncthreads();
  // ---- gather-writes to fragment-ready global layouts ----
  const int lane = t & 63;
  const int fg = (lane >> 4) & 3;
  // wfrag / qfrag: 16 units = mi(2) x kw(8)
#pragma unroll
  for (int it = 0; it < 4; ++it) {
    const int u = it * 4 + (t >> 6);
    const int mi = u >> 3, kw = u & 7;
    const int c = mi * 16 + (lane & 15);
    const int dk0 = kw * 32 + fg * 8;
    const float4 a = *(const float4*)&vb[c][dk0];
    const float4 b2 = *(const float4*)&vb[c][dk0 + 4];
    int4 o;
    o.x = f2bf(a.x) | ((unsigned)f2bf(a.y) << 16);
    o.y = f2bf(a.z) | ((unsigned)f2bf(a.w) << 16);
    o.z = f2bf(b2.x) | ((unsigned)f2bf(b2.y) << 16);
    o.w = f2bf(b2.z) | ((unsigned)f2bf(b2.w) << 16);
    *(int4*)&wfrag[cid * 8192 + u * 512 + lane * 8] = o;
    const float4 qa = *(const float4*)&qs[c][dk0];
    const float4 qb = *(const float4*)&qs[c][dk0 + 4];
    int4 oq;
    oq.x = f2bf(qa.x) | ((unsigned)f2bf(qa.y) << 16);
    oq.y = f2bf(qa.z) | ((unsigned)f2bf(qa.w) << 16);
    oq.z = f2bf(qb.x) | ((unsigned)f2bf(qb.y) << 16);
    oq.w = f2bf(qb.z) | ((unsigned)f2bf(qb.w) << 16);
    *(int4*)&qfrag[cid * 8192 + u * 512 + lane * 8] = oq;
  }
  // ktfrag: 16 units = mi(16); value = k[c = fg*8+j][dk = mi*16 + fr]
#pragma unroll
  for (int it = 0; it < 4; ++it) {
    const int mi = it * 4 + (t >> 6);
    const int dk = mi * 16 + (lane & 15);
    const int c0 = fg * 8;
    unsigned short e[8];
#pragma unroll
    for (int j = 0; j < 8; ++j) e[j] = f2bf(ks[c0 + j][dk]);
    int4 o;
    o.x = e[0] | ((unsigned)e[1] << 16);
    o.y = e[2] | ((unsigned)e[3] << 16);
    o.z = e[4] | ((unsigned)e[5] << 16);
    o.w = e[6] | ((unsigned)e[7] << 16);
    *(int4*)&ktfrag[cid * 8192 + mi * 512 + lane * 8] = o;
  }
  // afrag: 2 units = mi(2); value = attn[c = mi*16+fr][c' = fg*8+j]
  if (t < 128) {
    const int mi = t >> 6;
    const int c = mi * 16 + (lane & 15);
    const int c0 = fg * 8;
    const float4 a = *(const float4*)&attn_l[c][c0];
    const float4 b2 = *(const float4*)&attn_l[c][c0 + 4];
    int4 o;
    o.x = f2bf(a.x) | ((unsigned)f2bf(a.y) << 16);
    o.y = f2bf(a.z) | ((unsigned)f2bf(a.w) << 16);
    o.z = f2bf(b2.x) | ((unsigned)f2bf(b2.y) << 16);
    o.w = f2bf(b2.z) | ((unsigned)f2bf(b2.w) << 16);
    *(int4*)&afrag[cid * 1024 + mi * 512 + lane * 8] = o;
  }
  // u0frag: 32 units = dvs(16) x mi(2); f32 C-frag order
#pragma unroll
  for (int it = 0; it < 8; ++it) {
    const int u = it * 4 + (t >> 6);
    const int dvs = u >> 1, mi = u & 1;
    const int c0 = mi * 16 + fg * 4;
    const int dv = dvs * 16 + (lane & 15);
    float4 o;
    o.x = u0l[c0 + 0][dv];
    o.y = u0l[c0 + 1][dv];
    o.z = u0l[c0 + 2][dv];
    o.w = u0l[c0 + 3][dv];
    *(float4*)&u0frag[cid * 8192 + u * 256 + lane * 4] = o;
  }
}

// ---------------------------------------------------------------------------
// Scan v3: MFMA, 1 wave per block. grid = 128 = 8 bh (XCD-affine) x 16 dv16.
// S[256 dk, 16 dv] lives in 16 f32x4 accumulators. Per chunk: 50 MFMA.
// Double-buffered global_load_lds staging of frag-ready operands.
// ---------------------------------------------------------------------------
__global__ __launch_bounds__(64) void scan_mfma(
    const unsigned short* __restrict__ wfrag, const unsigned short* __restrict__ qfrag,
    const unsigned short* __restrict__ ktfrag, const unsigned short* __restrict__ afrag,
    const float* __restrict__ u0frag, float* __restrict__ dout) {
  const int bh = blockIdx.x & 7;
  const int dvs = blockIdx.x >> 3;
  const int lane = threadIdx.x;
  const int fr = lane & 15, fg = lane >> 4;
  const int swz = (fr & 7) << 4;
  __shared__ __align__(16) unsigned short wf[2][8192];
  __shared__ __align__(16) unsigned short qf[2][8192];
  __shared__ __align__(16) unsigned short ktf[2][8192];
  __shared__ __align__(16) unsigned short af[2][1024];
  __shared__ __align__(16) float u0f[2][512];
  __shared__ __align__(16) unsigned short St[4096];  // [dv16][dk256] bf16, XOR-swz
  __shared__ __align__(16) unsigned short ut[512];   // [dv16][c32] bf16, XOR-swz
  f32x4 S[16];
#pragma unroll
  for (int i = 0; i < 16; ++i) S[i] = (f32x4){0.f, 0.f, 0.f, 0.f};

  // prologue: stage chunk 0 into buf 0
  {
    const size_t fb = (size_t)(bh * NCHn);
    const char* wsrc = (const char*)(wfrag + fb * 8192);
    const char* qsrc = (const char*)(qfrag + fb * 8192);
    const char* ksrc = (const char*)(ktfrag + fb * 8192);
    const char* asrc = (const char*)(afrag + fb * 1024);
    const char* usrc = (const char*)(u0frag + fb * 8192 + dvs * 512);
#pragma unroll
    for (int u = 0; u < 16; ++u) {
      gl2lds16(wsrc + u * 1024 + lane * 16, (char*)wf[0] + u * 1024 + lane * 16);
      gl2lds16(qsrc + u * 1024 + lane * 16, (char*)qf[0] + u * 1024 + lane * 16);
      gl2lds16(ksrc + u * 1024 + lane * 16, (char*)ktf[0] + u * 1024 + lane * 16);
    }
#pragma unroll
    for (int u = 0; u < 2; ++u) {
      gl2lds16(asrc + u * 1024 + lane * 16, (char*)af[0] + u * 1024 + lane * 16);
      gl2lds16(usrc + u * 1024 + lane * 16, (char*)u0f[0] + u * 1024 + lane * 16);
    }
  }

  for (int n = 0; n < NCHn; ++n) {
    const int cur = n & 1;
    // pack S -> St  (St[dv=fr][dk], byte addr (fr*512 + dk*2) ^ swz)
#pragma unroll
    for (int mi = 0; mi < 16; ++mi) {
      const int dk0 = mi * 16 + fg * 4;
      const unsigned w0 = cvt_pk_bf16(S[mi][0], S[mi][1]);
      const unsigned w1 = cvt_pk_bf16(S[mi][2], S[mi][3]);
      const int a = (fr * 512 + dk0 * 2) ^ swz;
      *(uint2*)((char*)St + a) = make_uint2(w0, w1);
    }
    __syncthreads();  // bar1: St visible; staged buf[cur] drained (vmcnt)

    short8 sb[8];
#pragma unroll
    for (int kw = 0; kw < 8; ++kw) {
      const int a = (fr * 512 + kw * 64 + fg * 16) ^ swz;
      sb[kw] = *(const short8*)((const char*)St + a);
    }
    f32x4 up[2], oq[2];
    up[0] = up[1] = (f32x4){0.f, 0.f, 0.f, 0.f};
    oq[0] = oq[1] = (f32x4){0.f, 0.f, 0.f, 0.f};
#pragma unroll
    for (int kw = 0; kw < 8; ++kw) {
#pragma unroll
      for (int mi = 0; mi < 2; ++mi) {
        const short8 aw = *(const short8*)&wf[cur][(mi * 8 + kw) * 512 + lane * 8];
        up[mi] = __builtin_amdgcn_mfma_f32_16x16x32_bf16(aw, sb[kw], up[mi], 0, 0, 0);
        const short8 aq = *(const short8*)&qf[cur][(mi * 8 + kw) * 512 + lane * 8];
        oq[mi] = __builtin_amdgcn_mfma_f32_16x16x32_bf16(aq, sb[kw], oq[mi], 0, 0, 0);
      }
    }
    // u = u0 - w@S ; pack to ut
#pragma unroll
    for (int mi = 0; mi < 2; ++mi) {
      const f32x4 u0v = *(const f32x4*)&u0f[cur][mi * 256 + lane * 4];
      const f32x4 uu = u0v - up[mi];
      const unsigned w0 = cvt_pk_bf16(uu[0], uu[1]);
      const unsigned w1 = cvt_pk_bf16(uu[2], uu[3]);
      const int c0 = mi * 16 + fg * 4;
      const int a = (fr * 64 + c0 * 2) ^ swz;
      *(uint2*)((char*)ut + a) = make_uint2(w0, w1);
    }
    __syncthreads();  // bar2: ut visible
    const short8 ub = *(const short8*)((const char*)ut + ((fr * 64 + fg * 16) ^ swz));
    // o = q@S + attn@u
#pragma unroll
    for (int mi = 0; mi < 2; ++mi) {
      const short8 aa = *(const short8*)&af[cur][mi * 512 + lane * 8];
      oq[mi] = __builtin_amdgcn_mfma_f32_16x16x32_bf16(aa, ub, oq[mi], 0, 0, 0);
    }
    // prefetch chunk n+1 into the other buffer (before the k^T@u cluster)
    if (n + 1 < NCHn) {
      const int nx = cur ^ 1;
      const size_t fb = (size_t)(bh * NCHn + n + 1);
      const char* wsrc = (const char*)(wfrag + fb * 8192);
      const char* qsrc = (const char*)(qfrag + fb * 8192);
      const char* ksrc = (const char*)(ktfrag + fb * 8192);
      const char* asrc = (const char*)(afrag + fb * 1024);
      const char* usrc = (const char*)(u0frag + fb * 8192 + dvs * 512);
#pragma unroll
      for (int u = 0; u < 16; ++u) {
        gl2lds16(wsrc + u * 1024 + lane * 16, (char*)wf[nx] + u * 1024 + lane * 16);
        gl2lds16(qsrc + u * 1024 + lane * 16, (char*)qf[nx] + u * 1024 + lane * 16);
        gl2lds16(ksrc + u * 1024 + lane * 16, (char*)ktf[nx] + u * 1024 + lane * 16);
      }
#pragma unroll
      for (int u = 0; u < 2; ++u) {
        gl2lds16(asrc + u * 1024 + lane * 16, (char*)af[nx] + u * 1024 + lane * 16);
        gl2lds16(usrc + u * 1024 + lane * 16, (char*)u0f[nx] + u * 1024 + lane * 16);
      }
    }
    // store o
    const size_t cb = ((size_t)((bh << 12) + (n << 5))) * 256;
#pragma unroll
    for (int mi = 0; mi < 2; ++mi)
#pragma unroll
      for (int r = 0; r < 4; ++r)
        dout[cb + (size_t)(mi * 16 + fg * 4 + r) * 256 + dvs * 16 + fr] = oq[mi][r];
    // S += k^T @ u
#pragma unroll
    for (int mi = 0; mi < 16; ++mi) {
      const short8 ak = *(const short8*)&ktf[cur][mi * 512 + lane * 8];
      S[mi] = __builtin_amdgcn_mfma_f32_16x16x32_bf16(ak, ub, S[mi], 0, 0, 0);
    }
  }
}

// ---------------------------------------------------------------------------
// Mix: streaming FIR along l with register ring buffer. grid = 512.
// ---------------------------------------------------------------------------
#define MIX_LT 64
__global__ __launch_bounds__(256) void mix_kernel(
    const float* __restrict__ v, const float* __restrict__ delta,
    const float* __restrict__ wgl, const float* __restrict__ pmix,
    const float* __restrict__ firs, const float* __restrict__ firl,
    const float* __restrict__ rms_w, unsigned short* __restrict__ out) {
  const int wgid = ((int)blockIdx.x & 7) * 64 + ((int)blockIdx.x >> 3);
  const int b = wgid >> 8;
  const int h = (wgid >> 6) & 3;
  const int lt = wgid & 63;
  const int l0 = lt * MIX_LT;
  const int t = threadIdx.x;
  const int wv = t >> 6, lane = t & 63;
  const float* vcol = v + ((((size_t)(b * Hn + h)) << 12)) * 256 + t;
  const float* dcol = delta + ((((size_t)(b * Hn + h)) << 12)) * 256 + t;
  float fw[31], fs3[3];
#pragma unroll
  for (int j = 0; j < 31; ++j) fw[j] = firl[((h << 8) + t) * 31 + j];
#pragma unroll
  for (int j = 0; j < 3; ++j) fs3[j] = firs[((h << 8) + t) * 3 + j];
  const float rw = rms_w[t];
  float win[31];
#pragma unroll
  for (int j = 0; j < 30; ++j) {
    const int ls = l0 - 30 + j;
    win[j] = (ls >= 0) ? vcol[(size_t)ls * 256] : 0.f;
  }
  win[30] = 0.f;
  __shared__ float wred[MIX_LT * 4];
  float o[MIX_LT];
#pragma unroll
  for (int i = 0; i < MIX_LT; ++i) {
    const int l = l0 + i;
    const float vnew = vcol[(size_t)l * 256];
    float lo = fw[30] * vnew;
#pragma unroll
    for (int j = 0; j < 30; ++j) lo = fmaf(fw[j], win[(i + j) % 31], lo);
    float sh = fs3[2] * vnew;
    sh = fmaf(fs3[1], win[(i + 29) % 31], sh);
    sh = fmaf(fs3[0], win[(i + 28) % 31], sh);
    win[(i + 30) % 31] = vnew;
    const int row = (b << 12) + l;
    const float p0 = pmix[row * 12 + h * 3 + 0];
    const float p1 = pmix[row * 12 + h * 3 + 1];
    const float p2 = pmix[row * 12 + h * 3 + 2];
    const float wg = wgl[row * 4 + h];
    const float mixv = p0 * vnew + p1 * sh + p2 * lo;
    const float oo = wg * dcol[(size_t)l * 256] + (1.f - wg) * mixv;
    o[i] = oo;
    float ss = oo * oo;
#pragma unroll
    for (int m = 1; m < 64; m <<= 1) ss += __shfl_xor(ss, m);
    if (lane == 0) wred[i * 4 + wv] = ss;
  }
  __syncthreads();
#pragma unroll
  for (int i = 0; i < MIX_LT; ++i) {
    const float sum = wred[i * 4] + wred[i * 4 + 1] + wred[i * 4 + 2] + wred[i * 4 + 3];
    const float sc = rsqrtf(sum * (1.f / 256.f) + 1e-5f);
    const int l = l0 + i;
    out[(size_t)((b << 12) + l) * 1024 + (h << 8) + t] = f2bf(o[i] * sc * rw);
  }
}

// ---------------------------------------------------------------------------
extern "C" void kernel_launch(void* const* d_in, const int* in_sizes, int n_in,
                              void* d_out, int out_size, void* d_ws, size_t ws_size,
                              hipStream_t stream) {
  const float* x = (const float*)d_in[0];
  const float* Wq = (const float*)d_in[1];
  const float* Wk = (const float*)d_in[2];
  const float* Wv = (const float*)d_in[3];
  const float* cq = (const float*)d_in[4];
  const float* ck = (const float*)d_in[5];
  const float* cv = (const float*)d_in[6];
  const float* Wb = (const float*)d_in[7];
  const float* firs = (const float*)d_in[8];
  const float* firl = (const float*)d_in[9];
  const float* Wg = (const float*)d_in[10];
  const float* bg = (const float*)d_in[11];
  const float* Wl = (const float*)d_in[12];
  const float* bl = (const float*)d_in[13];
  const float* ltemp = (const float*)d_in[14];
  const float* rmsw = (const float*)d_in[15];
  const float* Wo = (const float*)d_in[16];

  float* ws = (float*)d_ws;
  const size_t NE = (size_t)Bn * Ln * 1024;  // 8.39M floats
  float* qraw = ws;
  float* kraw = ws + NE;
  float* vraw = ws + 2 * NE;
  float* qn = ws + 3 * NE;
  float* kn = ws + 4 * NE;
  float* vn = ws + 5 * NE;
  float* beta = ws + 6 * NE;
  float* wgl = beta + (size_t)Bn * Hn * Ln;
  float* pmix = wgl + (size_t)Bn * Ln * Hn;
  float* attn_unused = pmix + (size_t)Bn * Ln * Hn * 3;
  unsigned short* Wot = (unsigned short*)(attn_unused + (size_t)Bn * Hn * NCHn * 1024);
  unsigned short* xb = (unsigned short*)qn;
  unsigned short* Wqt = (unsigned short*)(qn + 4194304);
  unsigned short* Wkt = Wqt + 1048576;
  unsigned short* Wvt = Wkt + 1048576;
  unsigned short* normed_bf = (unsigned short*)kn;  // kn dead after precomp
  // frag buffers (overlay dead regions):
  unsigned short* wfrag = (unsigned short*)qraw;    // 16.78 MB
  unsigned short* qfrag = wfrag + 8388608;          // 16.78 MB (qraw = 33.55 MB total)
  unsigned short* ktfrag = (unsigned short*)kraw;   // 16.78 MB
  unsigned short* afrag = ktfrag + 8388608;         // 2.1 MB
  float* u0frag = qn;   // exact per-chunk slot overlay of qn (read-before-write in precomp)
  float* dbuf = vraw;

  const dim3 wtg(32, 32);
  wt_kernel<<<wtg, 256, 0, stream>>>(Wq, Wqt, 1024, 1024);
  wt_kernel<<<wtg, 256, 0, stream>>>(Wk, Wkt, 1024, 1024);
  wt_kernel<<<wtg, 256, 0, stream>>>(Wv, Wvt, 1024, 1024);
  wt_kernel<<<wtg, 256, 0, stream>>>(Wo, Wot, 1024, 1024);
  f2bf_kernel<<<(int)(NE / 1024), 256, 0, stream>>>(x, xb, (int)NE);

  const dim3 gg(8, 64);  // N/128, M/128
  gemm_bf16<<<gg, 256, 0, stream>>>(xb, Wqt, qraw, Bn * Ln, 1024, 1024);
  gemm_bf16<<<gg, 256, 0, stream>>>(xb, Wkt, kraw, Bn * Ln, 1024, 1024);
  gemm_bf16<<<gg, 256, 0, stream>>>(xb, Wvt, vraw, Bn * Ln, 1024, 1024);
  gates_kernel<<<Bn * Ln / 4, 256, 0, stream>>>(x, Wb, Wg, bg, Wl, bl, ltemp,
                                                beta, wgl, pmix);
  conv_act_kernel<1><<<Bn * Ln, 256, 0, stream>>>(qraw, cq, qn);
  conv_act_kernel<1><<<Bn * Ln, 256, 0, stream>>>(kraw, ck, kn);
  conv_act_kernel<0><<<Bn * Ln, 256, 0, stream>>>(vraw, cv, vn);
  precomp_kernel<<<Bn * Hn * NCHn, 256, 0, stream>>>(qn, kn, vn, beta, wfrag,
                                                     qfrag, ktfrag, afrag, u0frag);
  scan_mfma<<<128, 64, 0, stream>>>(wfrag, qfrag, ktfrag, afrag, u0frag, dbuf);
  mix_kernel<<<Bn * Hn * (Ln / MIX_LT), 256, 0, stream>>>(
      vn, dbuf, wgl, pmix, firs, firl, rmsw, normed_bf);
  gemm_bf16<<<gg, 256, 0, stream>>>(normed_bf, Wot, (float*)d_out, Bn * Ln, 1024, 1024);
}

// Round 6
// 805.420 us; speedup vs baseline: 3.9179x; 1.1004x over previous
//
#include <hip/hip_runtime.h>
#include <hip/hip_bf16.h>
#include <math.h>

#define Bn 2
#define Ln 4096
#define Dn 1024
#define Hn 4
#define DKn 256
#define DVn 256
#define NCHn 128  // L/32 chunks

typedef __attribute__((ext_vector_type(8))) short short8;
typedef __attribute__((ext_vector_type(4))) float f32x4;

__device__ __forceinline__ float sigmoidf_(float x) { return 1.f / (1.f + __expf(-x)); }

__device__ __forceinline__ unsigned short f2bf(float f) {
  union { float f; unsigned u; } v; v.f = f;
  unsigned r = v.u + 0x7FFFu + ((v.u >> 16) & 1u);
  return (unsigned short)(r >> 16);
}

__device__ __forceinline__ unsigned cvt_pk_bf16(float a, float b) {
  unsigned r;
  asm volatile("v_cvt_pk_bf16_f32 %0, %1, %2" : "=v"(r) : "v"(a), "v"(b));
  return r;
}

__device__ __forceinline__ void gl2lds16(const void* g, void* l) {
  __builtin_amdgcn_global_load_lds((const __attribute__((address_space(1))) unsigned int*)g,
                                   (__attribute__((address_space(3))) unsigned int*)l, 16, 0, 0);
}

// ---------------------------------------------------------------------------
// Weight transpose + bf16 convert: Wt[n][k] = bf16(W[k][n]), K=N=1024.
// ---------------------------------------------------------------------------
__global__ __launch_bounds__(256) void wt_kernel(const float* __restrict__ W,
                                                 unsigned short* __restrict__ Wt,
                                                 int K, int N) {
  __shared__ float tile[32][33];
  const int bx = blockIdx.x * 32;  // n
  const int by = blockIdx.y * 32;  // k
  const int tx = threadIdx.x & 31, ty4 = (threadIdx.x >> 5) * 4;
#pragma unroll
  for (int r = 0; r < 4; ++r)
    tile[ty4 + r][tx] = W[(size_t)(by + ty4 + r) * N + bx + tx];
  __syncthreads();
#pragma unroll
  for (int r = 0; r < 4; ++r)
    Wt[(size_t)(bx + ty4 + r) * K + by + tx] = f2bf(tile[tx][ty4 + r]);
}

// ---------------------------------------------------------------------------
// fp32 -> bf16 elementwise, n % 1024 == 0
// ---------------------------------------------------------------------------
__global__ __launch_bounds__(256) void f2bf_kernel(const float* __restrict__ in,
                                                   unsigned short* __restrict__ out,
                                                   int n) {
  const int i4 = (blockIdx.x * 256 + threadIdx.x) * 4;
  if (i4 >= n) return;
  const float4 v = *(const float4*)&in[i4];
  ushort4 o;
  o.x = f2bf(v.x); o.y = f2bf(v.y); o.z = f2bf(v.z); o.w = f2bf(v.w);
  *(ushort4*)&out[i4] = o;
}

// ---------------------------------------------------------------------------
// bf16 MFMA GEMM: C[M,N] f32 = A[M,K]bf16 @ Bt[N,K]bf16^T. 128x128 tile, BK=32.
// ---------------------------------------------------------------------------
__global__ __launch_bounds__(256, 2) void gemm_bf16(const unsigned short* __restrict__ A,
                                                    const unsigned short* __restrict__ Bt,
                                                    float* __restrict__ C,
                                                    int M, int N, int K) {
  __shared__ __align__(16) unsigned short As[128 * 32];
  __shared__ __align__(16) unsigned short Bs[128 * 32];
  const int tid = threadIdx.x;
  const int wid = tid >> 6, lane = tid & 63;
  const int row0 = blockIdx.y * 128, col0 = blockIdx.x * 128;
  const int wr64 = (wid >> 1) * 64, wc64 = (wid & 1) * 64;
  const int fr = lane & 15, fg = lane >> 4;
  f32x4 acc[4][4];
#pragma unroll
  for (int i = 0; i < 4; ++i)
#pragma unroll
    for (int j = 0; j < 4; ++j) acc[i][j] = (f32x4){0.f, 0.f, 0.f, 0.f};
  for (int k0 = 0; k0 < K; k0 += 32) {
#pragma unroll
    for (int i = 0; i < 2; ++i) {
      const int off = wid * 2048 + i * 1024 + (lane << 4);  // LDS byte offset
      const int r = off >> 6;                               // tile row
      const int kb = off & 63;                              // byte within row
      gl2lds16((const char*)A + ((size_t)(row0 + r) * K + k0) * 2 + kb, (char*)As + off);
      gl2lds16((const char*)Bt + ((size_t)(col0 + r) * K + k0) * 2 + kb, (char*)Bs + off);
    }
    __syncthreads();
    short8 a[4], b[4];
#pragma unroll
    for (int mi = 0; mi < 4; ++mi)
      a[mi] = *(const short8*)&As[(wr64 + mi * 16 + fr) * 32 + fg * 8];
#pragma unroll
    for (int ni = 0; ni < 4; ++ni)
      b[ni] = *(const short8*)&Bs[(wc64 + ni * 16 + fr) * 32 + fg * 8];
#pragma unroll
    for (int mi = 0; mi < 4; ++mi)
#pragma unroll
      for (int ni = 0; ni < 4; ++ni)
        acc[mi][ni] = __builtin_amdgcn_mfma_f32_16x16x32_bf16(a[mi], b[ni], acc[mi][ni], 0, 0, 0);
    __syncthreads();
  }
#pragma unroll
  for (int mi = 0; mi < 4; ++mi) {
    const int orow = row0 + wr64 + mi * 16 + fg * 4;
#pragma unroll
    for (int ni = 0; ni < 4; ++ni) {
      const int ocol = col0 + wc64 + ni * 16 + fr;
#pragma unroll
      for (int r = 0; r < 4; ++r)
        C[(size_t)(orow + r) * N + ocol] = acc[mi][ni][r];
    }
  }
}

// ---------------------------------------------------------------------------
// Gate projections (unchanged)
// ---------------------------------------------------------------------------
__global__ __launch_bounds__(256) void gates_kernel(
    const float* __restrict__ x, const float* __restrict__ Wb,
    const float* __restrict__ Wg, const float* __restrict__ bg,
    const float* __restrict__ Wl, const float* __restrict__ bl,
    const float* __restrict__ log_temp, float* __restrict__ beta,
    float* __restrict__ wgl, float* __restrict__ pmix) {
  const int wave = threadIdx.x >> 6, lane = threadIdx.x & 63;
  const int row = (blockIdx.x << 2) + wave;
  if (row >= Bn * Ln) return;
  const float* xr = x + (size_t)row * Dn;
  float acc[20];
#pragma unroll
  for (int c = 0; c < 20; ++c) acc[c] = 0.f;
#pragma unroll
  for (int i = 0; i < 4; ++i) {
    const float4 xv = *(const float4*)&xr[(lane << 2) + (i << 8)];
    const float xa[4] = {xv.x, xv.y, xv.z, xv.w};
#pragma unroll
    for (int j = 0; j < 4; ++j) {
      const int kk = (i << 8) + (lane << 2) + j;
      const float xx = xa[j];
#pragma unroll
      for (int h = 0; h < 4; ++h) acc[h] = fmaf(xx, Wb[kk * 4 + h], acc[h]);
#pragma unroll
      for (int h = 0; h < 4; ++h) acc[4 + h] = fmaf(xx, Wg[kk * 4 + h], acc[4 + h]);
#pragma unroll
      for (int c = 0; c < 12; ++c) acc[8 + c] = fmaf(xx, Wl[kk * 12 + c], acc[8 + c]);
    }
  }
#pragma unroll
  for (int c = 0; c < 20; ++c)
    for (int off = 32; off; off >>= 1) acc[c] += __shfl_down(acc[c], off);
  if (lane == 0) {
    const int b = row >> 12, l = row & (Ln - 1);
#pragma unroll
    for (int h = 0; h < 4; ++h)
      beta[((size_t)(b * Hn + h) << 12) + l] = sigmoidf_(acc[h]);
#pragma unroll
    for (int h = 0; h < 4; ++h) wgl[row * 4 + h] = sigmoidf_(acc[4 + h] + bg[h]);
#pragma unroll
    for (int h = 0; h < 4; ++h) {
      const float it = 1.f / __expf(log_temp[h]);
      const float l0 = (acc[8 + h * 3 + 0] + bl[h * 3 + 0]) * it;
      const float l1 = (acc[8 + h * 3 + 1] + bl[h * 3 + 1]) * it;
      const float l2 = (acc[8 + h * 3 + 2] + bl[h * 3 + 2]) * it;
      const float mx = fmaxf(l0, fmaxf(l1, l2));
      const float e0 = __expf(l0 - mx), e1 = __expf(l1 - mx), e2 = __expf(l2 - mx);
      const float is = 1.f / (e0 + e1 + e2);
      pmix[row * 12 + h * 3 + 0] = e0 * is;
      pmix[row * 12 + h * 3 + 1] = e1 * is;
      pmix[row * 12 + h * 3 + 2] = e2 * is;
    }
  }
}

// ---------------------------------------------------------------------------
// Causal depthwise conv (K=4) + SiLU (+ optional l2norm). (unchanged)
// ---------------------------------------------------------------------------
template <int DO_L2>
__global__ __launch_bounds__(256) void conv_act_kernel(
    const float* __restrict__ raw, const float* __restrict__ cw,
    float* __restrict__ out) {
  const int blk = blockIdx.x;
  const int b = blk >> 12, l = blk & (Ln - 1);
  const int t = threadIdx.x;
  float vals[4];
#pragma unroll
  for (int g = 0; g < 4; ++g) {
    const int c = (g << 8) + t;
    float a = 0.f;
#pragma unroll
    for (int j = 0; j < 4; ++j) {
      const int ls = l - 3 + j;
      if (ls >= 0) a = fmaf(cw[c * 4 + j], raw[(((size_t)b << 12) + ls) * 1024 + c], a);
    }
    vals[g] = a * sigmoidf_(a);
  }
  if (DO_L2) {
    __shared__ float red[4][4];
    float ss[4];
#pragma unroll
    for (int g = 0; g < 4; ++g) ss[g] = vals[g] * vals[g];
#pragma unroll
    for (int g = 0; g < 4; ++g)
      for (int off = 32; off; off >>= 1) ss[g] += __shfl_down(ss[g], off);
    const int wave = t >> 6, lane = t & 63;
    if (lane == 0) {
#pragma unroll
      for (int g = 0; g < 4; ++g) red[wave][g] = ss[g];
    }
    __syncthreads();
#pragma unroll
    for (int g = 0; g < 4; ++g) {
      const float s = red[0][g] + red[1][g] + red[2][g] + red[3][g];
      vals[g] *= rsqrtf(s + 1e-6f);
    }
  }
#pragma unroll
  for (int g = 0; g < 4; ++g)
    out[((((size_t)(b * Hn + g)) << 12) + l) * 256 + t] = vals[g];
}

// ---------------------------------------------------------------------------
// Per-chunk precompute (unchanged from round 5: emits frag-ready layouts)
// ---------------------------------------------------------------------------
__global__ __launch_bounds__(256) void precomp_kernel(
    const float* __restrict__ q, const float* __restrict__ k,
    const float* __restrict__ v, const float* __restrict__ beta,
    unsigned short* __restrict__ wfrag, unsigned short* __restrict__ qfrag,
    unsigned short* __restrict__ ktfrag, unsigned short* __restrict__ afrag,
    float* __restrict__ u0frag) {
  const int blk = blockIdx.x;
  const int n = blk & 127, bh = blk >> 7;
  const size_t base = (((size_t)bh << 12) + (n << 5)) * 256;
  const size_t cid = (size_t)(bh * NCHn + n);
  __shared__ __align__(16) float qs[32][260];
  __shared__ __align__(16) float ks[32][260];
  __shared__ __align__(16) float vb[32][260];   // v*beta; later reused for w
  __shared__ __align__(16) float u0l[32][260];
  __shared__ float Am[32][33], Tm[32][33], bet[32];
  __shared__ __align__(16) float attn_l[32][36];
  const int t = threadIdx.x;
  if (t < 32) bet[t] = beta[((size_t)bh << 12) + (n << 5) + t];
  __syncthreads();
  for (int idx = t; idx < 32 * 64; idx += 256) {
    const int r = idx >> 6, fi = (idx & 63) << 2;
    *(float4*)&qs[r][fi] = *(const float4*)&q[base + r * 256 + fi];
    *(float4*)&ks[r][fi] = *(const float4*)&k[base + r * 256 + fi];
    float4 vv = *(const float4*)&v[base + r * 256 + fi];
    const float bm = bet[r];
    vv.x *= bm; vv.y *= bm; vv.z *= bm; vv.w *= bm;
    *(float4*)&vb[r][fi] = vv;
  }
  __syncthreads();
  {
    const int i = t >> 3, j0 = t & 7;
    float dq[4] = {0.f, 0.f, 0.f, 0.f}, dk2[4] = {0.f, 0.f, 0.f, 0.f};
    for (int d = 0; d < 256; d += 4) {
      const float4 qi = *(const float4*)&qs[i][d];
      const float4 ki = *(const float4*)&ks[i][d];
#pragma unroll
      for (int jj = 0; jj < 4; ++jj) {
        const float4 kj = *(const float4*)&ks[j0 + (jj << 3)][d];
        dq[jj] = fmaf(qi.x, kj.x, dq[jj]);
        dq[jj] = fmaf(qi.y, kj.y, dq[jj]);
        dq[jj] = fmaf(qi.z, kj.z, dq[jj]);
        dq[jj] = fmaf(qi.w, kj.w, dq[jj]);
        dk2[jj] = fmaf(ki.x, kj.x, dk2[jj]);
        dk2[jj] = fmaf(ki.y, kj.y, dk2[jj]);
        dk2[jj] = fmaf(ki.z, kj.z, dk2[jj]);
        dk2[jj] = fmaf(ki.w, kj.w, dk2[jj]);
      }
    }
    const float bi = bet[i];
#pragma unroll
    for (int jj = 0; jj < 4; ++jj) {
      const int j = j0 + (jj << 3);
      Am[i][j] = bi * dk2[jj];
      attn_l[i][j] = (j <= i) ? dq[jj] : 0.f;
    }
  }
  for (int idx = t; idx < 1024; idx += 256)
    Tm[idx >> 5][idx & 31] = ((idx >> 5) == (idx & 31)) ? 1.f : 0.f;
  __syncthreads();
  for (int i = 1; i < 32; ++i) {
    if (t < 32) {
      float s = 0.f;
      for (int m = 0; m < i; ++m) s = fmaf(Am[i][m], Tm[m][t], s);
      Tm[i][t] = ((i == t) ? 1.f : 0.f) - s;
    }
    __syncthreads();
  }
  {
    const int i = t >> 3;
    const int dj = (t & 7) << 2;
    float4 ua[8], wa[8];
#pragma unroll
    for (int s = 0; s < 8; ++s) {
      ua[s] = make_float4(0.f, 0.f, 0.f, 0.f);
      wa[s] = make_float4(0.f, 0.f, 0.f, 0.f);
    }
    for (int m = 0; m < 32; ++m) {
      const float tim = Tm[i][m];
      const float t2m = tim * bet[m];
#pragma unroll
      for (int s = 0; s < 8; ++s) {
        const int d = dj + (s << 5);
        const float4 vv = *(const float4*)&vb[m][d];
        const float4 kk = *(const float4*)&ks[m][d];
        ua[s].x = fmaf(tim, vv.x, ua[s].x);
        ua[s].y = fmaf(tim, vv.y, ua[s].y);
        ua[s].z = fmaf(tim, vv.z, ua[s].z);
        ua[s].w = fmaf(tim, vv.w, ua[s].w);
        wa[s].x = fmaf(t2m, kk.x, wa[s].x);
        wa[s].y = fmaf(t2m, kk.y, wa[s].y);
        wa[s].z = fmaf(t2m, kk.z, wa[s].z);
        wa[s].w = fmaf(t2m, kk.w, wa[s].w);
      }
    }
    __syncthreads();  // all reads of vb done before overwrite
#pragma unroll
    for (int s = 0; s < 8; ++s) {
      const int d = dj + (s << 5);
      *(float4*)&u0l[i][d] = ua[s];
      *(float4*)&vb[i][d] = wa[s];   // vb now holds w
    }
  }
  __syncthreads();
  // ---- gather-writes to fragment-ready global layouts ----
  const int lane = t & 63;
  const int fg = (lane >> 4) & 3;
#pragma unroll
  for (int it = 0; it < 4; ++it) {
    const int u = it * 4 + (t >> 6);
    const int mi = u >> 3, kw = u & 7;
    const int c = mi * 16 + (lane & 15);
    const int dk0 = kw * 32 + fg * 8;
    const float4 a = *(const float4*)&vb[c][dk0];
    const float4 b2 = *(const float4*)&vb[c][dk0 + 4];
    int4 o;
    o.x = f2bf(a.x) | ((unsigned)f2bf(a.y) << 16);
    o.y = f2bf(a.z) | ((unsigned)f2bf(a.w) << 16);
    o.z = f2bf(b2.x) | ((unsigned)f2bf(b2.y) << 16);
    o.w = f2bf(b2.z) | ((unsigned)f2bf(b2.w) << 16);
    *(int4*)&wfrag[cid * 8192 + u * 512 + lane * 8] = o;
    const float4 qa = *(const float4*)&qs[c][dk0];
    const float4 qb = *(const float4*)&qs[c][dk0 + 4];
    int4 oq;
    oq.x = f2bf(qa.x) | ((unsigned)f2bf(qa.y) << 16);
    oq.y = f2bf(qa.z) | ((unsigned)f2bf(qa.w) << 16);
    oq.z = f2bf(qb.x) | ((unsigned)f2bf(qb.y) << 16);
    oq.w = f2bf(qb.z) | ((unsigned)f2bf(qb.w) << 16);
    *(int4*)&qfrag[cid * 8192 + u * 512 + lane * 8] = oq;
  }
#pragma unroll
  for (int it = 0; it < 4; ++it) {
    const int mi = it * 4 + (t >> 6);
    const int dk = mi * 16 + (lane & 15);
    const int c0 = fg * 8;
    unsigned short e[8];
#pragma unroll
    for (int j = 0; j < 8; ++j) e[j] = f2bf(ks[c0 + j][dk]);
    int4 o;
    o.x = e[0] | ((unsigned)e[1] << 16);
    o.y = e[2] | ((unsigned)e[3] << 16);
    o.z = e[4] | ((unsigned)e[5] << 16);
    o.w = e[6] | ((unsigned)e[7] << 16);
    *(int4*)&ktfrag[cid * 8192 + mi * 512 + lane * 8] = o;
  }
  if (t < 128) {
    const int mi = t >> 6;
    const int c = mi * 16 + (lane & 15);
    const int c0 = fg * 8;
    const float4 a = *(const float4*)&attn_l[c][c0];
    const float4 b2 = *(const float4*)&attn_l[c][c0 + 4];
    int4 o;
    o.x = f2bf(a.x) | ((unsigned)f2bf(a.y) << 16);
    o.y = f2bf(a.z) | ((unsigned)f2bf(a.w) << 16);
    o.z = f2bf(b2.x) | ((unsigned)f2bf(b2.y) << 16);
    o.w = f2bf(b2.z) | ((unsigned)f2bf(b2.w) << 16);
    *(int4*)&afrag[cid * 1024 + mi * 512 + lane * 8] = o;
  }
#pragma unroll
  for (int it = 0; it < 8; ++it) {
    const int u = it * 4 + (t >> 6);
    const int dvs = u >> 1, mi = u & 1;
    const int c0 = mi * 16 + fg * 4;
    const int dv = dvs * 16 + (lane & 15);
    float4 o;
    o.x = u0l[c0 + 0][dv];
    o.y = u0l[c0 + 1][dv];
    o.z = u0l[c0 + 2][dv];
    o.w = u0l[c0 + 3][dv];
    *(float4*)&u0frag[cid * 8192 + u * 256 + lane * 4] = o;
  }
}

// ---------------------------------------------------------------------------
// Scan v4: single wave, BARRIER-FREE. Counted vmcnt (T4), precise lgkmcnt,
// sched_barrier(0) after each asm wait (rule #18). Split MFMA chains.
// grid = 128 = 8 bh (XCD-affine) x 16 dv16.
// Per-wave VMEM order: [loads(n):52][stores(n-1):8][loads(n+1):52] ≤ 60 live.
// ---------------------------------------------------------------------------
__global__ __launch_bounds__(64) void scan_mfma(
    const unsigned short* __restrict__ wfrag, const unsigned short* __restrict__ qfrag,
    const unsigned short* __restrict__ ktfrag, const unsigned short* __restrict__ afrag,
    const float* __restrict__ u0frag, float* __restrict__ dout) {
  const int bh = blockIdx.x & 7;
  const int dvs = blockIdx.x >> 3;
  const int lane = threadIdx.x;
  const int fr = lane & 15, fg = lane >> 4;
  const int swz = (fr & 7) << 4;
  __shared__ __align__(16) unsigned short wf[2][8192];
  __shared__ __align__(16) unsigned short qf[2][8192];
  __shared__ __align__(16) unsigned short ktf[2][8192];
  __shared__ __align__(16) unsigned short af[2][1024];
  __shared__ __align__(16) float u0f[2][512];
  __shared__ __align__(16) unsigned short St[4096];  // [dv16][dk256] bf16, XOR-swz
  __shared__ __align__(16) unsigned short ut[512];   // [dv16][c32] bf16, XOR-swz
  f32x4 S[16];
#pragma unroll
  for (int i = 0; i < 16; ++i) S[i] = (f32x4){0.f, 0.f, 0.f, 0.f};

  // prologue: stage chunk 0 into buf 0 (52 loads)
  {
    const size_t fb = (size_t)(bh * NCHn);
    const char* wsrc = (const char*)(wfrag + fb * 8192);
    const char* qsrc = (const char*)(qfrag + fb * 8192);
    const char* ksrc = (const char*)(ktfrag + fb * 8192);
    const char* asrc = (const char*)(afrag + fb * 1024);
    const char* usrc = (const char*)(u0frag + fb * 8192 + dvs * 512);
#pragma unroll
    for (int u = 0; u < 16; ++u) {
      gl2lds16(wsrc + u * 1024 + lane * 16, (char*)wf[0] + u * 1024 + lane * 16);
      gl2lds16(qsrc + u * 1024 + lane * 16, (char*)qf[0] + u * 1024 + lane * 16);
      gl2lds16(ksrc + u * 1024 + lane * 16, (char*)ktf[0] + u * 1024 + lane * 16);
    }
#pragma unroll
    for (int u = 0; u < 2; ++u) {
      gl2lds16(asrc + u * 1024 + lane * 16, (char*)af[0] + u * 1024 + lane * 16);
      gl2lds16(usrc + u * 1024 + lane * 16, (char*)u0f[0] + u * 1024 + lane * 16);
    }
  }

  for (int n = 0; n < NCHn; ++n) {
    const int cur = n & 1;
    // pack S -> St  (no hazard with staged bufs)
#pragma unroll
    for (int mi = 0; mi < 16; ++mi) {
      const int dk0 = mi * 16 + fg * 4;
      const unsigned w0 = cvt_pk_bf16(S[mi][0], S[mi][1]);
      const unsigned w1 = cvt_pk_bf16(S[mi][2], S[mi][3]);
      const int a = (fr * 512 + dk0 * 2) ^ swz;
      *(uint2*)((char*)St + a) = make_uint2(w0, w1);
    }
    // wait: chunk-n staged loads retired (stores(n-1) [8 newest] may float);
    // St writes visible (lgkmcnt). No barrier: single wave.
    if (n == 0) {
      asm volatile("s_waitcnt vmcnt(0) lgkmcnt(0)" ::: "memory");
    } else {
      asm volatile("s_waitcnt vmcnt(8) lgkmcnt(0)" ::: "memory");
    }
    __builtin_amdgcn_sched_barrier(0);

    short8 sb[8];
#pragma unroll
    for (int kw = 0; kw < 8; ++kw) {
      const int a = (fr * 512 + kw * 64 + fg * 16) ^ swz;
      sb[kw] = *(const short8*)((const char*)St + a);
    }
    // w@S and q@S with split accumulator chains (depth 4 instead of 8)
    f32x4 upA[2], upB[2], oqA[2], oqB[2];
#pragma unroll
    for (int mi = 0; mi < 2; ++mi) {
      upA[mi] = (f32x4){0.f, 0.f, 0.f, 0.f};
      upB[mi] = (f32x4){0.f, 0.f, 0.f, 0.f};
      oqA[mi] = (f32x4){0.f, 0.f, 0.f, 0.f};
      oqB[mi] = (f32x4){0.f, 0.f, 0.f, 0.f};
    }
#pragma unroll
    for (int kw = 0; kw < 4; ++kw) {
#pragma unroll
      for (int mi = 0; mi < 2; ++mi) {
        const short8 aw = *(const short8*)&wf[cur][(mi * 8 + kw) * 512 + lane * 8];
        upA[mi] = __builtin_amdgcn_mfma_f32_16x16x32_bf16(aw, sb[kw], upA[mi], 0, 0, 0);
        const short8 aq = *(const short8*)&qf[cur][(mi * 8 + kw) * 512 + lane * 8];
        oqA[mi] = __builtin_amdgcn_mfma_f32_16x16x32_bf16(aq, sb[kw], oqA[mi], 0, 0, 0);
      }
    }
#pragma unroll
    for (int kw = 4; kw < 8; ++kw) {
#pragma unroll
      for (int mi = 0; mi < 2; ++mi) {
        const short8 aw = *(const short8*)&wf[cur][(mi * 8 + kw) * 512 + lane * 8];
        upB[mi] = __builtin_amdgcn_mfma_f32_16x16x32_bf16(aw, sb[kw], upB[mi], 0, 0, 0);
        const short8 aq = *(const short8*)&qf[cur][(mi * 8 + kw) * 512 + lane * 8];
        oqB[mi] = __builtin_amdgcn_mfma_f32_16x16x32_bf16(aq, sb[kw], oqB[mi], 0, 0, 0);
      }
    }
    // u = u0 - w@S ; pack to ut
    f32x4 oq[2];
#pragma unroll
    for (int mi = 0; mi < 2; ++mi) {
      oq[mi] = oqA[mi] + oqB[mi];
      const f32x4 u0v = *(const f32x4*)&u0f[cur][mi * 256 + lane * 4];
      const f32x4 uu = u0v - (upA[mi] + upB[mi]);
      const unsigned w0 = cvt_pk_bf16(uu[0], uu[1]);
      const unsigned w1 = cvt_pk_bf16(uu[2], uu[3]);
      const int c0 = mi * 16 + fg * 4;
      const int a = (fr * 64 + c0 * 2) ^ swz;
      *(uint2*)((char*)ut + a) = make_uint2(w0, w1);
    }
    // issue prefetch(n+1) now (overlaps the lgkm drain below; used next chunk)
    if (n + 1 < NCHn) {
      const int nx = cur ^ 1;
      const size_t fb = (size_t)(bh * NCHn + n + 1);
      const char* wsrc = (const char*)(wfrag + fb * 8192);
      const char* qsrc = (const char*)(qfrag + fb * 8192);
      const char* ksrc = (const char*)(ktfrag + fb * 8192);
      const char* asrc = (const char*)(afrag + fb * 1024);
      const char* usrc = (const char*)(u0frag + fb * 8192 + dvs * 512);
#pragma unroll
      for (int u = 0; u < 16; ++u) {
        gl2lds16(wsrc + u * 1024 + lane * 16, (char*)wf[nx] + u * 1024 + lane * 16);
        gl2lds16(qsrc + u * 1024 + lane * 16, (char*)qf[nx] + u * 1024 + lane * 16);
        gl2lds16(ksrc + u * 1024 + lane * 16, (char*)ktf[nx] + u * 1024 + lane * 16);
      }
#pragma unroll
      for (int u = 0; u < 2; ++u) {
        gl2lds16(asrc + u * 1024 + lane * 16, (char*)af[nx] + u * 1024 + lane * 16);
        gl2lds16(usrc + u * 1024 + lane * 16, (char*)u0f[nx] + u * 1024 + lane * 16);
      }
    }
    // ut visible (gl2lds counts in vmcnt, not lgkmcnt — this only drains ds ops)
    asm volatile("s_waitcnt lgkmcnt(0)" ::: "memory");
    __builtin_amdgcn_sched_barrier(0);

    const short8 ub = *(const short8*)((const char*)ut + ((fr * 64 + fg * 16) ^ swz));
    // o = q@S + attn@u
#pragma unroll
    for (int mi = 0; mi < 2; ++mi) {
      const short8 aa = *(const short8*)&af[cur][mi * 512 + lane * 8];
      oq[mi] = __builtin_amdgcn_mfma_f32_16x16x32_bf16(aa, ub, oq[mi], 0, 0, 0);
    }
    // store o (8 scalar stores; drain allowance = vmcnt(8) next chunk)
    const size_t cb = ((size_t)((bh << 12) + (n << 5))) * 256;
#pragma unroll
    for (int mi = 0; mi < 2; ++mi)
#pragma unroll
      for (int r = 0; r < 4; ++r)
        dout[cb + (size_t)(mi * 16 + fg * 4 + r) * 256 + dvs * 16 + fr] = oq[mi][r];
    // S += k^T @ u  (16 independent MFMAs)
#pragma unroll
    for (int mi = 0; mi < 16; ++mi) {
      const short8 ak = *(const short8*)&ktf[cur][mi * 512 + lane * 8];
      S[mi] = __builtin_amdgcn_mfma_f32_16x16x32_bf16(ak, ub, S[mi], 0, 0, 0);
    }
  }
}

// ---------------------------------------------------------------------------
// Mix: streaming FIR along l with register ring buffer. grid = 512.
// ---------------------------------------------------------------------------
#define MIX_LT 64
__global__ __launch_bounds__(256) void mix_kernel(
    const float* __restrict__ v, const float* __restrict__ delta,
    const float* __restrict__ wgl, const float* __restrict__ pmix,
    const float* __restrict__ firs, const float* __restrict__ firl,
    const float* __restrict__ rms_w, unsigned short* __restrict__ out) {
  const int wgid = ((int)blockIdx.x & 7) * 64 + ((int)blockIdx.x >> 3);
  const int b = wgid >> 8;
  const int h = (wgid >> 6) & 3;
  const int lt = wgid & 63;
  const int l0 = lt * MIX_LT;
  const int t = threadIdx.x;
  const int wv = t >> 6, lane = t & 63;
  const float* vcol = v + ((((size_t)(b * Hn + h)) << 12)) * 256 + t;
  const float* dcol = delta + ((((size_t)(b * Hn + h)) << 12)) * 256 + t;
  float fw[31], fs3[3];
#pragma unroll
  for (int j = 0; j < 31; ++j) fw[j] = firl[((h << 8) + t) * 31 + j];
#pragma unroll
  for (int j = 0; j < 3; ++j) fs3[j] = firs[((h << 8) + t) * 3 + j];
  const float rw = rms_w[t];
  float win[31];
#pragma unroll
  for (int j = 0; j < 30; ++j) {
    const int ls = l0 - 30 + j;
    win[j] = (ls >= 0) ? vcol[(size_t)ls * 256] : 0.f;
  }
  win[30] = 0.f;
  __shared__ float wred[MIX_LT * 4];
  float o[MIX_LT];
#pragma unroll
  for (int i = 0; i < MIX_LT; ++i) {
    const int l = l0 + i;
    const float vnew = vcol[(size_t)l * 256];
    float lo = fw[30] * vnew;
#pragma unroll
    for (int j = 0; j < 30; ++j) lo = fmaf(fw[j], win[(i + j) % 31], lo);
    float sh = fs3[2] * vnew;
    sh = fmaf(fs3[1], win[(i + 29) % 31], sh);
    sh = fmaf(fs3[0], win[(i + 28) % 31], sh);
    win[(i + 30) % 31] = vnew;
    const int row = (b << 12) + l;
    const float p0 = pmix[row * 12 + h * 3 + 0];
    const float p1 = pmix[row * 12 + h * 3 + 1];
    const float p2 = pmix[row * 12 + h * 3 + 2];
    const float wg = wgl[row * 4 + h];
    const float mixv = p0 * vnew + p1 * sh + p2 * lo;
    const float oo = wg * dcol[(size_t)l * 256] + (1.f - wg) * mixv;
    o[i] = oo;
    float ss = oo * oo;
#pragma unroll
    for (int m = 1; m < 64; m <<= 1) ss += __shfl_xor(ss, m);
    if (lane == 0) wred[i * 4 + wv] = ss;
  }
  __syncthreads();
#pragma unroll
  for (int i = 0; i < MIX_LT; ++i) {
    const float sum = wred[i * 4] + wred[i * 4 + 1] + wred[i * 4 + 2] + wred[i * 4 + 3];
    const float sc = rsqrtf(sum * (1.f / 256.f) + 1e-5f);
    const int l = l0 + i;
    out[(size_t)((b << 12) + l) * 1024 + (h << 8) + t] = f2bf(o[i] * sc * rw);
  }
}

// ---------------------------------------------------------------------------
extern "C" void kernel_launch(void* const* d_in, const int* in_sizes, int n_in,
                              void* d_out, int out_size, void* d_ws, size_t ws_size,
                              hipStream_t stream) {
  const float* x = (const float*)d_in[0];
  const float* Wq = (const float*)d_in[1];
  const float* Wk = (const float*)d_in[2];
  const float* Wv = (const float*)d_in[3];
  const float* cq = (const float*)d_in[4];
  const float* ck = (const float*)d_in[5];
  const float* cv = (const float*)d_in[6];
  const float* Wb = (const float*)d_in[7];
  const float* firs = (const float*)d_in[8];
  const float* firl = (const float*)d_in[9];
  const float* Wg = (const float*)d_in[10];
  const float* bg = (const float*)d_in[11];
  const float* Wl = (const float*)d_in[12];
  const float* bl = (const float*)d_in[13];
  const float* ltemp = (const float*)d_in[14];
  const float* rmsw = (const float*)d_in[15];
  const float* Wo = (const float*)d_in[16];

  float* ws = (float*)d_ws;
  const size_t NE = (size_t)Bn * Ln * 1024;  // 8.39M floats
  float* qraw = ws;
  float* kraw = ws + NE;
  float* vraw = ws + 2 * NE;
  float* qn = ws + 3 * NE;
  float* kn = ws + 4 * NE;
  float* vn = ws + 5 * NE;
  float* beta = ws + 6 * NE;
  float* wgl = beta + (size_t)Bn * Hn * Ln;
  float* pmix = wgl + (size_t)Bn * Ln * Hn;
  float* attn_unused = pmix + (size_t)Bn * Ln * Hn * 3;
  unsigned short* Wot = (unsigned short*)(attn_unused + (size_t)Bn * Hn * NCHn * 1024);
  unsigned short* xb = (unsigned short*)qn;
  unsigned short* Wqt = (unsigned short*)(qn + 4194304);
  unsigned short* Wkt = Wqt + 1048576;
  unsigned short* Wvt = Wkt + 1048576;
  unsigned short* normed_bf = (unsigned short*)kn;  // kn dead after precomp
  unsigned short* wfrag = (unsigned short*)qraw;
  unsigned short* qfrag = wfrag + 8388608;
  unsigned short* ktfrag = (unsigned short*)kraw;
  unsigned short* afrag = ktfrag + 8388608;
  float* u0frag = qn;   // exact per-chunk slot overlay of qn
  float* dbuf = vraw;

  const dim3 wtg(32, 32);
  wt_kernel<<<wtg, 256, 0, stream>>>(Wq, Wqt, 1024, 1024);
  wt_kernel<<<wtg, 256, 0, stream>>>(Wk, Wkt, 1024, 1024);
  wt_kernel<<<wtg, 256, 0, stream>>>(Wv, Wvt, 1024, 1024);
  wt_kernel<<<wtg, 256, 0, stream>>>(Wo, Wot, 1024, 1024);
  f2bf_kernel<<<(int)(NE / 1024), 256, 0, stream>>>(x, xb, (int)NE);

  const dim3 gg(8, 64);  // N/128, M/128
  gemm_bf16<<<gg, 256, 0, stream>>>(xb, Wqt, qraw, Bn * Ln, 1024, 1024);
  gemm_bf16<<<gg, 256, 0, stream>>>(xb, Wkt, kraw, Bn * Ln, 1024, 1024);
  gemm_bf16<<<gg, 256, 0, stream>>>(xb, Wvt, vraw, Bn * Ln, 1024, 1024);
  gates_kernel<<<Bn * Ln / 4, 256, 0, stream>>>(x, Wb, Wg, bg, Wl, bl, ltemp,
                                                beta, wgl, pmix);
  conv_act_kernel<1><<<Bn * Ln, 256, 0, stream>>>(qraw, cq, qn);
  conv_act_kernel<1><<<Bn * Ln, 256, 0, stream>>>(kraw, ck, kn);
  conv_act_kernel<0><<<Bn * Ln, 256, 0, stream>>>(vraw, cv, vn);
  precomp_kernel<<<Bn * Hn * NCHn, 256, 0, stream>>>(qn, kn, vn, beta, wfrag,
                                                     qfrag, ktfrag, afrag, u0frag);
  scan_mfma<<<128, 64, 0, stream>>>(wfrag, qfrag, ktfrag, afrag, u0frag, dbuf);
  mix_kernel<<<Bn * Hn * (Ln / MIX_LT), 256, 0, stream>>>(
      vn, dbuf, wgl, pmix, firs, firl, rmsw, normed_bf);
  gemm_bf16<<<gg, 256, 0, stream>>>(normed_bf, Wot, (float*)d_out, Bn * Ln, 1024, 1024);
}

// Round 7
// 755.071 us; speedup vs baseline: 4.1792x; 1.0667x over previous
//
#include <hip/hip_runtime.h>
#include <hip/hip_bf16.h>
#include <math.h>

#define Bn 2
#define Ln 4096
#define Dn 1024
#define Hn 4
#define DKn 256
#define DVn 256
#define NCHn 128  // L/32 chunks

typedef __attribute__((ext_vector_type(8))) short short8;
typedef __attribute__((ext_vector_type(4))) float f32x4;

__device__ __forceinline__ float sigmoidf_(float x) { return 1.f / (1.f + __expf(-x)); }

__device__ __forceinline__ unsigned short f2bf(float f) {
  union { float f; unsigned u; } v; v.f = f;
  unsigned r = v.u + 0x7FFFu + ((v.u >> 16) & 1u);
  return (unsigned short)(r >> 16);
}

__device__ __forceinline__ unsigned cvt_pk_bf16(float a, float b) {
  unsigned r;
  asm volatile("v_cvt_pk_bf16_f32 %0, %1, %2" : "=v"(r) : "v"(a), "v"(b));
  return r;
}

__device__ __forceinline__ void gl2lds16(const void* g, void* l) {
  __builtin_amdgcn_global_load_lds((const __attribute__((address_space(1))) unsigned int*)g,
                                   (__attribute__((address_space(3))) unsigned int*)l, 16, 0, 0);
}

// ---------------------------------------------------------------------------
// Weight transpose + bf16 convert: Wt[n][k] = bf16(W[k][n]), K=N=1024.
// ---------------------------------------------------------------------------
__global__ __launch_bounds__(256) void wt_kernel(const float* __restrict__ W,
                                                 unsigned short* __restrict__ Wt,
                                                 int K, int N) {
  __shared__ float tile[32][33];
  const int bx = blockIdx.x * 32;  // n
  const int by = blockIdx.y * 32;  // k
  const int tx = threadIdx.x & 31, ty4 = (threadIdx.x >> 5) * 4;
#pragma unroll
  for (int r = 0; r < 4; ++r)
    tile[ty4 + r][tx] = W[(size_t)(by + ty4 + r) * N + bx + tx];
  __syncthreads();
#pragma unroll
  for (int r = 0; r < 4; ++r)
    Wt[(size_t)(bx + ty4 + r) * K + by + tx] = f2bf(tile[tx][ty4 + r]);
}

// ---------------------------------------------------------------------------
// fp32 -> bf16 elementwise, n % 1024 == 0
// ---------------------------------------------------------------------------
__global__ __launch_bounds__(256) void f2bf_kernel(const float* __restrict__ in,
                                                   unsigned short* __restrict__ out,
                                                   int n) {
  const int i4 = (blockIdx.x * 256 + threadIdx.x) * 4;
  if (i4 >= n) return;
  const float4 v = *(const float4*)&in[i4];
  ushort4 o;
  o.x = f2bf(v.x); o.y = f2bf(v.y); o.z = f2bf(v.z); o.w = f2bf(v.w);
  *(ushort4*)&out[i4] = o;
}

// ---------------------------------------------------------------------------
// bf16 MFMA GEMM: C[M,N] f32 = A[M,K]bf16 @ Bt[N,K]bf16^T. 128x128 tile, BK=32.
// ---------------------------------------------------------------------------
__global__ __launch_bounds__(256, 2) void gemm_bf16(const unsigned short* __restrict__ A,
                                                    const unsigned short* __restrict__ Bt,
                                                    float* __restrict__ C,
                                                    int M, int N, int K) {
  __shared__ __align__(16) unsigned short As[128 * 32];
  __shared__ __align__(16) unsigned short Bs[128 * 32];
  const int tid = threadIdx.x;
  const int wid = tid >> 6, lane = tid & 63;
  const int row0 = blockIdx.y * 128, col0 = blockIdx.x * 128;
  const int wr64 = (wid >> 1) * 64, wc64 = (wid & 1) * 64;
  const int fr = lane & 15, fg = lane >> 4;
  f32x4 acc[4][4];
#pragma unroll
  for (int i = 0; i < 4; ++i)
#pragma unroll
    for (int j = 0; j < 4; ++j) acc[i][j] = (f32x4){0.f, 0.f, 0.f, 0.f};
  for (int k0 = 0; k0 < K; k0 += 32) {
#pragma unroll
    for (int i = 0; i < 2; ++i) {
      const int off = wid * 2048 + i * 1024 + (lane << 4);  // LDS byte offset
      const int r = off >> 6;                               // tile row
      const int kb = off & 63;                              // byte within row
      gl2lds16((const char*)A + ((size_t)(row0 + r) * K + k0) * 2 + kb, (char*)As + off);
      gl2lds16((const char*)Bt + ((size_t)(col0 + r) * K + k0) * 2 + kb, (char*)Bs + off);
    }
    __syncthreads();
    short8 a[4], b[4];
#pragma unroll
    for (int mi = 0; mi < 4; ++mi)
      a[mi] = *(const short8*)&As[(wr64 + mi * 16 + fr) * 32 + fg * 8];
#pragma unroll
    for (int ni = 0; ni < 4; ++ni)
      b[ni] = *(const short8*)&Bs[(wc64 + ni * 16 + fr) * 32 + fg * 8];
#pragma unroll
    for (int mi = 0; mi < 4; ++mi)
#pragma unroll
      for (int ni = 0; ni < 4; ++ni)
        acc[mi][ni] = __builtin_amdgcn_mfma_f32_16x16x32_bf16(a[mi], b[ni], acc[mi][ni], 0, 0, 0);
    __syncthreads();
  }
#pragma unroll
  for (int mi = 0; mi < 4; ++mi) {
    const int orow = row0 + wr64 + mi * 16 + fg * 4;
#pragma unroll
    for (int ni = 0; ni < 4; ++ni) {
      const int ocol = col0 + wc64 + ni * 16 + fr;
#pragma unroll
      for (int r = 0; r < 4; ++r)
        C[(size_t)(orow + r) * N + ocol] = acc[mi][ni][r];
    }
  }
}

// ---------------------------------------------------------------------------
// Gate projections (unchanged)
// ---------------------------------------------------------------------------
__global__ __launch_bounds__(256) void gates_kernel(
    const float* __restrict__ x, const float* __restrict__ Wb,
    const float* __restrict__ Wg, const float* __restrict__ bg,
    const float* __restrict__ Wl, const float* __restrict__ bl,
    const float* __restrict__ log_temp, float* __restrict__ beta,
    float* __restrict__ wgl, float* __restrict__ pmix) {
  const int wave = threadIdx.x >> 6, lane = threadIdx.x & 63;
  const int row = (blockIdx.x << 2) + wave;
  if (row >= Bn * Ln) return;
  const float* xr = x + (size_t)row * Dn;
  float acc[20];
#pragma unroll
  for (int c = 0; c < 20; ++c) acc[c] = 0.f;
#pragma unroll
  for (int i = 0; i < 4; ++i) {
    const float4 xv = *(const float4*)&xr[(lane << 2) + (i << 8)];
    const float xa[4] = {xv.x, xv.y, xv.z, xv.w};
#pragma unroll
    for (int j = 0; j < 4; ++j) {
      const int kk = (i << 8) + (lane << 2) + j;
      const float xx = xa[j];
#pragma unroll
      for (int h = 0; h < 4; ++h) acc[h] = fmaf(xx, Wb[kk * 4 + h], acc[h]);
#pragma unroll
      for (int h = 0; h < 4; ++h) acc[4 + h] = fmaf(xx, Wg[kk * 4 + h], acc[4 + h]);
#pragma unroll
      for (int c = 0; c < 12; ++c) acc[8 + c] = fmaf(xx, Wl[kk * 12 + c], acc[8 + c]);
    }
  }
#pragma unroll
  for (int c = 0; c < 20; ++c)
    for (int off = 32; off; off >>= 1) acc[c] += __shfl_down(acc[c], off);
  if (lane == 0) {
    const int b = row >> 12, l = row & (Ln - 1);
#pragma unroll
    for (int h = 0; h < 4; ++h)
      beta[((size_t)(b * Hn + h) << 12) + l] = sigmoidf_(acc[h]);
#pragma unroll
    for (int h = 0; h < 4; ++h) wgl[row * 4 + h] = sigmoidf_(acc[4 + h] + bg[h]);
#pragma unroll
    for (int h = 0; h < 4; ++h) {
      const float it = 1.f / __expf(log_temp[h]);
      const float l0 = (acc[8 + h * 3 + 0] + bl[h * 3 + 0]) * it;
      const float l1 = (acc[8 + h * 3 + 1] + bl[h * 3 + 1]) * it;
      const float l2 = (acc[8 + h * 3 + 2] + bl[h * 3 + 2]) * it;
      const float mx = fmaxf(l0, fmaxf(l1, l2));
      const float e0 = __expf(l0 - mx), e1 = __expf(l1 - mx), e2 = __expf(l2 - mx);
      const float is = 1.f / (e0 + e1 + e2);
      pmix[row * 12 + h * 3 + 0] = e0 * is;
      pmix[row * 12 + h * 3 + 1] = e1 * is;
      pmix[row * 12 + h * 3 + 2] = e2 * is;
    }
  }
}

// ---------------------------------------------------------------------------
// Causal depthwise conv (K=4) + SiLU (+ optional l2norm). (unchanged)
// ---------------------------------------------------------------------------
template <int DO_L2>
__global__ __launch_bounds__(256) void conv_act_kernel(
    const float* __restrict__ raw, const float* __restrict__ cw,
    float* __restrict__ out) {
  const int blk = blockIdx.x;
  const int b = blk >> 12, l = blk & (Ln - 1);
  const int t = threadIdx.x;
  float vals[4];
#pragma unroll
  for (int g = 0; g < 4; ++g) {
    const int c = (g << 8) + t;
    float a = 0.f;
#pragma unroll
    for (int j = 0; j < 4; ++j) {
      const int ls = l - 3 + j;
      if (ls >= 0) a = fmaf(cw[c * 4 + j], raw[(((size_t)b << 12) + ls) * 1024 + c], a);
    }
    vals[g] = a * sigmoidf_(a);
  }
  if (DO_L2) {
    __shared__ float red[4][4];
    float ss[4];
#pragma unroll
    for (int g = 0; g < 4; ++g) ss[g] = vals[g] * vals[g];
#pragma unroll
    for (int g = 0; g < 4; ++g)
      for (int off = 32; off; off >>= 1) ss[g] += __shfl_down(ss[g], off);
    const int wave = t >> 6, lane = t & 63;
    if (lane == 0) {
#pragma unroll
      for (int g = 0; g < 4; ++g) red[wave][g] = ss[g];
    }
    __syncthreads();
#pragma unroll
    for (int g = 0; g < 4; ++g) {
      const float s = red[0][g] + red[1][g] + red[2][g] + red[3][g];
      vals[g] *= rsqrtf(s + 1e-6f);
    }
  }
#pragma unroll
  for (int g = 0; g < 4; ++g)
    out[((((size_t)(b * Hn + g)) << 12) + l) * 256 + t] = vals[g];
}

// ---------------------------------------------------------------------------
// Per-chunk precompute (unchanged: emits frag-ready layouts)
// ---------------------------------------------------------------------------
__global__ __launch_bounds__(256) void precomp_kernel(
    const float* __restrict__ q, const float* __restrict__ k,
    const float* __restrict__ v, const float* __restrict__ beta,
    unsigned short* __restrict__ wfrag, unsigned short* __restrict__ qfrag,
    unsigned short* __restrict__ ktfrag, unsigned short* __restrict__ afrag,
    float* __restrict__ u0frag) {
  const int blk = blockIdx.x;
  const int n = blk & 127, bh = blk >> 7;
  const size_t base = (((size_t)bh << 12) + (n << 5)) * 256;
  const size_t cid = (size_t)(bh * NCHn + n);
  __shared__ __align__(16) float qs[32][260];
  __shared__ __align__(16) float ks[32][260];
  __shared__ __align__(16) float vb[32][260];   // v*beta; later reused for w
  __shared__ __align__(16) float u0l[32][260];
  __shared__ float Am[32][33], Tm[32][33], bet[32];
  __shared__ __align__(16) float attn_l[32][36];
  const int t = threadIdx.x;
  if (t < 32) bet[t] = beta[((size_t)bh << 12) + (n << 5) + t];
  __syncthreads();
  for (int idx = t; idx < 32 * 64; idx += 256) {
    const int r = idx >> 6, fi = (idx & 63) << 2;
    *(float4*)&qs[r][fi] = *(const float4*)&q[base + r * 256 + fi];
    *(float4*)&ks[r][fi] = *(const float4*)&k[base + r * 256 + fi];
    float4 vv = *(const float4*)&v[base + r * 256 + fi];
    const float bm = bet[r];
    vv.x *= bm; vv.y *= bm; vv.z *= bm; vv.w *= bm;
    *(float4*)&vb[r][fi] = vv;
  }
  __syncthreads();
  {
    const int i = t >> 3, j0 = t & 7;
    float dq[4] = {0.f, 0.f, 0.f, 0.f}, dk2[4] = {0.f, 0.f, 0.f, 0.f};
    for (int d = 0; d < 256; d += 4) {
      const float4 qi = *(const float4*)&qs[i][d];
      const float4 ki = *(const float4*)&ks[i][d];
#pragma unroll
      for (int jj = 0; jj < 4; ++jj) {
        const float4 kj = *(const float4*)&ks[j0 + (jj << 3)][d];
        dq[jj] = fmaf(qi.x, kj.x, dq[jj]);
        dq[jj] = fmaf(qi.y, kj.y, dq[jj]);
        dq[jj] = fmaf(qi.z, kj.z, dq[jj]);
        dq[jj] = fmaf(qi.w, kj.w, dq[jj]);
        dk2[jj] = fmaf(ki.x, kj.x, dk2[jj]);
        dk2[jj] = fmaf(ki.y, kj.y, dk2[jj]);
        dk2[jj] = fmaf(ki.z, kj.z, dk2[jj]);
        dk2[jj] = fmaf(ki.w, kj.w, dk2[jj]);
      }
    }
    const float bi = bet[i];
#pragma unroll
    for (int jj = 0; jj < 4; ++jj) {
      const int j = j0 + (jj << 3);
      Am[i][j] = bi * dk2[jj];
      attn_l[i][j] = (j <= i) ? dq[jj] : 0.f;
    }
  }
  for (int idx = t; idx < 1024; idx += 256)
    Tm[idx >> 5][idx & 31] = ((idx >> 5) == (idx & 31)) ? 1.f : 0.f;
  __syncthreads();
  for (int i = 1; i < 32; ++i) {
    if (t < 32) {
      float s = 0.f;
      for (int m = 0; m < i; ++m) s = fmaf(Am[i][m], Tm[m][t], s);
      Tm[i][t] = ((i == t) ? 1.f : 0.f) - s;
    }
    __syncthreads();
  }
  {
    const int i = t >> 3;
    const int dj = (t & 7) << 2;
    float4 ua[8], wa[8];
#pragma unroll
    for (int s = 0; s < 8; ++s) {
      ua[s] = make_float4(0.f, 0.f, 0.f, 0.f);
      wa[s] = make_float4(0.f, 0.f, 0.f, 0.f);
    }
    for (int m = 0; m < 32; ++m) {
      const float tim = Tm[i][m];
      const float t2m = tim * bet[m];
#pragma unroll
      for (int s = 0; s < 8; ++s) {
        const int d = dj + (s << 5);
        const float4 vv = *(const float4*)&vb[m][d];
        const float4 kk = *(const float4*)&ks[m][d];
        ua[s].x = fmaf(tim, vv.x, ua[s].x);
        ua[s].y = fmaf(tim, vv.y, ua[s].y);
        ua[s].z = fmaf(tim, vv.z, ua[s].z);
        ua[s].w = fmaf(tim, vv.w, ua[s].w);
        wa[s].x = fmaf(t2m, kk.x, wa[s].x);
        wa[s].y = fmaf(t2m, kk.y, wa[s].y);
        wa[s].z = fmaf(t2m, kk.z, wa[s].z);
        wa[s].w = fmaf(t2m, kk.w, wa[s].w);
      }
    }
    __syncthreads();  // all reads of vb done before overwrite
#pragma unroll
    for (int s = 0; s < 8; ++s) {
      const int d = dj + (s << 5);
      *(float4*)&u0l[i][d] = ua[s];
      *(float4*)&vb[i][d] = wa[s];   // vb now holds w
    }
  }
  __syncthreads();
  // ---- gather-writes to fragment-ready global layouts ----
  const int lane = t & 63;
  const int fg = (lane >> 4) & 3;
#pragma unroll
  for (int it = 0; it < 4; ++it) {
    const int u = it * 4 + (t >> 6);
    const int mi = u >> 3, kw = u & 7;
    const int c = mi * 16 + (lane & 15);
    const int dk0 = kw * 32 + fg * 8;
    const float4 a = *(const float4*)&vb[c][dk0];
    const float4 b2 = *(const float4*)&vb[c][dk0 + 4];
    int4 o;
    o.x = f2bf(a.x) | ((unsigned)f2bf(a.y) << 16);
    o.y = f2bf(a.z) | ((unsigned)f2bf(a.w) << 16);
    o.z = f2bf(b2.x) | ((unsigned)f2bf(b2.y) << 16);
    o.w = f2bf(b2.z) | ((unsigned)f2bf(b2.w) << 16);
    *(int4*)&wfrag[cid * 8192 + u * 512 + lane * 8] = o;
    const float4 qa = *(const float4*)&qs[c][dk0];
    const float4 qb = *(const float4*)&qs[c][dk0 + 4];
    int4 oq;
    oq.x = f2bf(qa.x) | ((unsigned)f2bf(qa.y) << 16);
    oq.y = f2bf(qa.z) | ((unsigned)f2bf(qa.w) << 16);
    oq.z = f2bf(qb.x) | ((unsigned)f2bf(qb.y) << 16);
    oq.w = f2bf(qb.z) | ((unsigned)f2bf(qb.w) << 16);
    *(int4*)&qfrag[cid * 8192 + u * 512 + lane * 8] = oq;
  }
#pragma unroll
  for (int it = 0; it < 4; ++it) {
    const int mi = it * 4 + (t >> 6);
    const int dk = mi * 16 + (lane & 15);
    const int c0 = fg * 8;
    unsigned short e[8];
#pragma unroll
    for (int j = 0; j < 8; ++j) e[j] = f2bf(ks[c0 + j][dk]);
    int4 o;
    o.x = e[0] | ((unsigned)e[1] << 16);
    o.y = e[2] | ((unsigned)e[3] << 16);
    o.z = e[4] | ((unsigned)e[5] << 16);
    o.w = e[6] | ((unsigned)e[7] << 16);
    *(int4*)&ktfrag[cid * 8192 + mi * 512 + lane * 8] = o;
  }
  if (t < 128) {
    const int mi = t >> 6;
    const int c = mi * 16 + (lane & 15);
    const int c0 = fg * 8;
    const float4 a = *(const float4*)&attn_l[c][c0];
    const float4 b2 = *(const float4*)&attn_l[c][c0 + 4];
    int4 o;
    o.x = f2bf(a.x) | ((unsigned)f2bf(a.y) << 16);
    o.y = f2bf(a.z) | ((unsigned)f2bf(a.w) << 16);
    o.z = f2bf(b2.x) | ((unsigned)f2bf(b2.y) << 16);
    o.w = f2bf(b2.z) | ((unsigned)f2bf(b2.w) << 16);
    *(int4*)&afrag[cid * 1024 + mi * 512 + lane * 8] = o;
  }
#pragma unroll
  for (int it = 0; it < 8; ++it) {
    const int u = it * 4 + (t >> 6);
    const int dvs = u >> 1, mi = u & 1;
    const int c0 = mi * 16 + fg * 4;
    const int dv = dvs * 16 + (lane & 15);
    float4 o;
    o.x = u0l[c0 + 0][dv];
    o.y = u0l[c0 + 1][dv];
    o.z = u0l[c0 + 2][dv];
    o.w = u0l[c0 + 3][dv];
    *(float4*)&u0frag[cid * 8192 + u * 256 + lane * 4] = o;
  }
}

// ---------------------------------------------------------------------------
// Scan v5: 2 waves per block, dk split 128/128. grid = 128 = 8 bh x 16 dv16.
// Wave w owns dk rows [128w,128w+128): S-half = 8 C-frag accumulators.
// Wave-private staging (counted per-wave vmcnt), raw s_barrier + lgkm-only
// drains for the small cross-wave exchanges (pu/po/ut).
// ---------------------------------------------------------------------------
__global__ __launch_bounds__(128, 1) void scan_mfma(
    const unsigned short* __restrict__ wfrag, const unsigned short* __restrict__ qfrag,
    const unsigned short* __restrict__ ktfrag, const unsigned short* __restrict__ afrag,
    const float* __restrict__ u0frag, float* __restrict__ dout) {
  const int bh = blockIdx.x & 7;
  const int dvs = blockIdx.x >> 3;
  const int tid = threadIdx.x;
  const int w = tid >> 6;
  const int lane = tid & 63;
  const int fr = lane & 15, fg = lane >> 4;
  const int swz = (fr & 7) << 4;
  // staging: [buf][wave][unit][512] bf16 (wave-private halves)
  __shared__ __align__(16) unsigned short wf[2][2][8][512];
  __shared__ __align__(16) unsigned short qf[2][2][8][512];
  __shared__ __align__(16) unsigned short ktf[2][2][8][512];
  __shared__ __align__(16) unsigned short af[2][2][512];   // wave0-staged
  __shared__ __align__(16) float u0f[2][2][256];           // wave0-staged
  __shared__ __align__(16) unsigned short St[2][2048];     // per-wave [dv16][dk128]
  __shared__ __align__(16) unsigned short ut[512];         // [dv16][c32]
  __shared__ __align__(16) float pu1[2][256];              // wave1 partial u
  __shared__ __align__(16) float po1[2][256];              // wave1 partial o
  f32x4 S[8];
#pragma unroll
  for (int i = 0; i < 8; ++i) S[i] = (f32x4){0.f, 0.f, 0.f, 0.f};

  // prologue: stage chunk 0
  {
    const size_t fb = (size_t)(bh * NCHn);
#pragma unroll
    for (int u8 = 0; u8 < 8; ++u8) {
      const int mi = u8 >> 2, kwp = u8 & 3;
      const int u = mi * 8 + 4 * w + kwp;
      gl2lds16((const char*)(wfrag + fb * 8192) + u * 1024 + lane * 16,
               (char*)&wf[0][w][u8][0] + lane * 16);
      gl2lds16((const char*)(qfrag + fb * 8192) + u * 1024 + lane * 16,
               (char*)&qf[0][w][u8][0] + lane * 16);
      gl2lds16((const char*)(ktfrag + fb * 8192) + (8 * w + u8) * 1024 + lane * 16,
               (char*)&ktf[0][w][u8][0] + lane * 16);
    }
    if (w == 0) {
#pragma unroll
      for (int u = 0; u < 2; ++u) {
        gl2lds16((const char*)(afrag + fb * 1024) + u * 1024 + lane * 16,
                 (char*)&af[0][u][0] + lane * 16);
        gl2lds16((const char*)(u0frag + fb * 8192 + dvs * 512) + u * 1024 + lane * 16,
                 (char*)&u0f[0][u][0] + lane * 16);
      }
    }
  }

  for (int n = 0; n < NCHn; ++n) {
    const int cur = n & 1;
    // pack S-half -> St[w]  ([dv=fr][dk'128], XOR-swz)
#pragma unroll
    for (int mi = 0; mi < 8; ++mi) {
      const unsigned w0 = cvt_pk_bf16(S[mi][0], S[mi][1]);
      const unsigned w1 = cvt_pk_bf16(S[mi][2], S[mi][3]);
      const int a = (fr * 256 + mi * 32 + fg * 8) ^ swz;
      *(uint2*)((char*)&St[w][0] + a) = make_uint2(w0, w1);
    }
    // per-wave waits: chunk-n loads retired; pack writes visible
    if (n == 0) {
      asm volatile("s_waitcnt vmcnt(0) lgkmcnt(0)" ::: "memory");
    } else if (w == 0) {
      asm volatile("s_waitcnt vmcnt(8) lgkmcnt(0)" ::: "memory");
    } else {
      asm volatile("s_waitcnt vmcnt(0) lgkmcnt(0)" ::: "memory");
    }
    __builtin_amdgcn_sched_barrier(0);

    // B-frags of own S-half
    short8 sb[4];
#pragma unroll
    for (int kwp = 0; kwp < 4; ++kwp) {
      const int a = (fr * 256 + kwp * 64 + fg * 16) ^ swz;
      sb[kwp] = *(const short8*)((const char*)&St[w][0] + a);
    }
    // prefetch chunk n+1 (wave-private buffers)
    if (n + 1 < NCHn) {
      const int nx = cur ^ 1;
      const size_t fb = (size_t)(bh * NCHn + n + 1);
#pragma unroll
      for (int u8 = 0; u8 < 8; ++u8) {
        const int mi = u8 >> 2, kwp = u8 & 3;
        const int u = mi * 8 + 4 * w + kwp;
        gl2lds16((const char*)(wfrag + fb * 8192) + u * 1024 + lane * 16,
                 (char*)&wf[nx][w][u8][0] + lane * 16);
        gl2lds16((const char*)(qfrag + fb * 8192) + u * 1024 + lane * 16,
                 (char*)&qf[nx][w][u8][0] + lane * 16);
        gl2lds16((const char*)(ktfrag + fb * 8192) + (8 * w + u8) * 1024 + lane * 16,
                 (char*)&ktf[nx][w][u8][0] + lane * 16);
      }
      if (w == 0) {
#pragma unroll
        for (int u = 0; u < 2; ++u) {
          gl2lds16((const char*)(afrag + fb * 1024) + u * 1024 + lane * 16,
                   (char*)&af[nx][u][0] + lane * 16);
          gl2lds16((const char*)(u0frag + fb * 8192 + dvs * 512) + u * 1024 + lane * 16,
                   (char*)&u0f[nx][u][0] + lane * 16);
        }
      }
    }
    // partial w@S and q@S over own dk half (4-deep chains)
    f32x4 up[2], oq[2];
    up[0] = up[1] = (f32x4){0.f, 0.f, 0.f, 0.f};
    oq[0] = oq[1] = (f32x4){0.f, 0.f, 0.f, 0.f};
#pragma unroll
    for (int kwp = 0; kwp < 4; ++kwp) {
#pragma unroll
      for (int mi = 0; mi < 2; ++mi) {
        const short8 aw = *(const short8*)((const char*)wf +
            (((cur * 2 + w) * 8 + mi * 4 + kwp) * 1024) + lane * 16);
        up[mi] = __builtin_amdgcn_mfma_f32_16x16x32_bf16(aw, sb[kwp], up[mi], 0, 0, 0);
        const short8 aq = *(const short8*)((const char*)qf +
            (((cur * 2 + w) * 8 + mi * 4 + kwp) * 1024) + lane * 16);
        oq[mi] = __builtin_amdgcn_mfma_f32_16x16x32_bf16(aq, sb[kwp], oq[mi], 0, 0, 0);
      }
    }
    // wave1 ships partials
    if (w == 1) {
#pragma unroll
      for (int mi = 0; mi < 2; ++mi) {
        *(f32x4*)&pu1[mi][lane * 4] = up[mi];
        *(f32x4*)&po1[mi][lane * 4] = oq[mi];
      }
    }
    asm volatile("s_waitcnt lgkmcnt(0)" ::: "memory");
    __builtin_amdgcn_s_barrier();  // barrier1: partials visible
    // wave0: combine, compute u, pack ut, finish o partial
    f32x4 o_f[2];
    if (w == 0) {
#pragma unroll
      for (int mi = 0; mi < 2; ++mi) {
        const f32x4 p1 = *(const f32x4*)&pu1[mi][lane * 4];
        const f32x4 u0v = *(const f32x4*)&u0f[cur][mi][lane * 4];
        const f32x4 uu = u0v - up[mi] - p1;
        const unsigned w0 = cvt_pk_bf16(uu[0], uu[1]);
        const unsigned w1 = cvt_pk_bf16(uu[2], uu[3]);
        const int a = (fr * 64 + (mi * 32 + fg * 8)) ^ swz;
        *(uint2*)((char*)ut + a) = make_uint2(w0, w1);
        o_f[mi] = oq[mi] + *(const f32x4*)&po1[mi][lane * 4];
      }
    }
    asm volatile("s_waitcnt lgkmcnt(0)" ::: "memory");
    __builtin_amdgcn_s_barrier();  // barrier2: ut visible
    __builtin_amdgcn_sched_barrier(0);
    const short8 ub = *(const short8*)((const char*)ut + ((fr * 64 + fg * 16) ^ swz));
    if (w == 0) {
      // o = q@S + attn@u ; store
#pragma unroll
      for (int mi = 0; mi < 2; ++mi) {
        const short8 aa = *(const short8*)((const char*)af +
            ((cur * 2 + mi) * 1024) + lane * 16);
        o_f[mi] = __builtin_amdgcn_mfma_f32_16x16x32_bf16(aa, ub, o_f[mi], 0, 0, 0);
      }
      const size_t cb = ((size_t)((bh << 12) + (n << 5))) * 256;
#pragma unroll
      for (int mi = 0; mi < 2; ++mi)
#pragma unroll
        for (int r = 0; r < 4; ++r)
          dout[cb + (size_t)(mi * 16 + fg * 4 + r) * 256 + dvs * 16 + fr] = o_f[mi][r];
    }
    // S-half += k^T @ u (8 independent MFMAs)
#pragma unroll
    for (int mi = 0; mi < 8; ++mi) {
      const short8 ak = *(const short8*)((const char*)ktf +
          (((cur * 2 + w) * 8 + mi) * 1024) + lane * 16);
      S[mi] = __builtin_amdgcn_mfma_f32_16x16x32_bf16(ak, ub, S[mi], 0, 0, 0);
    }
  }
}

// ---------------------------------------------------------------------------
// Mix: streaming FIR along l with register ring buffer. grid = 512.
// ---------------------------------------------------------------------------
#define MIX_LT 64
__global__ __launch_bounds__(256) void mix_kernel(
    const float* __restrict__ v, const float* __restrict__ delta,
    const float* __restrict__ wgl, const float* __restrict__ pmix,
    const float* __restrict__ firs, const float* __restrict__ firl,
    const float* __restrict__ rms_w, unsigned short* __restrict__ out) {
  const int wgid = ((int)blockIdx.x & 7) * 64 + ((int)blockIdx.x >> 3);
  const int b = wgid >> 8;
  const int h = (wgid >> 6) & 3;
  const int lt = wgid & 63;
  const int l0 = lt * MIX_LT;
  const int t = threadIdx.x;
  const int wv = t >> 6, lane = t & 63;
  const float* vcol = v + ((((size_t)(b * Hn + h)) << 12)) * 256 + t;
  const float* dcol = delta + ((((size_t)(b * Hn + h)) << 12)) * 256 + t;
  float fw[31], fs3[3];
#pragma unroll
  for (int j = 0; j < 31; ++j) fw[j] = firl[((h << 8) + t) * 31 + j];
#pragma unroll
  for (int j = 0; j < 3; ++j) fs3[j] = firs[((h << 8) + t) * 3 + j];
  const float rw = rms_w[t];
  float win[31];
#pragma unroll
  for (int j = 0; j < 30; ++j) {
    const int ls = l0 - 30 + j;
    win[j] = (ls >= 0) ? vcol[(size_t)ls * 256] : 0.f;
  }
  win[30] = 0.f;
  __shared__ float wred[MIX_LT * 4];
  float o[MIX_LT];
#pragma unroll
  for (int i = 0; i < MIX_LT; ++i) {
    const int l = l0 + i;
    const float vnew = vcol[(size_t)l * 256];
    float lo = fw[30] * vnew;
#pragma unroll
    for (int j = 0; j < 30; ++j) lo = fmaf(fw[j], win[(i + j) % 31], lo);
    float sh = fs3[2] * vnew;
    sh = fmaf(fs3[1], win[(i + 29) % 31], sh);
    sh = fmaf(fs3[0], win[(i + 28) % 31], sh);
    win[(i + 30) % 31] = vnew;
    const int row = (b << 12) + l;
    const float p0 = pmix[row * 12 + h * 3 + 0];
    const float p1 = pmix[row * 12 + h * 3 + 1];
    const float p2 = pmix[row * 12 + h * 3 + 2];
    const float wg = wgl[row * 4 + h];
    const float mixv = p0 * vnew + p1 * sh + p2 * lo;
    const float oo = wg * dcol[(size_t)l * 256] + (1.f - wg) * mixv;
    o[i] = oo;
    float ss = oo * oo;
#pragma unroll
    for (int m = 1; m < 64; m <<= 1) ss += __shfl_xor(ss, m);
    if (lane == 0) wred[i * 4 + wv] = ss;
  }
  __syncthreads();
#pragma unroll
  for (int i = 0; i < MIX_LT; ++i) {
    const float sum = wred[i * 4] + wred[i * 4 + 1] + wred[i * 4 + 2] + wred[i * 4 + 3];
    const float sc = rsqrtf(sum * (1.f / 256.f) + 1e-5f);
    const int l = l0 + i;
    out[(size_t)((b << 12) + l) * 1024 + (h << 8) + t] = f2bf(o[i] * sc * rw);
  }
}

// ---------------------------------------------------------------------------
extern "C" void kernel_launch(void* const* d_in, const int* in_sizes, int n_in,
                              void* d_out, int out_size, void* d_ws, size_t ws_size,
                              hipStream_t stream) {
  const float* x = (const float*)d_in[0];
  const float* Wq = (const float*)d_in[1];
  const float* Wk = (const float*)d_in[2];
  const float* Wv = (const float*)d_in[3];
  const float* cq = (const float*)d_in[4];
  const float* ck = (const float*)d_in[5];
  const float* cv = (const float*)d_in[6];
  const float* Wb = (const float*)d_in[7];
  const float* firs = (const float*)d_in[8];
  const float* firl = (const float*)d_in[9];
  const float* Wg = (const float*)d_in[10];
  const float* bg = (const float*)d_in[11];
  const float* Wl = (const float*)d_in[12];
  const float* bl = (const float*)d_in[13];
  const float* ltemp = (const float*)d_in[14];
  const float* rmsw = (const float*)d_in[15];
  const float* Wo = (const float*)d_in[16];

  float* ws = (float*)d_ws;
  const size_t NE = (size_t)Bn * Ln * 1024;  // 8.39M floats
  float* qraw = ws;
  float* kraw = ws + NE;
  float* vraw = ws + 2 * NE;
  float* qn = ws + 3 * NE;
  float* kn = ws + 4 * NE;
  float* vn = ws + 5 * NE;
  float* beta = ws + 6 * NE;
  float* wgl = beta + (size_t)Bn * Hn * Ln;
  float* pmix = wgl + (size_t)Bn * Ln * Hn;
  float* attn_unused = pmix + (size_t)Bn * Ln * Hn * 3;
  unsigned short* Wot = (unsigned short*)(attn_unused + (size_t)Bn * Hn * NCHn * 1024);
  unsigned short* xb = (unsigned short*)qn;
  unsigned short* Wqt = (unsigned short*)(qn + 4194304);
  unsigned short* Wkt = Wqt + 1048576;
  unsigned short* Wvt = Wkt + 1048576;
  unsigned short* normed_bf = (unsigned short*)kn;  // kn dead after precomp
  unsigned short* wfrag = (unsigned short*)qraw;
  unsigned short* qfrag = wfrag + 8388608;
  unsigned short* ktfrag = (unsigned short*)kraw;
  unsigned short* afrag = ktfrag + 8388608;
  float* u0frag = qn;   // exact per-chunk slot overlay of qn
  float* dbuf = vraw;

  const dim3 wtg(32, 32);
  wt_kernel<<<wtg, 256, 0, stream>>>(Wq, Wqt, 1024, 1024);
  wt_kernel<<<wtg, 256, 0, stream>>>(Wk, Wkt, 1024, 1024);
  wt_kernel<<<wtg, 256, 0, stream>>>(Wv, Wvt, 1024, 1024);
  wt_kernel<<<wtg, 256, 0, stream>>>(Wo, Wot, 1024, 1024);
  f2bf_kernel<<<(int)(NE / 1024), 256, 0, stream>>>(x, xb, (int)NE);

  const dim3 gg(8, 64);  // N/128, M/128
  gemm_bf16<<<gg, 256, 0, stream>>>(xb, Wqt, qraw, Bn * Ln, 1024, 1024);
  gemm_bf16<<<gg, 256, 0, stream>>>(xb, Wkt, kraw, Bn * Ln, 1024, 1024);
  gemm_bf16<<<gg, 256, 0, stream>>>(xb, Wvt, vraw, Bn * Ln, 1024, 1024);
  gates_kernel<<<Bn * Ln / 4, 256, 0, stream>>>(x, Wb, Wg, bg, Wl, bl, ltemp,
                                                beta, wgl, pmix);
  conv_act_kernel<1><<<Bn * Ln, 256, 0, stream>>>(qraw, cq, qn);
  conv_act_kernel<1><<<Bn * Ln, 256, 0, stream>>>(kraw, ck, kn);
  conv_act_kernel<0><<<Bn * Ln, 256, 0, stream>>>(vraw, cv, vn);
  precomp_kernel<<<Bn * Hn * NCHn, 256, 0, stream>>>(qn, kn, vn, beta, wfrag,
                                                     qfrag, ktfrag, afrag, u0frag);
  scan_mfma<<<128, 128, 0, stream>>>(wfrag, qfrag, ktfrag, afrag, u0frag, dbuf);
  mix_kernel<<<Bn * Hn * (Ln / MIX_LT), 256, 0, stream>>>(
      vn, dbuf, wgl, pmix, firs, firl, rmsw, normed_bf);
  gemm_bf16<<<gg, 256, 0, stream>>>(normed_bf, Wot, (float*)d_out, Bn * Ln, 1024, 1024);
}

// Round 8
// 650.137 us; speedup vs baseline: 4.8537x; 1.1614x over previous
//
#include <hip/hip_runtime.h>
#include <hip/hip_bf16.h>
#include <math.h>

#define Bn 2
#define Ln 4096
#define Dn 1024
#define Hn 4
#define DKn 256
#define DVn 256
#define NCHn 128  // L/32 chunks

typedef __attribute__((ext_vector_type(8))) short short8;
typedef __attribute__((ext_vector_type(4))) float f32x4;

__device__ __forceinline__ float sigmoidf_(float x) { return 1.f / (1.f + __expf(-x)); }

__device__ __forceinline__ unsigned short f2bf(float f) {
  union { float f; unsigned u; } v; v.f = f;
  unsigned r = v.u + 0x7FFFu + ((v.u >> 16) & 1u);
  return (unsigned short)(r >> 16);
}

__device__ __forceinline__ unsigned cvt_pk_bf16(float a, float b) {
  unsigned r;
  asm volatile("v_cvt_pk_bf16_f32 %0, %1, %2" : "=v"(r) : "v"(a), "v"(b));
  return r;
}

__device__ __forceinline__ void gl2lds16(const void* g, void* l) {
  __builtin_amdgcn_global_load_lds((const __attribute__((address_space(1))) unsigned int*)g,
                                   (__attribute__((address_space(3))) unsigned int*)l, 16, 0, 0);
}

// ---------------------------------------------------------------------------
// Weight transpose + bf16 convert: Wt[n][k] = bf16(W[k][n]), K=N=1024.
// ---------------------------------------------------------------------------
__global__ __launch_bounds__(256) void wt_kernel(const float* __restrict__ W,
                                                 unsigned short* __restrict__ Wt,
                                                 int K, int N) {
  __shared__ float tile[32][33];
  const int bx = blockIdx.x * 32;  // n
  const int by = blockIdx.y * 32;  // k
  const int tx = threadIdx.x & 31, ty4 = (threadIdx.x >> 5) * 4;
#pragma unroll
  for (int r = 0; r < 4; ++r)
    tile[ty4 + r][tx] = W[(size_t)(by + ty4 + r) * N + bx + tx];
  __syncthreads();
#pragma unroll
  for (int r = 0; r < 4; ++r)
    Wt[(size_t)(bx + ty4 + r) * K + by + tx] = f2bf(tile[tx][ty4 + r]);
}

// ---------------------------------------------------------------------------
// fp32 -> bf16 elementwise, n % 1024 == 0
// ---------------------------------------------------------------------------
__global__ __launch_bounds__(256) void f2bf_kernel(const float* __restrict__ in,
                                                   unsigned short* __restrict__ out,
                                                   int n) {
  const int i4 = (blockIdx.x * 256 + threadIdx.x) * 4;
  if (i4 >= n) return;
  const float4 v = *(const float4*)&in[i4];
  ushort4 o;
  o.x = f2bf(v.x); o.y = f2bf(v.y); o.z = f2bf(v.z); o.w = f2bf(v.w);
  *(ushort4*)&out[i4] = o;
}

// ---------------------------------------------------------------------------
// bf16 MFMA GEMM: C[M,N] f32 = A[M,K]bf16 @ Bt[N,K]bf16^T. 128x128 tile, BK=32.
// ---------------------------------------------------------------------------
__global__ __launch_bounds__(256, 2) void gemm_bf16(const unsigned short* __restrict__ A,
                                                    const unsigned short* __restrict__ Bt,
                                                    float* __restrict__ C,
                                                    int M, int N, int K) {
  __shared__ __align__(16) unsigned short As[128 * 32];
  __shared__ __align__(16) unsigned short Bs[128 * 32];
  const int tid = threadIdx.x;
  const int wid = tid >> 6, lane = tid & 63;
  const int row0 = blockIdx.y * 128, col0 = blockIdx.x * 128;
  const int wr64 = (wid >> 1) * 64, wc64 = (wid & 1) * 64;
  const int fr = lane & 15, fg = lane >> 4;
  f32x4 acc[4][4];
#pragma unroll
  for (int i = 0; i < 4; ++i)
#pragma unroll
    for (int j = 0; j < 4; ++j) acc[i][j] = (f32x4){0.f, 0.f, 0.f, 0.f};
  for (int k0 = 0; k0 < K; k0 += 32) {
#pragma unroll
    for (int i = 0; i < 2; ++i) {
      const int off = wid * 2048 + i * 1024 + (lane << 4);  // LDS byte offset
      const int r = off >> 6;                               // tile row
      const int kb = off & 63;                              // byte within row
      gl2lds16((const char*)A + ((size_t)(row0 + r) * K + k0) * 2 + kb, (char*)As + off);
      gl2lds16((const char*)Bt + ((size_t)(col0 + r) * K + k0) * 2 + kb, (char*)Bs + off);
    }
    __syncthreads();
    short8 a[4], b[4];
#pragma unroll
    for (int mi = 0; mi < 4; ++mi)
      a[mi] = *(const short8*)&As[(wr64 + mi * 16 + fr) * 32 + fg * 8];
#pragma unroll
    for (int ni = 0; ni < 4; ++ni)
      b[ni] = *(const short8*)&Bs[(wc64 + ni * 16 + fr) * 32 + fg * 8];
#pragma unroll
    for (int mi = 0; mi < 4; ++mi)
#pragma unroll
      for (int ni = 0; ni < 4; ++ni)
        acc[mi][ni] = __builtin_amdgcn_mfma_f32_16x16x32_bf16(a[mi], b[ni], acc[mi][ni], 0, 0, 0);
    __syncthreads();
  }
#pragma unroll
  for (int mi = 0; mi < 4; ++mi) {
    const int orow = row0 + wr64 + mi * 16 + fg * 4;
#pragma unroll
    for (int ni = 0; ni < 4; ++ni) {
      const int ocol = col0 + wc64 + ni * 16 + fr;
#pragma unroll
      for (int r = 0; r < 4; ++r)
        C[(size_t)(orow + r) * N + ocol] = acc[mi][ni][r];
    }
  }
}

// ---------------------------------------------------------------------------
// Gate projections (unchanged)
// ---------------------------------------------------------------------------
__global__ __launch_bounds__(256) void gates_kernel(
    const float* __restrict__ x, const float* __restrict__ Wb,
    const float* __restrict__ Wg, const float* __restrict__ bg,
    const float* __restrict__ Wl, const float* __restrict__ bl,
    const float* __restrict__ log_temp, float* __restrict__ beta,
    float* __restrict__ wgl, float* __restrict__ pmix) {
  const int wave = threadIdx.x >> 6, lane = threadIdx.x & 63;
  const int row = (blockIdx.x << 2) + wave;
  if (row >= Bn * Ln) return;
  const float* xr = x + (size_t)row * Dn;
  float acc[20];
#pragma unroll
  for (int c = 0; c < 20; ++c) acc[c] = 0.f;
#pragma unroll
  for (int i = 0; i < 4; ++i) {
    const float4 xv = *(const float4*)&xr[(lane << 2) + (i << 8)];
    const float xa[4] = {xv.x, xv.y, xv.z, xv.w};
#pragma unroll
    for (int j = 0; j < 4; ++j) {
      const int kk = (i << 8) + (lane << 2) + j;
      const float xx = xa[j];
#pragma unroll
      for (int h = 0; h < 4; ++h) acc[h] = fmaf(xx, Wb[kk * 4 + h], acc[h]);
#pragma unroll
      for (int h = 0; h < 4; ++h) acc[4 + h] = fmaf(xx, Wg[kk * 4 + h], acc[4 + h]);
#pragma unroll
      for (int c = 0; c < 12; ++c) acc[8 + c] = fmaf(xx, Wl[kk * 12 + c], acc[8 + c]);
    }
  }
#pragma unroll
  for (int c = 0; c < 20; ++c)
    for (int off = 32; off; off >>= 1) acc[c] += __shfl_down(acc[c], off);
  if (lane == 0) {
    const int b = row >> 12, l = row & (Ln - 1);
#pragma unroll
    for (int h = 0; h < 4; ++h)
      beta[((size_t)(b * Hn + h) << 12) + l] = sigmoidf_(acc[h]);
#pragma unroll
    for (int h = 0; h < 4; ++h) wgl[row * 4 + h] = sigmoidf_(acc[4 + h] + bg[h]);
#pragma unroll
    for (int h = 0; h < 4; ++h) {
      const float it = 1.f / __expf(log_temp[h]);
      const float l0 = (acc[8 + h * 3 + 0] + bl[h * 3 + 0]) * it;
      const float l1 = (acc[8 + h * 3 + 1] + bl[h * 3 + 1]) * it;
      const float l2 = (acc[8 + h * 3 + 2] + bl[h * 3 + 2]) * it;
      const float mx = fmaxf(l0, fmaxf(l1, l2));
      const float e0 = __expf(l0 - mx), e1 = __expf(l1 - mx), e2 = __expf(l2 - mx);
      const float is = 1.f / (e0 + e1 + e2);
      pmix[row * 12 + h * 3 + 0] = e0 * is;
      pmix[row * 12 + h * 3 + 1] = e1 * is;
      pmix[row * 12 + h * 3 + 2] = e2 * is;
    }
  }
}

// ---------------------------------------------------------------------------
// Causal depthwise conv (K=4) + SiLU (+ optional l2norm). (unchanged)
// ---------------------------------------------------------------------------
template <int DO_L2>
__global__ __launch_bounds__(256) void conv_act_kernel(
    const float* __restrict__ raw, const float* __restrict__ cw,
    float* __restrict__ out) {
  const int blk = blockIdx.x;
  const int b = blk >> 12, l = blk & (Ln - 1);
  const int t = threadIdx.x;
  float vals[4];
#pragma unroll
  for (int g = 0; g < 4; ++g) {
    const int c = (g << 8) + t;
    float a = 0.f;
#pragma unroll
    for (int j = 0; j < 4; ++j) {
      const int ls = l - 3 + j;
      if (ls >= 0) a = fmaf(cw[c * 4 + j], raw[(((size_t)b << 12) + ls) * 1024 + c], a);
    }
    vals[g] = a * sigmoidf_(a);
  }
  if (DO_L2) {
    __shared__ float red[4][4];
    float ss[4];
#pragma unroll
    for (int g = 0; g < 4; ++g) ss[g] = vals[g] * vals[g];
#pragma unroll
    for (int g = 0; g < 4; ++g)
      for (int off = 32; off; off >>= 1) ss[g] += __shfl_down(ss[g], off);
    const int wave = t >> 6, lane = t & 63;
    if (lane == 0) {
#pragma unroll
      for (int g = 0; g < 4; ++g) red[wave][g] = ss[g];
    }
    __syncthreads();
#pragma unroll
    for (int g = 0; g < 4; ++g) {
      const float s = red[0][g] + red[1][g] + red[2][g] + red[3][g];
      vals[g] *= rsqrtf(s + 1e-6f);
    }
  }
#pragma unroll
  for (int g = 0; g < 4; ++g)
    out[((((size_t)(b * Hn + g)) << 12) + l) * 256 + t] = vals[g];
}

// ---------------------------------------------------------------------------
// Per-chunk precompute (unchanged: emits frag-ready layouts)
// ---------------------------------------------------------------------------
__global__ __launch_bounds__(256) void precomp_kernel(
    const float* __restrict__ q, const float* __restrict__ k,
    const float* __restrict__ v, const float* __restrict__ beta,
    unsigned short* __restrict__ wfrag, unsigned short* __restrict__ qfrag,
    unsigned short* __restrict__ ktfrag, unsigned short* __restrict__ afrag,
    float* __restrict__ u0frag) {
  const int blk = blockIdx.x;
  const int n = blk & 127, bh = blk >> 7;
  const size_t base = (((size_t)bh << 12) + (n << 5)) * 256;
  const size_t cid = (size_t)(bh * NCHn + n);
  __shared__ __align__(16) float qs[32][260];
  __shared__ __align__(16) float ks[32][260];
  __shared__ __align__(16) float vb[32][260];   // v*beta; later reused for w
  __shared__ __align__(16) float u0l[32][260];
  __shared__ float Am[32][33], Tm[32][33], bet[32];
  __shared__ __align__(16) float attn_l[32][36];
  const int t = threadIdx.x;
  if (t < 32) bet[t] = beta[((size_t)bh << 12) + (n << 5) + t];
  __syncthreads();
  for (int idx = t; idx < 32 * 64; idx += 256) {
    const int r = idx >> 6, fi = (idx & 63) << 2;
    *(float4*)&qs[r][fi] = *(const float4*)&q[base + r * 256 + fi];
    *(float4*)&ks[r][fi] = *(const float4*)&k[base + r * 256 + fi];
    float4 vv = *(const float4*)&v[base + r * 256 + fi];
    const float bm = bet[r];
    vv.x *= bm; vv.y *= bm; vv.z *= bm; vv.w *= bm;
    *(float4*)&vb[r][fi] = vv;
  }
  __syncthreads();
  {
    const int i = t >> 3, j0 = t & 7;
    float dq[4] = {0.f, 0.f, 0.f, 0.f}, dk2[4] = {0.f, 0.f, 0.f, 0.f};
    for (int d = 0; d < 256; d += 4) {
      const float4 qi = *(const float4*)&qs[i][d];
      const float4 ki = *(const float4*)&ks[i][d];
#pragma unroll
      for (int jj = 0; jj < 4; ++jj) {
        const float4 kj = *(const float4*)&ks[j0 + (jj << 3)][d];
        dq[jj] = fmaf(qi.x, kj.x, dq[jj]);
        dq[jj] = fmaf(qi.y, kj.y, dq[jj]);
        dq[jj] = fmaf(qi.z, kj.z, dq[jj]);
        dq[jj] = fmaf(qi.w, kj.w, dq[jj]);
        dk2[jj] = fmaf(ki.x, kj.x, dk2[jj]);
        dk2[jj] = fmaf(ki.y, kj.y, dk2[jj]);
        dk2[jj] = fmaf(ki.z, kj.z, dk2[jj]);
        dk2[jj] = fmaf(ki.w, kj.w, dk2[jj]);
      }
    }
    const float bi = bet[i];
#pragma unroll
    for (int jj = 0; jj < 4; ++jj) {
      const int j = j0 + (jj << 3);
      Am[i][j] = bi * dk2[jj];
      attn_l[i][j] = (j <= i) ? dq[jj] : 0.f;
    }
  }
  for (int idx = t; idx < 1024; idx += 256)
    Tm[idx >> 5][idx & 31] = ((idx >> 5) == (idx & 31)) ? 1.f : 0.f;
  __syncthreads();
  for (int i = 1; i < 32; ++i) {
    if (t < 32) {
      float s = 0.f;
      for (int m = 0; m < i; ++m) s = fmaf(Am[i][m], Tm[m][t], s);
      Tm[i][t] = ((i == t) ? 1.f : 0.f) - s;
    }
    __syncthreads();
  }
  {
    const int i = t >> 3;
    const int dj = (t & 7) << 2;
    float4 ua[8], wa[8];
#pragma unroll
    for (int s = 0; s < 8; ++s) {
      ua[s] = make_float4(0.f, 0.f, 0.f, 0.f);
      wa[s] = make_float4(0.f, 0.f, 0.f, 0.f);
    }
    for (int m = 0; m < 32; ++m) {
      const float tim = Tm[i][m];
      const float t2m = tim * bet[m];
#pragma unroll
      for (int s = 0; s < 8; ++s) {
        const int d = dj + (s << 5);
        const float4 vv = *(const float4*)&vb[m][d];
        const float4 kk = *(const float4*)&ks[m][d];
        ua[s].x = fmaf(tim, vv.x, ua[s].x);
        ua[s].y = fmaf(tim, vv.y, ua[s].y);
        ua[s].z = fmaf(tim, vv.z, ua[s].z);
        ua[s].w = fmaf(tim, vv.w, ua[s].w);
        wa[s].x = fmaf(t2m, kk.x, wa[s].x);
        wa[s].y = fmaf(t2m, kk.y, wa[s].y);
        wa[s].z = fmaf(t2m, kk.z, wa[s].z);
        wa[s].w = fmaf(t2m, kk.w, wa[s].w);
      }
    }
    __syncthreads();  // all reads of vb done before overwrite
#pragma unroll
    for (int s = 0; s < 8; ++s) {
      const int d = dj + (s << 5);
      *(float4*)&u0l[i][d] = ua[s];
      *(float4*)&vb[i][d] = wa[s];   // vb now holds w
    }
  }
  __syncthreads();
  // ---- gather-writes to fragment-ready global layouts ----
  const int lane = t & 63;
  const int fg = (lane >> 4) & 3;
#pragma unroll
  for (int it = 0; it < 4; ++it) {
    const int u = it * 4 + (t >> 6);
    const int mi = u >> 3, kw = u & 7;
    const int c = mi * 16 + (lane & 15);
    const int dk0 = kw * 32 + fg * 8;
    const float4 a = *(const float4*)&vb[c][dk0];
    const float4 b2 = *(const float4*)&vb[c][dk0 + 4];
    int4 o;
    o.x = f2bf(a.x) | ((unsigned)f2bf(a.y) << 16);
    o.y = f2bf(a.z) | ((unsigned)f2bf(a.w) << 16);
    o.z = f2bf(b2.x) | ((unsigned)f2bf(b2.y) << 16);
    o.w = f2bf(b2.z) | ((unsigned)f2bf(b2.w) << 16);
    *(int4*)&wfrag[cid * 8192 + u * 512 + lane * 8] = o;
    const float4 qa = *(const float4*)&qs[c][dk0];
    const float4 qb = *(const float4*)&qs[c][dk0 + 4];
    int4 oq;
    oq.x = f2bf(qa.x) | ((unsigned)f2bf(qa.y) << 16);
    oq.y = f2bf(qa.z) | ((unsigned)f2bf(qa.w) << 16);
    oq.z = f2bf(qb.x) | ((unsigned)f2bf(qb.y) << 16);
    oq.w = f2bf(qb.z) | ((unsigned)f2bf(qb.w) << 16);
    *(int4*)&qfrag[cid * 8192 + u * 512 + lane * 8] = oq;
  }
#pragma unroll
  for (int it = 0; it < 4; ++it) {
    const int mi = it * 4 + (t >> 6);
    const int dk = mi * 16 + (lane & 15);
    const int c0 = fg * 8;
    unsigned short e[8];
#pragma unroll
    for (int j = 0; j < 8; ++j) e[j] = f2bf(ks[c0 + j][dk]);
    int4 o;
    o.x = e[0] | ((unsigned)e[1] << 16);
    o.y = e[2] | ((unsigned)e[3] << 16);
    o.z = e[4] | ((unsigned)e[5] << 16);
    o.w = e[6] | ((unsigned)e[7] << 16);
    *(int4*)&ktfrag[cid * 8192 + mi * 512 + lane * 8] = o;
  }
  if (t < 128) {
    const int mi = t >> 6;
    const int c = mi * 16 + (lane & 15);
    const int c0 = fg * 8;
    const float4 a = *(const float4*)&attn_l[c][c0];
    const float4 b2 = *(const float4*)&attn_l[c][c0 + 4];
    int4 o;
    o.x = f2bf(a.x) | ((unsigned)f2bf(a.y) << 16);
    o.y = f2bf(a.z) | ((unsigned)f2bf(a.w) << 16);
    o.z = f2bf(b2.x) | ((unsigned)f2bf(b2.y) << 16);
    o.w = f2bf(b2.z) | ((unsigned)f2bf(b2.w) << 16);
    *(int4*)&afrag[cid * 1024 + mi * 512 + lane * 8] = o;
  }
#pragma unroll
  for (int it = 0; it < 8; ++it) {
    const int u = it * 4 + (t >> 6);
    const int dvs = u >> 1, mi = u & 1;
    const int c0 = mi * 16 + fg * 4;
    const int dv = dvs * 16 + (lane & 15);
    float4 o;
    o.x = u0l[c0 + 0][dv];
    o.y = u0l[c0 + 1][dv];
    o.z = u0l[c0 + 2][dv];
    o.w = u0l[c0 + 3][dv];
    *(float4*)&u0frag[cid * 8192 + u * 256 + lane * 4] = o;
  }
}

// ---------------------------------------------------------------------------
// Scan v6: 2 waves (dk split), A-operands DIRECT global->VGPR (no LDS
// staging; compiler inserts exact counted vmcnt). Single-buffered regs with
// issue-after-consume prefetch. LDS only for St/ut/partials exchanges.
// grid = 128 = 8 bh (XCD-affine) x 16 dv16.
// ---------------------------------------------------------------------------
__global__ __launch_bounds__(128, 1) void scan_mfma(
    const unsigned short* __restrict__ wfrag, const unsigned short* __restrict__ qfrag,
    const unsigned short* __restrict__ ktfrag, const unsigned short* __restrict__ afrag,
    const float* __restrict__ u0frag, float* __restrict__ dout) {
  const int bh = blockIdx.x & 7;
  const int dvs = blockIdx.x >> 3;
  const int tid = threadIdx.x;
  const int w = tid >> 6;
  const int lane = tid & 63;
  const int fr = lane & 15, fg = lane >> 4;
  const int swz = (fr & 7) << 4;
  __shared__ __align__(16) unsigned short St[2][2048];  // per-wave [dv16][dk128]
  __shared__ __align__(16) unsigned short ut[512];      // [dv16][c32]
  __shared__ __align__(16) float pu1[2][256];
  __shared__ __align__(16) float po1[2][256];
  f32x4 S[8];
#pragma unroll
  for (int i = 0; i < 8; ++i) S[i] = (f32x4){0.f, 0.f, 0.f, 0.f};

  const unsigned short* wbase = wfrag + (size_t)(bh * NCHn) * 8192;
  const unsigned short* qbase = qfrag + (size_t)(bh * NCHn) * 8192;
  const unsigned short* kbase = ktfrag + (size_t)(bh * NCHn) * 8192;
  const unsigned short* abase = afrag + (size_t)(bh * NCHn) * 1024;
  const float* ubase = u0frag + (size_t)(bh * NCHn) * 8192 + dvs * 512;

  short8 wr[8], qr[8], ktr[8];
  short8 ar[2] = {};
  f32x4 u0r[2] = {};
  // load chunk 0 operands
#pragma unroll
  for (int u8 = 0; u8 < 8; ++u8) {
    const int mi = u8 >> 2, kwp = u8 & 3;
    const int u = mi * 8 + 4 * w + kwp;
    wr[u8] = *(const short8*)&wbase[u * 512 + lane * 8];
    qr[u8] = *(const short8*)&qbase[u * 512 + lane * 8];
    ktr[u8] = *(const short8*)&kbase[(8 * w + u8) * 512 + lane * 8];
  }
  if (w == 0) {
#pragma unroll
    for (int u = 0; u < 2; ++u) {
      ar[u] = *(const short8*)&abase[u * 512 + lane * 8];
      u0r[u] = *(const f32x4*)&ubase[u * 256 + lane * 4];
    }
  }

  for (int n = 0; n < NCHn; ++n) {
    const int np = (n + 1 < NCHn) ? (n + 1) : n;  // last iter: harmless reload
    // pack S-half -> St[w]  (wave-private; same-wave aliasing ordered by compiler)
#pragma unroll
    for (int mi = 0; mi < 8; ++mi) {
      const unsigned w0 = cvt_pk_bf16(S[mi][0], S[mi][1]);
      const unsigned w1 = cvt_pk_bf16(S[mi][2], S[mi][3]);
      const int a = (fr * 256 + mi * 32 + fg * 8) ^ swz;
      *(uint2*)((char*)&St[w][0] + a) = make_uint2(w0, w1);
    }
    short8 sb[4];
#pragma unroll
    for (int kwp = 0; kwp < 4; ++kwp) {
      const int a = (fr * 256 + kwp * 64 + fg * 16) ^ swz;
      sb[kwp] = *(const short8*)((const char*)&St[w][0] + a);
    }
    // partial w@S, q@S over own dk half (consumes wr, qr)
    f32x4 up[2], oq[2];
    up[0] = up[1] = (f32x4){0.f, 0.f, 0.f, 0.f};
    oq[0] = oq[1] = (f32x4){0.f, 0.f, 0.f, 0.f};
#pragma unroll
    for (int kwp = 0; kwp < 4; ++kwp) {
#pragma unroll
      for (int mi = 0; mi < 2; ++mi) {
        up[mi] = __builtin_amdgcn_mfma_f32_16x16x32_bf16(wr[mi * 4 + kwp], sb[kwp], up[mi], 0, 0, 0);
        oq[mi] = __builtin_amdgcn_mfma_f32_16x16x32_bf16(qr[mi * 4 + kwp], sb[kwp], oq[mi], 0, 0, 0);
      }
    }
    // prefetch next chunk's w/q into the just-freed regs
    {
      const unsigned short* wp = wbase + (size_t)np * 8192;
      const unsigned short* qp = qbase + (size_t)np * 8192;
#pragma unroll
      for (int u8 = 0; u8 < 8; ++u8) {
        const int mi = u8 >> 2, kwp = u8 & 3;
        const int u = mi * 8 + 4 * w + kwp;
        wr[u8] = *(const short8*)&wp[u * 512 + lane * 8];
        qr[u8] = *(const short8*)&qp[u * 512 + lane * 8];
      }
    }
    // wave1 ships partials
    if (w == 1) {
#pragma unroll
      for (int mi = 0; mi < 2; ++mi) {
        *(f32x4*)&pu1[mi][lane * 4] = up[mi];
        *(f32x4*)&po1[mi][lane * 4] = oq[mi];
      }
      asm volatile("s_waitcnt lgkmcnt(0)" ::: "memory");
    }
    __builtin_amdgcn_s_barrier();  // barrier1: partials visible
    __builtin_amdgcn_sched_barrier(0);
    f32x4 o_f[2];
    if (w == 0) {
#pragma unroll
      for (int mi = 0; mi < 2; ++mi) {
        const f32x4 p1 = *(const f32x4*)&pu1[mi][lane * 4];
        const f32x4 uu = u0r[mi] - up[mi] - p1;
        const unsigned w0 = cvt_pk_bf16(uu[0], uu[1]);
        const unsigned w1 = cvt_pk_bf16(uu[2], uu[3]);
        const int a = (fr * 64 + mi * 32 + fg * 8) ^ swz;
        *(uint2*)((char*)ut + a) = make_uint2(w0, w1);
        o_f[mi] = oq[mi] + *(const f32x4*)&po1[mi][lane * 4];
      }
      asm volatile("s_waitcnt lgkmcnt(0)" ::: "memory");
    }
    __builtin_amdgcn_s_barrier();  // barrier2: ut visible
    __builtin_amdgcn_sched_barrier(0);
    const short8 ub = *(const short8*)((const char*)ut + ((fr * 64 + fg * 16) ^ swz));
    if (w == 0) {
      // o = q@S + attn@u (consumes ar), then prefetch ar/u0r, then store
#pragma unroll
      for (int mi = 0; mi < 2; ++mi)
        o_f[mi] = __builtin_amdgcn_mfma_f32_16x16x32_bf16(ar[mi], ub, o_f[mi], 0, 0, 0);
      const unsigned short* ap = abase + (size_t)np * 1024;
      const float* up_ = ubase + (size_t)np * 8192;
#pragma unroll
      for (int u = 0; u < 2; ++u) {
        ar[u] = *(const short8*)&ap[u * 512 + lane * 8];
        u0r[u] = *(const f32x4*)&up_[u * 256 + lane * 4];
      }
      const size_t cb = ((size_t)((bh << 12) + (n << 5))) * 256;
#pragma unroll
      for (int mi = 0; mi < 2; ++mi)
#pragma unroll
        for (int r = 0; r < 4; ++r)
          dout[cb + (size_t)(mi * 16 + fg * 4 + r) * 256 + dvs * 16 + fr] = o_f[mi][r];
    }
    // S-half += k^T @ u (consumes ktr)
#pragma unroll
    for (int mi = 0; mi < 8; ++mi)
      S[mi] = __builtin_amdgcn_mfma_f32_16x16x32_bf16(ktr[mi], ub, S[mi], 0, 0, 0);
    // prefetch next ktr
    {
      const unsigned short* kp = kbase + (size_t)np * 8192;
#pragma unroll
      for (int u8 = 0; u8 < 8; ++u8)
        ktr[u8] = *(const short8*)&kp[(8 * w + u8) * 512 + lane * 8];
    }
  }
}

// ---------------------------------------------------------------------------
// Mix: streaming FIR along l with register ring buffer. grid = 512.
// ---------------------------------------------------------------------------
#define MIX_LT 64
__global__ __launch_bounds__(256) void mix_kernel(
    const float* __restrict__ v, const float* __restrict__ delta,
    const float* __restrict__ wgl, const float* __restrict__ pmix,
    const float* __restrict__ firs, const float* __restrict__ firl,
    const float* __restrict__ rms_w, unsigned short* __restrict__ out) {
  const int wgid = ((int)blockIdx.x & 7) * 64 + ((int)blockIdx.x >> 3);
  const int b = wgid >> 8;
  const int h = (wgid >> 6) & 3;
  const int lt = wgid & 63;
  const int l0 = lt * MIX_LT;
  const int t = threadIdx.x;
  const int wv = t >> 6, lane = t & 63;
  const float* vcol = v + ((((size_t)(b * Hn + h)) << 12)) * 256 + t;
  const float* dcol = delta + ((((size_t)(b * Hn + h)) << 12)) * 256 + t;
  float fw[31], fs3[3];
#pragma unroll
  for (int j = 0; j < 31; ++j) fw[j] = firl[((h << 8) + t) * 31 + j];
#pragma unroll
  for (int j = 0; j < 3; ++j) fs3[j] = firs[((h << 8) + t) * 3 + j];
  const float rw = rms_w[t];
  float win[31];
#pragma unroll
  for (int j = 0; j < 30; ++j) {
    const int ls = l0 - 30 + j;
    win[j] = (ls >= 0) ? vcol[(size_t)ls * 256] : 0.f;
  }
  win[30] = 0.f;
  __shared__ float wred[MIX_LT * 4];
  float o[MIX_LT];
#pragma unroll
  for (int i = 0; i < MIX_LT; ++i) {
    const int l = l0 + i;
    const float vnew = vcol[(size_t)l * 256];
    float lo = fw[30] * vnew;
#pragma unroll
    for (int j = 0; j < 30; ++j) lo = fmaf(fw[j], win[(i + j) % 31], lo);
    float sh = fs3[2] * vnew;
    sh = fmaf(fs3[1], win[(i + 29) % 31], sh);
    sh = fmaf(fs3[0], win[(i + 28) % 31], sh);
    win[(i + 30) % 31] = vnew;
    const int row = (b << 12) + l;
    const float p0 = pmix[row * 12 + h * 3 + 0];
    const float p1 = pmix[row * 12 + h * 3 + 1];
    const float p2 = pmix[row * 12 + h * 3 + 2];
    const float wg = wgl[row * 4 + h];
    const float mixv = p0 * vnew + p1 * sh + p2 * lo;
    const float oo = wg * dcol[(size_t)l * 256] + (1.f - wg) * mixv;
    o[i] = oo;
    float ss = oo * oo;
#pragma unroll
    for (int m = 1; m < 64; m <<= 1) ss += __shfl_xor(ss, m);
    if (lane == 0) wred[i * 4 + wv] = ss;
  }
  __syncthreads();
#pragma unroll
  for (int i = 0; i < MIX_LT; ++i) {
    const float sum = wred[i * 4] + wred[i * 4 + 1] + wred[i * 4 + 2] + wred[i * 4 + 3];
    const float sc = rsqrtf(sum * (1.f / 256.f) + 1e-5f);
    const int l = l0 + i;
    out[(size_t)((b << 12) + l) * 1024 + (h << 8) + t] = f2bf(o[i] * sc * rw);
  }
}

// ---------------------------------------------------------------------------
extern "C" void kernel_launch(void* const* d_in, const int* in_sizes, int n_in,
                              void* d_out, int out_size, void* d_ws, size_t ws_size,
                              hipStream_t stream) {
  const float* x = (const float*)d_in[0];
  const float* Wq = (const float*)d_in[1];
  const float* Wk = (const float*)d_in[2];
  const float* Wv = (const float*)d_in[3];
  const float* cq = (const float*)d_in[4];
  const float* ck = (const float*)d_in[5];
  const float* cv = (const float*)d_in[6];
  const float* Wb = (const float*)d_in[7];
  const float* firs = (const float*)d_in[8];
  const float* firl = (const float*)d_in[9];
  const float* Wg = (const float*)d_in[10];
  const float* bg = (const float*)d_in[11];
  const float* Wl = (const float*)d_in[12];
  const float* bl = (const float*)d_in[13];
  const float* ltemp = (const float*)d_in[14];
  const float* rmsw = (const float*)d_in[15];
  const float* Wo = (const float*)d_in[16];

  float* ws = (float*)d_ws;
  const size_t NE = (size_t)Bn * Ln * 1024;  // 8.39M floats
  float* qraw = ws;
  float* kraw = ws + NE;
  float* vraw = ws + 2 * NE;
  float* qn = ws + 3 * NE;
  float* kn = ws + 4 * NE;
  float* vn = ws + 5 * NE;
  float* beta = ws + 6 * NE;
  float* wgl = beta + (size_t)Bn * Hn * Ln;
  float* pmix = wgl + (size_t)Bn * Ln * Hn;
  float* attn_unused = pmix + (size_t)Bn * Ln * Hn * 3;
  unsigned short* Wot = (unsigned short*)(attn_unused + (size_t)Bn * Hn * NCHn * 1024);
  unsigned short* xb = (unsigned short*)qn;
  unsigned short* Wqt = (unsigned short*)(qn + 4194304);
  unsigned short* Wkt = Wqt + 1048576;
  unsigned short* Wvt = Wkt + 1048576;
  unsigned short* normed_bf = (unsigned short*)kn;  // kn dead after precomp
  unsigned short* wfrag = (unsigned short*)qraw;
  unsigned short* qfrag = wfrag + 8388608;
  unsigned short* ktfrag = (unsigned short*)kraw;
  unsigned short* afrag = ktfrag + 8388608;
  float* u0frag = qn;   // exact per-chunk slot overlay of qn
  float* dbuf = vraw;

  const dim3 wtg(32, 32);
  wt_kernel<<<wtg, 256, 0, stream>>>(Wq, Wqt, 1024, 1024);
  wt_kernel<<<wtg, 256, 0, stream>>>(Wk, Wkt, 1024, 1024);
  wt_kernel<<<wtg, 256, 0, stream>>>(Wv, Wvt, 1024, 1024);
  wt_kernel<<<wtg, 256, 0, stream>>>(Wo, Wot, 1024, 1024);
  f2bf_kernel<<<(int)(NE / 1024), 256, 0, stream>>>(x, xb, (int)NE);

  const dim3 gg(8, 64);  // N/128, M/128
  gemm_bf16<<<gg, 256, 0, stream>>>(xb, Wqt, qraw, Bn * Ln, 1024, 1024);
  gemm_bf16<<<gg, 256, 0, stream>>>(xb, Wkt, kraw, Bn * Ln, 1024, 1024);
  gemm_bf16<<<gg, 256, 0, stream>>>(xb, Wvt, vraw, Bn * Ln, 1024, 1024);
  gates_kernel<<<Bn * Ln / 4, 256, 0, stream>>>(x, Wb, Wg, bg, Wl, bl, ltemp,
                                                beta, wgl, pmix);
  conv_act_kernel<1><<<Bn * Ln, 256, 0, stream>>>(qraw, cq, qn);
  conv_act_kernel<1><<<Bn * Ln, 256, 0, stream>>>(kraw, ck, kn);
  conv_act_kernel<0><<<Bn * Ln, 256, 0, stream>>>(vraw, cv, vn);
  precomp_kernel<<<Bn * Hn * NCHn, 256, 0, stream>>>(qn, kn, vn, beta, wfrag,
                                                     qfrag, ktfrag, afrag, u0frag);
  scan_mfma<<<128, 128, 0, stream>>>(wfrag, qfrag, ktfrag, afrag, u0frag, dbuf);
  mix_kernel<<<Bn * Hn * (Ln / MIX_LT), 256, 0, stream>>>(
      vn, dbuf, wgl, pmix, firs, firl, rmsw, normed_bf);
  gemm_bf16<<<gg, 256, 0, stream>>>(normed_bf, Wot, (float*)d_out, Bn * Ln, 1024, 1024);
}

// Round 9
// 565.397 us; speedup vs baseline: 5.5812x; 1.1499x over previous
//
#include <hip/hip_runtime.h>
#include <hip/hip_bf16.h>
#include <math.h>

#define Bn 2
#define Ln 4096
#define Dn 1024
#define Hn 4
#define DKn 256
#define DVn 256
#define NCHn 128  // L/32 chunks

typedef __attribute__((ext_vector_type(8))) short short8;
typedef __attribute__((ext_vector_type(4))) float f32x4;

__device__ __forceinline__ float sigmoidf_(float x) { return 1.f / (1.f + __expf(-x)); }

__device__ __forceinline__ unsigned short f2bf(float f) {
  union { float f; unsigned u; } v; v.f = f;
  unsigned r = v.u + 0x7FFFu + ((v.u >> 16) & 1u);
  return (unsigned short)(r >> 16);
}

__device__ __forceinline__ unsigned cvt_pk_bf16(float a, float b) {
  unsigned r;
  asm volatile("v_cvt_pk_bf16_f32 %0, %1, %2" : "=v"(r) : "v"(a), "v"(b));
  return r;
}

__device__ __forceinline__ short8 pack_i4(int4 o) {
  short8 r;
  __builtin_memcpy(&r, &o, 16);
  return r;
}

__device__ __forceinline__ void gl2lds16(const void* g, void* l) {
  __builtin_amdgcn_global_load_lds((const __attribute__((address_space(1))) unsigned int*)g,
                                   (__attribute__((address_space(3))) unsigned int*)l, 16, 0, 0);
}

// ---------------------------------------------------------------------------
// Weight transpose + bf16 convert: Wt[n][k] = bf16(W[k][n]), K=N=1024.
// ---------------------------------------------------------------------------
__global__ __launch_bounds__(256) void wt_kernel(const float* __restrict__ W,
                                                 unsigned short* __restrict__ Wt,
                                                 int K, int N) {
  __shared__ float tile[32][33];
  const int bx = blockIdx.x * 32;  // n
  const int by = blockIdx.y * 32;  // k
  const int tx = threadIdx.x & 31, ty4 = (threadIdx.x >> 5) * 4;
#pragma unroll
  for (int r = 0; r < 4; ++r)
    tile[ty4 + r][tx] = W[(size_t)(by + ty4 + r) * N + bx + tx];
  __syncthreads();
#pragma unroll
  for (int r = 0; r < 4; ++r)
    Wt[(size_t)(bx + ty4 + r) * K + by + tx] = f2bf(tile[tx][ty4 + r]);
}

// ---------------------------------------------------------------------------
// fp32 -> bf16 elementwise, n % 1024 == 0
// ---------------------------------------------------------------------------
__global__ __launch_bounds__(256) void f2bf_kernel(const float* __restrict__ in,
                                                   unsigned short* __restrict__ out,
                                                   int n) {
  const int i4 = (blockIdx.x * 256 + threadIdx.x) * 4;
  if (i4 >= n) return;
  const float4 v = *(const float4*)&in[i4];
  ushort4 o;
  o.x = f2bf(v.x); o.y = f2bf(v.y); o.z = f2bf(v.z); o.w = f2bf(v.w);
  *(ushort4*)&out[i4] = o;
}

// ---------------------------------------------------------------------------
// bf16 MFMA GEMM: C[M,N] f32 = A[M,K]bf16 @ Bt[N,K]bf16^T. 128x128 tile, BK=32.
// ---------------------------------------------------------------------------
__global__ __launch_bounds__(256, 2) void gemm_bf16(const unsigned short* __restrict__ A,
                                                    const unsigned short* __restrict__ Bt,
                                                    float* __restrict__ C,
                                                    int M, int N, int K) {
  __shared__ __align__(16) unsigned short As[128 * 32];
  __shared__ __align__(16) unsigned short Bs[128 * 32];
  const int tid = threadIdx.x;
  const int wid = tid >> 6, lane = tid & 63;
  const int row0 = blockIdx.y * 128, col0 = blockIdx.x * 128;
  const int wr64 = (wid >> 1) * 64, wc64 = (wid & 1) * 64;
  const int fr = lane & 15, fg = lane >> 4;
  f32x4 acc[4][4];
#pragma unroll
  for (int i = 0; i < 4; ++i)
#pragma unroll
    for (int j = 0; j < 4; ++j) acc[i][j] = (f32x4){0.f, 0.f, 0.f, 0.f};
  for (int k0 = 0; k0 < K; k0 += 32) {
#pragma unroll
    for (int i = 0; i < 2; ++i) {
      const int off = wid * 2048 + i * 1024 + (lane << 4);  // LDS byte offset
      const int r = off >> 6;                               // tile row
      const int kb = off & 63;                              // byte within row
      gl2lds16((const char*)A + ((size_t)(row0 + r) * K + k0) * 2 + kb, (char*)As + off);
      gl2lds16((const char*)Bt + ((size_t)(col0 + r) * K + k0) * 2 + kb, (char*)Bs + off);
    }
    __syncthreads();
    short8 a[4], b[4];
#pragma unroll
    for (int mi = 0; mi < 4; ++mi)
      a[mi] = *(const short8*)&As[(wr64 + mi * 16 + fr) * 32 + fg * 8];
#pragma unroll
    for (int ni = 0; ni < 4; ++ni)
      b[ni] = *(const short8*)&Bs[(wc64 + ni * 16 + fr) * 32 + fg * 8];
#pragma unroll
    for (int mi = 0; mi < 4; ++mi)
#pragma unroll
      for (int ni = 0; ni < 4; ++ni)
        acc[mi][ni] = __builtin_amdgcn_mfma_f32_16x16x32_bf16(a[mi], b[ni], acc[mi][ni], 0, 0, 0);
    __syncthreads();
  }
#pragma unroll
  for (int mi = 0; mi < 4; ++mi) {
    const int orow = row0 + wr64 + mi * 16 + fg * 4;
#pragma unroll
    for (int ni = 0; ni < 4; ++ni) {
      const int ocol = col0 + wc64 + ni * 16 + fr;
#pragma unroll
      for (int r = 0; r < 4; ++r)
        C[(size_t)(orow + r) * N + ocol] = acc[mi][ni][r];
    }
  }
}

// ---------------------------------------------------------------------------
// Gate projections (unchanged)
// ---------------------------------------------------------------------------
__global__ __launch_bounds__(256) void gates_kernel(
    const float* __restrict__ x, const float* __restrict__ Wb,
    const float* __restrict__ Wg, const float* __restrict__ bg,
    const float* __restrict__ Wl, const float* __restrict__ bl,
    const float* __restrict__ log_temp, float* __restrict__ beta,
    float* __restrict__ wgl, float* __restrict__ pmix) {
  const int wave = threadIdx.x >> 6, lane = threadIdx.x & 63;
  const int row = (blockIdx.x << 2) + wave;
  if (row >= Bn * Ln) return;
  const float* xr = x + (size_t)row * Dn;
  float acc[20];
#pragma unroll
  for (int c = 0; c < 20; ++c) acc[c] = 0.f;
#pragma unroll
  for (int i = 0; i < 4; ++i) {
    const float4 xv = *(const float4*)&xr[(lane << 2) + (i << 8)];
    const float xa[4] = {xv.x, xv.y, xv.z, xv.w};
#pragma unroll
    for (int j = 0; j < 4; ++j) {
      const int kk = (i << 8) + (lane << 2) + j;
      const float xx = xa[j];
#pragma unroll
      for (int h = 0; h < 4; ++h) acc[h] = fmaf(xx, Wb[kk * 4 + h], acc[h]);
#pragma unroll
      for (int h = 0; h < 4; ++h) acc[4 + h] = fmaf(xx, Wg[kk * 4 + h], acc[4 + h]);
#pragma unroll
      for (int c = 0; c < 12; ++c) acc[8 + c] = fmaf(xx, Wl[kk * 12 + c], acc[8 + c]);
    }
  }
#pragma unroll
  for (int c = 0; c < 20; ++c)
    for (int off = 32; off; off >>= 1) acc[c] += __shfl_down(acc[c], off);
  if (lane == 0) {
    const int b = row >> 12, l = row & (Ln - 1);
#pragma unroll
    for (int h = 0; h < 4; ++h)
      beta[((size_t)(b * Hn + h) << 12) + l] = sigmoidf_(acc[h]);
#pragma unroll
    for (int h = 0; h < 4; ++h) wgl[row * 4 + h] = sigmoidf_(acc[4 + h] + bg[h]);
#pragma unroll
    for (int h = 0; h < 4; ++h) {
      const float it = 1.f / __expf(log_temp[h]);
      const float l0 = (acc[8 + h * 3 + 0] + bl[h * 3 + 0]) * it;
      const float l1 = (acc[8 + h * 3 + 1] + bl[h * 3 + 1]) * it;
      const float l2 = (acc[8 + h * 3 + 2] + bl[h * 3 + 2]) * it;
      const float mx = fmaxf(l0, fmaxf(l1, l2));
      const float e0 = __expf(l0 - mx), e1 = __expf(l1 - mx), e2 = __expf(l2 - mx);
      const float is = 1.f / (e0 + e1 + e2);
      pmix[row * 12 + h * 3 + 0] = e0 * is;
      pmix[row * 12 + h * 3 + 1] = e1 * is;
      pmix[row * 12 + h * 3 + 2] = e2 * is;
    }
  }
}

// ---------------------------------------------------------------------------
// Causal depthwise conv (K=4) + SiLU (+ optional l2norm). (unchanged)
// ---------------------------------------------------------------------------
template <int DO_L2>
__global__ __launch_bounds__(256) void conv_act_kernel(
    const float* __restrict__ raw, const float* __restrict__ cw,
    float* __restrict__ out) {
  const int blk = blockIdx.x;
  const int b = blk >> 12, l = blk & (Ln - 1);
  const int t = threadIdx.x;
  float vals[4];
#pragma unroll
  for (int g = 0; g < 4; ++g) {
    const int c = (g << 8) + t;
    float a = 0.f;
#pragma unroll
    for (int j = 0; j < 4; ++j) {
      const int ls = l - 3 + j;
      if (ls >= 0) a = fmaf(cw[c * 4 + j], raw[(((size_t)b << 12) + ls) * 1024 + c], a);
    }
    vals[g] = a * sigmoidf_(a);
  }
  if (DO_L2) {
    __shared__ float red[4][4];
    float ss[4];
#pragma unroll
    for (int g = 0; g < 4; ++g) ss[g] = vals[g] * vals[g];
#pragma unroll
    for (int g = 0; g < 4; ++g)
      for (int off = 32; off; off >>= 1) ss[g] += __shfl_down(ss[g], off);
    const int wave = t >> 6, lane = t & 63;
    if (lane == 0) {
#pragma unroll
      for (int g = 0; g < 4; ++g) red[wave][g] = ss[g];
    }
    __syncthreads();
#pragma unroll
    for (int g = 0; g < 4; ++g) {
      const float s = red[0][g] + red[1][g] + red[2][g] + red[3][g];
      vals[g] *= rsqrtf(s + 1e-6f);
    }
  }
#pragma unroll
  for (int g = 0; g < 4; ++g)
    out[((((size_t)(b * Hn + g)) << 12) + l) * 256 + t] = vals[g];
}

// ---------------------------------------------------------------------------
// Precomp v2: MFMA for all four matmuls, barrier-free substitution,
// bf16 LDS (64 KB -> 2 blocks/CU). Outputs identical frag layouts.
// ---------------------------------------------------------------------------
__global__ __launch_bounds__(256, 2) void precomp_kernel(
    const float* __restrict__ q, const float* __restrict__ k,
    const float* __restrict__ v, const float* __restrict__ beta,
    unsigned short* __restrict__ wfrag, unsigned short* __restrict__ qfrag,
    unsigned short* __restrict__ ktfrag, unsigned short* __restrict__ afrag,
    float* __restrict__ u0frag) {
  const int blk = blockIdx.x;
  const int n = blk & 127, bh = blk >> 7;
  const size_t base = (((size_t)bh << 12) + (n << 5)) * 256;
  const size_t cid = (size_t)(bh * NCHn + n);
  __shared__ __align__(16) unsigned short ksb[32][264];
  __shared__ __align__(16) unsigned short qsb[32][264];  // later reused for w staging
  __shared__ __align__(16) unsigned short vbb[32][264];
  __shared__ float Tm[32][33], Am[32][33], bet[32];
  __shared__ __align__(16) float attn_l[32][36];
  const int t = threadIdx.x;
  const int wid = t >> 6, lane = t & 63;
  const int fr = lane & 15, fg = lane >> 4;
  if (t < 32) bet[t] = beta[((size_t)bh << 12) + (n << 5) + t];
  // ---- load + f32->bf16 convert (v scaled by beta) ----
#pragma unroll
  for (int it = 0; it < 4; ++it) {
    const int idx = t + it * 256;
    const int r = idx >> 5, c8 = (idx & 31) << 3;
    const float bv = beta[((size_t)bh << 12) + (n << 5) + r];
    const float4 q0 = *(const float4*)&q[base + r * 256 + c8];
    const float4 q1 = *(const float4*)&q[base + r * 256 + c8 + 4];
    const float4 k0 = *(const float4*)&k[base + r * 256 + c8];
    const float4 k1 = *(const float4*)&k[base + r * 256 + c8 + 4];
    const float4 v0 = *(const float4*)&v[base + r * 256 + c8];
    const float4 v1 = *(const float4*)&v[base + r * 256 + c8 + 4];
    int4 oq, ok, ov;
    oq.x = cvt_pk_bf16(q0.x, q0.y); oq.y = cvt_pk_bf16(q0.z, q0.w);
    oq.z = cvt_pk_bf16(q1.x, q1.y); oq.w = cvt_pk_bf16(q1.z, q1.w);
    ok.x = cvt_pk_bf16(k0.x, k0.y); ok.y = cvt_pk_bf16(k0.z, k0.w);
    ok.z = cvt_pk_bf16(k1.x, k1.y); ok.w = cvt_pk_bf16(k1.z, k1.w);
    ov.x = cvt_pk_bf16(v0.x * bv, v0.y * bv); ov.y = cvt_pk_bf16(v0.z * bv, v0.w * bv);
    ov.z = cvt_pk_bf16(v1.x * bv, v1.y * bv); ov.w = cvt_pk_bf16(v1.z * bv, v1.w * bv);
    *(int4*)&qsb[r][c8] = oq;
    *(int4*)&ksb[r][c8] = ok;
    *(int4*)&vbb[r][c8] = ov;
  }
  __syncthreads();  // bar1: LDS + bet staged
  // ---- phase 2: G = k@k^T, At = q@k^T via MFMA (wave = 16x16 tile) ----
  {
    const int ti = wid >> 1, tj = wid & 1;
    f32x4 G = (f32x4){0.f, 0.f, 0.f, 0.f};
    f32x4 At = (f32x4){0.f, 0.f, 0.f, 0.f};
#pragma unroll
    for (int kw = 0; kw < 8; ++kw) {
      const short8 krow = *(const short8*)&ksb[ti * 16 + fr][kw * 32 + fg * 8];
      const short8 kcol = *(const short8*)&ksb[tj * 16 + fr][kw * 32 + fg * 8];
      const short8 qrow = *(const short8*)&qsb[ti * 16 + fr][kw * 32 + fg * 8];
      G = __builtin_amdgcn_mfma_f32_16x16x32_bf16(krow, kcol, G, 0, 0, 0);
      At = __builtin_amdgcn_mfma_f32_16x16x32_bf16(qrow, kcol, At, 0, 0, 0);
    }
#pragma unroll
    for (int r_ = 0; r_ < 4; ++r_) {
      const int i = ti * 16 + fg * 4 + r_;
      const int j = tj * 16 + fr;
      Am[i][j] = bet[i] * G[r_];
      attn_l[i][j] = (j <= i) ? At[r_] : 0.f;
    }
  }
  // ---- qfrag / ktfrag gathers (read-only on qsb/ksb) ----
#pragma unroll
  for (int it = 0; it < 4; ++it) {
    const int u = it * 4 + wid;
    const int mi = u >> 3, kw = u & 7;
    *(int4*)&qfrag[cid * 8192 + u * 512 + lane * 8] =
        *(const int4*)&qsb[mi * 16 + fr][kw * 32 + fg * 8];
  }
#pragma unroll
  for (int it = 0; it < 4; ++it) {
    const int mi = it * 4 + wid;
    const int dk = mi * 16 + fr;
    unsigned short e[8];
#pragma unroll
    for (int j = 0; j < 8; ++j) e[j] = ksb[fg * 8 + j][dk];
    int4 o;
    o.x = e[0] | ((unsigned)e[1] << 16);
    o.y = e[2] | ((unsigned)e[3] << 16);
    o.z = e[4] | ((unsigned)e[5] << 16);
    o.w = e[6] | ((unsigned)e[7] << 16);
    *(int4*)&ktfrag[cid * 8192 + mi * 512 + lane * 8] = o;
  }
  __syncthreads();  // bar2: Am / attn_l visible
  // ---- afrag (waves 2,3) ----
  if (t >= 128) {
    const int mi = (t >> 6) - 2;
    const int c = mi * 16 + fr;
    const float4 a = *(const float4*)&attn_l[c][fg * 8];
    const float4 b2 = *(const float4*)&attn_l[c][fg * 8 + 4];
    int4 o;
    o.x = f2bf(a.x) | ((unsigned)f2bf(a.y) << 16);
    o.y = f2bf(a.z) | ((unsigned)f2bf(a.w) << 16);
    o.z = f2bf(b2.x) | ((unsigned)f2bf(b2.y) << 16);
    o.w = f2bf(b2.z) | ((unsigned)f2bf(b2.w) << 16);
    *(int4*)&afrag[cid * 1024 + mi * 512 + lane * 8] = o;
  }
  // ---- forward substitution: lane t owns T column t, no barriers ----
  if (t < 32) {
    float Tcol[32];
    Tcol[0] = (t == 0) ? 1.f : 0.f;
#pragma unroll
    for (int i = 1; i < 32; ++i) {
      float s0 = 0.f, s1 = 0.f;
      int m = 0;
#pragma unroll
      for (; m + 2 <= i; m += 2) {
        s0 = fmaf(Am[i][m], Tcol[m], s0);
        s1 = fmaf(Am[i][m + 1], Tcol[m + 1], s1);
      }
      if (m < i) s0 = fmaf(Am[i][m], Tcol[m], s0);
      Tcol[i] = ((i == t) ? 1.f : 0.f) - s0 - s1;
    }
#pragma unroll
    for (int i = 0; i < 32; ++i) Tm[i][t] = Tcol[i];
  }
  __syncthreads();  // bar3: Tm visible
  // ---- u0 = T@vb, w = (T.beta)@k via MFMA (K=32, one MFMA per tile) ----
  {
    float betr[8];
#pragma unroll
    for (int j = 0; j < 8; ++j) betr[j] = bet[fg * 8 + j];
    short8 Tf[2], Tbf[2];
#pragma unroll
    for (int mi = 0; mi < 2; ++mi) {
      float tv[8];
#pragma unroll
      for (int j = 0; j < 8; ++j) tv[j] = Tm[mi * 16 + fr][fg * 8 + j];
      int4 p, pb;
      p.x = cvt_pk_bf16(tv[0], tv[1]); p.y = cvt_pk_bf16(tv[2], tv[3]);
      p.z = cvt_pk_bf16(tv[4], tv[5]); p.w = cvt_pk_bf16(tv[6], tv[7]);
      pb.x = cvt_pk_bf16(tv[0] * betr[0], tv[1] * betr[1]);
      pb.y = cvt_pk_bf16(tv[2] * betr[2], tv[3] * betr[3]);
      pb.z = cvt_pk_bf16(tv[4] * betr[4], tv[5] * betr[5]);
      pb.w = cvt_pk_bf16(tv[6] * betr[6], tv[7] * betr[7]);
      Tf[mi] = pack_i4(p);
      Tbf[mi] = pack_i4(pb);
    }
    const f32x4 zero = (f32x4){0.f, 0.f, 0.f, 0.f};
#pragma unroll
    for (int tt = 0; tt < 4; ++tt) {
      const int tjc = wid * 4 + tt;
      unsigned short ev[8], ek[8];
#pragma unroll
      for (int j = 0; j < 8; ++j) {
        ev[j] = vbb[fg * 8 + j][tjc * 16 + fr];
        ek[j] = ksb[fg * 8 + j][tjc * 16 + fr];
      }
      int4 pv, pk;
      pv.x = ev[0] | ((unsigned)ev[1] << 16); pv.y = ev[2] | ((unsigned)ev[3] << 16);
      pv.z = ev[4] | ((unsigned)ev[5] << 16); pv.w = ev[6] | ((unsigned)ev[7] << 16);
      pk.x = ek[0] | ((unsigned)ek[1] << 16); pk.y = ek[2] | ((unsigned)ek[3] << 16);
      pk.z = ek[4] | ((unsigned)ek[5] << 16); pk.w = ek[6] | ((unsigned)ek[7] << 16);
      const short8 vbf = pack_i4(pv);
      const short8 kbf = pack_i4(pk);
#pragma unroll
      for (int mi = 0; mi < 2; ++mi) {
        const f32x4 U = __builtin_amdgcn_mfma_f32_16x16x32_bf16(Tf[mi], vbf, zero, 0, 0, 0);
        *(f32x4*)&u0frag[cid * 8192 + (tjc * 2 + mi) * 256 + lane * 4] = U;
        const f32x4 W = __builtin_amdgcn_mfma_f32_16x16x32_bf16(Tbf[mi], kbf, zero, 0, 0, 0);
#pragma unroll
        for (int r_ = 0; r_ < 4; ++r_)
          qsb[mi * 16 + fg * 4 + r_][tjc * 16 + fr] = f2bf(W[r_]);
      }
    }
  }
  __syncthreads();  // bar4: w staging (in qsb) visible
  // ---- wfrag gather from staged w ----
#pragma unroll
  for (int it = 0; it < 4; ++it) {
    const int u = it * 4 + wid;
    const int mi = u >> 3, kw = u & 7;
    *(int4*)&wfrag[cid * 8192 + u * 512 + lane * 8] =
        *(const int4*)&qsb[mi * 16 + fr][kw * 32 + fg * 8];
  }
}

// ---------------------------------------------------------------------------
// Scan v6 (unchanged from round 8)
// ---------------------------------------------------------------------------
__global__ __launch_bounds__(128, 1) void scan_mfma(
    const unsigned short* __restrict__ wfrag, const unsigned short* __restrict__ qfrag,
    const unsigned short* __restrict__ ktfrag, const unsigned short* __restrict__ afrag,
    const float* __restrict__ u0frag, float* __restrict__ dout) {
  const int bh = blockIdx.x & 7;
  const int dvs = blockIdx.x >> 3;
  const int tid = threadIdx.x;
  const int w = tid >> 6;
  const int lane = tid & 63;
  const int fr = lane & 15, fg = lane >> 4;
  const int swz = (fr & 7) << 4;
  __shared__ __align__(16) unsigned short St[2][2048];  // per-wave [dv16][dk128]
  __shared__ __align__(16) unsigned short ut[512];      // [dv16][c32]
  __shared__ __align__(16) float pu1[2][256];
  __shared__ __align__(16) float po1[2][256];
  f32x4 S[8];
#pragma unroll
  for (int i = 0; i < 8; ++i) S[i] = (f32x4){0.f, 0.f, 0.f, 0.f};

  const unsigned short* wbase = wfrag + (size_t)(bh * NCHn) * 8192;
  const unsigned short* qbase = qfrag + (size_t)(bh * NCHn) * 8192;
  const unsigned short* kbase = ktfrag + (size_t)(bh * NCHn) * 8192;
  const unsigned short* abase = afrag + (size_t)(bh * NCHn) * 1024;
  const float* ubase = u0frag + (size_t)(bh * NCHn) * 8192 + dvs * 512;

  short8 wr[8], qr[8], ktr[8];
  short8 ar[2] = {};
  f32x4 u0r[2] = {};
#pragma unroll
  for (int u8 = 0; u8 < 8; ++u8) {
    const int mi = u8 >> 2, kwp = u8 & 3;
    const int u = mi * 8 + 4 * w + kwp;
    wr[u8] = *(const short8*)&wbase[u * 512 + lane * 8];
    qr[u8] = *(const short8*)&qbase[u * 512 + lane * 8];
    ktr[u8] = *(const short8*)&kbase[(8 * w + u8) * 512 + lane * 8];
  }
  if (w == 0) {
#pragma unroll
    for (int u = 0; u < 2; ++u) {
      ar[u] = *(const short8*)&abase[u * 512 + lane * 8];
      u0r[u] = *(const f32x4*)&ubase[u * 256 + lane * 4];
    }
  }

  for (int n = 0; n < NCHn; ++n) {
    const int np = (n + 1 < NCHn) ? (n + 1) : n;
#pragma unroll
    for (int mi = 0; mi < 8; ++mi) {
      const unsigned w0 = cvt_pk_bf16(S[mi][0], S[mi][1]);
      const unsigned w1 = cvt_pk_bf16(S[mi][2], S[mi][3]);
      const int a = (fr * 256 + mi * 32 + fg * 8) ^ swz;
      *(uint2*)((char*)&St[w][0] + a) = make_uint2(w0, w1);
    }
    short8 sb[4];
#pragma unroll
    for (int kwp = 0; kwp < 4; ++kwp) {
      const int a = (fr * 256 + kwp * 64 + fg * 16) ^ swz;
      sb[kwp] = *(const short8*)((const char*)&St[w][0] + a);
    }
    f32x4 up[2], oq[2];
    up[0] = up[1] = (f32x4){0.f, 0.f, 0.f, 0.f};
    oq[0] = oq[1] = (f32x4){0.f, 0.f, 0.f, 0.f};
#pragma unroll
    for (int kwp = 0; kwp < 4; ++kwp) {
#pragma unroll
      for (int mi = 0; mi < 2; ++mi) {
        up[mi] = __builtin_amdgcn_mfma_f32_16x16x32_bf16(wr[mi * 4 + kwp], sb[kwp], up[mi], 0, 0, 0);
        oq[mi] = __builtin_amdgcn_mfma_f32_16x16x32_bf16(qr[mi * 4 + kwp], sb[kwp], oq[mi], 0, 0, 0);
      }
    }
    {
      const unsigned short* wp = wbase + (size_t)np * 8192;
      const unsigned short* qp = qbase + (size_t)np * 8192;
#pragma unroll
      for (int u8 = 0; u8 < 8; ++u8) {
        const int mi = u8 >> 2, kwp = u8 & 3;
        const int u = mi * 8 + 4 * w + kwp;
        wr[u8] = *(const short8*)&wp[u * 512 + lane * 8];
        qr[u8] = *(const short8*)&qp[u * 512 + lane * 8];
      }
    }
    if (w == 1) {
#pragma unroll
      for (int mi = 0; mi < 2; ++mi) {
        *(f32x4*)&pu1[mi][lane * 4] = up[mi];
        *(f32x4*)&po1[mi][lane * 4] = oq[mi];
      }
      asm volatile("s_waitcnt lgkmcnt(0)" ::: "memory");
    }
    __builtin_amdgcn_s_barrier();
    __builtin_amdgcn_sched_barrier(0);
    f32x4 o_f[2];
    if (w == 0) {
#pragma unroll
      for (int mi = 0; mi < 2; ++mi) {
        const f32x4 p1 = *(const f32x4*)&pu1[mi][lane * 4];
        const f32x4 uu = u0r[mi] - up[mi] - p1;
        const unsigned w0 = cvt_pk_bf16(uu[0], uu[1]);
        const unsigned w1 = cvt_pk_bf16(uu[2], uu[3]);
        const int a = (fr * 64 + mi * 32 + fg * 8) ^ swz;
        *(uint2*)((char*)ut + a) = make_uint2(w0, w1);
        o_f[mi] = oq[mi] + *(const f32x4*)&po1[mi][lane * 4];
      }
      asm volatile("s_waitcnt lgkmcnt(0)" ::: "memory");
    }
    __builtin_amdgcn_s_barrier();
    __builtin_amdgcn_sched_barrier(0);
    const short8 ub = *(const short8*)((const char*)ut + ((fr * 64 + fg * 16) ^ swz));
    if (w == 0) {
#pragma unroll
      for (int mi = 0; mi < 2; ++mi)
        o_f[mi] = __builtin_amdgcn_mfma_f32_16x16x32_bf16(ar[mi], ub, o_f[mi], 0, 0, 0);
      const unsigned short* ap = abase + (size_t)np * 1024;
      const float* up_ = ubase + (size_t)np * 8192;
#pragma unroll
      for (int u = 0; u < 2; ++u) {
        ar[u] = *(const short8*)&ap[u * 512 + lane * 8];
        u0r[u] = *(const f32x4*)&up_[u * 256 + lane * 4];
      }
      const size_t cb = ((size_t)((bh << 12) + (n << 5))) * 256;
#pragma unroll
      for (int mi = 0; mi < 2; ++mi)
#pragma unroll
        for (int r = 0; r < 4; ++r)
          dout[cb + (size_t)(mi * 16 + fg * 4 + r) * 256 + dvs * 16 + fr] = o_f[mi][r];
    }
#pragma unroll
    for (int mi = 0; mi < 8; ++mi)
      S[mi] = __builtin_amdgcn_mfma_f32_16x16x32_bf16(ktr[mi], ub, S[mi], 0, 0, 0);
    {
      const unsigned short* kp = kbase + (size_t)np * 8192;
#pragma unroll
      for (int u8 = 0; u8 < 8; ++u8)
        ktr[u8] = *(const short8*)&kp[(8 * w + u8) * 512 + lane * 8];
    }
  }
}

// ---------------------------------------------------------------------------
// Mix: streaming FIR along l with register ring buffer. grid = 512.
// ---------------------------------------------------------------------------
#define MIX_LT 64
__global__ __launch_bounds__(256) void mix_kernel(
    const float* __restrict__ v, const float* __restrict__ delta,
    const float* __restrict__ wgl, const float* __restrict__ pmix,
    const float* __restrict__ firs, const float* __restrict__ firl,
    const float* __restrict__ rms_w, unsigned short* __restrict__ out) {
  const int wgid = ((int)blockIdx.x & 7) * 64 + ((int)blockIdx.x >> 3);
  const int b = wgid >> 8;
  const int h = (wgid >> 6) & 3;
  const int lt = wgid & 63;
  const int l0 = lt * MIX_LT;
  const int t = threadIdx.x;
  const int wv = t >> 6, lane = t & 63;
  const float* vcol = v + ((((size_t)(b * Hn + h)) << 12)) * 256 + t;
  const float* dcol = delta + ((((size_t)(b * Hn + h)) << 12)) * 256 + t;
  float fw[31], fs3[3];
#pragma unroll
  for (int j = 0; j < 31; ++j) fw[j] = firl[((h << 8) + t) * 31 + j];
#pragma unroll
  for (int j = 0; j < 3; ++j) fs3[j] = firs[((h << 8) + t) * 3 + j];
  const float rw = rms_w[t];
  float win[31];
#pragma unroll
  for (int j = 0; j < 30; ++j) {
    const int ls = l0 - 30 + j;
    win[j] = (ls >= 0) ? vcol[(size_t)ls * 256] : 0.f;
  }
  win[30] = 0.f;
  __shared__ float wred[MIX_LT * 4];
  float o[MIX_LT];
#pragma unroll
  for (int i = 0; i < MIX_LT; ++i) {
    const int l = l0 + i;
    const float vnew = vcol[(size_t)l * 256];
    float lo = fw[30] * vnew;
#pragma unroll
    for (int j = 0; j < 30; ++j) lo = fmaf(fw[j], win[(i + j) % 31], lo);
    float sh = fs3[2] * vnew;
    sh = fmaf(fs3[1], win[(i + 29) % 31], sh);
    sh = fmaf(fs3[0], win[(i + 28) % 31], sh);
    win[(i + 30) % 31] = vnew;
    const int row = (b << 12) + l;
    const float p0 = pmix[row * 12 + h * 3 + 0];
    const float p1 = pmix[row * 12 + h * 3 + 1];
    const float p2 = pmix[row * 12 + h * 3 + 2];
    const float wg = wgl[row * 4 + h];
    const float mixv = p0 * vnew + p1 * sh + p2 * lo;
    const float oo = wg * dcol[(size_t)l * 256] + (1.f - wg) * mixv;
    o[i] = oo;
    float ss = oo * oo;
#pragma unroll
    for (int m = 1; m < 64; m <<= 1) ss += __shfl_xor(ss, m);
    if (lane == 0) wred[i * 4 + wv] = ss;
  }
  __syncthreads();
#pragma unroll
  for (int i = 0; i < MIX_LT; ++i) {
    const float sum = wred[i * 4] + wred[i * 4 + 1] + wred[i * 4 + 2] + wred[i * 4 + 3];
    const float sc = rsqrtf(sum * (1.f / 256.f) + 1e-5f);
    const int l = l0 + i;
    out[(size_t)((b << 12) + l) * 1024 + (h << 8) + t] = f2bf(o[i] * sc * rw);
  }
}

// ---------------------------------------------------------------------------
extern "C" void kernel_launch(void* const* d_in, const int* in_sizes, int n_in,
                              void* d_out, int out_size, void* d_ws, size_t ws_size,
                              hipStream_t stream) {
  const float* x = (const float*)d_in[0];
  const float* Wq = (const float*)d_in[1];
  const float* Wk = (const float*)d_in[2];
  const float* Wv = (const float*)d_in[3];
  const float* cq = (const float*)d_in[4];
  const float* ck = (const float*)d_in[5];
  const float* cv = (const float*)d_in[6];
  const float* Wb = (const float*)d_in[7];
  const float* firs = (const float*)d_in[8];
  const float* firl = (const float*)d_in[9];
  const float* Wg = (const float*)d_in[10];
  const float* bg = (const float*)d_in[11];
  const float* Wl = (const float*)d_in[12];
  const float* bl = (const float*)d_in[13];
  const float* ltemp = (const float*)d_in[14];
  const float* rmsw = (const float*)d_in[15];
  const float* Wo = (const float*)d_in[16];

  float* ws = (float*)d_ws;
  const size_t NE = (size_t)Bn * Ln * 1024;  // 8.39M floats
  float* qraw = ws;
  float* kraw = ws + NE;
  float* vraw = ws + 2 * NE;
  float* qn = ws + 3 * NE;
  float* kn = ws + 4 * NE;
  float* vn = ws + 5 * NE;
  float* beta = ws + 6 * NE;
  float* wgl = beta + (size_t)Bn * Hn * Ln;
  float* pmix = wgl + (size_t)Bn * Ln * Hn;
  float* attn_unused = pmix + (size_t)Bn * Ln * Hn * 3;
  unsigned short* Wot = (unsigned short*)(attn_unused + (size_t)Bn * Hn * NCHn * 1024);
  unsigned short* xb = (unsigned short*)qn;
  unsigned short* Wqt = (unsigned short*)(qn + 4194304);
  unsigned short* Wkt = Wqt + 1048576;
  unsigned short* Wvt = Wkt + 1048576;
  unsigned short* normed_bf = (unsigned short*)kn;  // kn dead after precomp
  unsigned short* wfrag = (unsigned short*)qraw;
  unsigned short* qfrag = wfrag + 8388608;
  unsigned short* ktfrag = (unsigned short*)kraw;
  unsigned short* afrag = ktfrag + 8388608;
  float* u0frag = qn;   // exact per-chunk slot overlay of qn
  float* dbuf = vraw;

  const dim3 wtg(32, 32);
  wt_kernel<<<wtg, 256, 0, stream>>>(Wq, Wqt, 1024, 1024);
  wt_kernel<<<wtg, 256, 0, stream>>>(Wk, Wkt, 1024, 1024);
  wt_kernel<<<wtg, 256, 0, stream>>>(Wv, Wvt, 1024, 1024);
  wt_kernel<<<wtg, 256, 0, stream>>>(Wo, Wot, 1024, 1024);
  f2bf_kernel<<<(int)(NE / 1024), 256, 0, stream>>>(x, xb, (int)NE);

  const dim3 gg(8, 64);  // N/128, M/128
  gemm_bf16<<<gg, 256, 0, stream>>>(xb, Wqt, qraw, Bn * Ln, 1024, 1024);
  gemm_bf16<<<gg, 256, 0, stream>>>(xb, Wkt, kraw, Bn * Ln, 1024, 1024);
  gemm_bf16<<<gg, 256, 0, stream>>>(xb, Wvt, vraw, Bn * Ln, 1024, 1024);
  gates_kernel<<<Bn * Ln / 4, 256, 0, stream>>>(x, Wb, Wg, bg, Wl, bl, ltemp,
                                                beta, wgl, pmix);
  conv_act_kernel<1><<<Bn * Ln, 256, 0, stream>>>(qraw, cq, qn);
  conv_act_kernel<1><<<Bn * Ln, 256, 0, stream>>>(kraw, ck, kn);
  conv_act_kernel<0><<<Bn * Ln, 256, 0, stream>>>(vraw, cv, vn);
  precomp_kernel<<<Bn * Hn * NCHn, 256, 0, stream>>>(qn, kn, vn, beta, wfrag,
                                                     qfrag, ktfrag, afrag, u0frag);
  scan_mfma<<<128, 128, 0, stream>>>(wfrag, qfrag, ktfrag, afrag, u0frag, dbuf);
  mix_kernel<<<Bn * Hn * (Ln / MIX_LT), 256, 0, stream>>>(
      vn, dbuf, wgl, pmix, firs, firl, rmsw, normed_bf);
  gemm_bf16<<<gg, 256, 0, stream>>>(normed_bf, Wot, (float*)d_out, Bn * Ln, 1024, 1024);
}

// Round 10
// 487.163 us; speedup vs baseline: 6.4775x; 1.1606x over previous
//
#include <hip/hip_runtime.h>
#include <hip/hip_bf16.h>
#include <math.h>

#define Bn 2
#define Ln 4096
#define Dn 1024
#define Hn 4
#define DKn 256
#define DVn 256
#define NCHn 128  // L/32 chunks

typedef __attribute__((ext_vector_type(8))) short short8;
typedef __attribute__((ext_vector_type(4))) float f32x4;

__device__ __forceinline__ float sigmoidf_(float x) { return 1.f / (1.f + __expf(-x)); }

__device__ __forceinline__ unsigned short f2bf(float f) {
  union { float f; unsigned u; } v; v.f = f;
  unsigned r = v.u + 0x7FFFu + ((v.u >> 16) & 1u);
  return (unsigned short)(r >> 16);
}

__device__ __forceinline__ unsigned cvt_pk_bf16(float a, float b) {
  unsigned r;
  asm volatile("v_cvt_pk_bf16_f32 %0, %1, %2" : "=v"(r) : "v"(a), "v"(b));
  return r;
}

__device__ __forceinline__ short8 pack_i4(int4 o) {
  short8 r;
  __builtin_memcpy(&r, &o, 16);
  return r;
}

__device__ __forceinline__ void gl2lds16(const void* g, void* l) {
  __builtin_amdgcn_global_load_lds((const __attribute__((address_space(1))) unsigned int*)g,
                                   (__attribute__((address_space(3))) unsigned int*)l, 16, 0, 0);
}

// ---------------------------------------------------------------------------
// Weight transpose + bf16 convert: Wt[n][k] = bf16(W[k][n]), K=N=1024.
// ---------------------------------------------------------------------------
__global__ __launch_bounds__(256) void wt_kernel(const float* __restrict__ W,
                                                 unsigned short* __restrict__ Wt,
                                                 int K, int N) {
  __shared__ float tile[32][33];
  const int bx = blockIdx.x * 32;  // n
  const int by = blockIdx.y * 32;  // k
  const int tx = threadIdx.x & 31, ty4 = (threadIdx.x >> 5) * 4;
#pragma unroll
  for (int r = 0; r < 4; ++r)
    tile[ty4 + r][tx] = W[(size_t)(by + ty4 + r) * N + bx + tx];
  __syncthreads();
#pragma unroll
  for (int r = 0; r < 4; ++r)
    Wt[(size_t)(bx + ty4 + r) * K + by + tx] = f2bf(tile[tx][ty4 + r]);
}

// ---------------------------------------------------------------------------
// fp32 -> bf16 elementwise, n % 1024 == 0
// ---------------------------------------------------------------------------
__global__ __launch_bounds__(256) void f2bf_kernel(const float* __restrict__ in,
                                                   unsigned short* __restrict__ out,
                                                   int n) {
  const int i4 = (blockIdx.x * 256 + threadIdx.x) * 4;
  if (i4 >= n) return;
  const float4 v = *(const float4*)&in[i4];
  ushort4 o;
  o.x = f2bf(v.x); o.y = f2bf(v.y); o.z = f2bf(v.z); o.w = f2bf(v.w);
  *(ushort4*)&out[i4] = o;
}

// ---------------------------------------------------------------------------
// bf16 MFMA GEMM: C[M,N] f32 = A[M,K]bf16 @ Bt[N,K]bf16^T. 128x128 tile, BK=32.
// ---------------------------------------------------------------------------
__global__ __launch_bounds__(256, 2) void gemm_bf16(const unsigned short* __restrict__ A,
                                                    const unsigned short* __restrict__ Bt,
                                                    float* __restrict__ C,
                                                    int M, int N, int K) {
  __shared__ __align__(16) unsigned short As[128 * 32];
  __shared__ __align__(16) unsigned short Bs[128 * 32];
  const int tid = threadIdx.x;
  const int wid = tid >> 6, lane = tid & 63;
  const int row0 = blockIdx.y * 128, col0 = blockIdx.x * 128;
  const int wr64 = (wid >> 1) * 64, wc64 = (wid & 1) * 64;
  const int fr = lane & 15, fg = lane >> 4;
  f32x4 acc[4][4];
#pragma unroll
  for (int i = 0; i < 4; ++i)
#pragma unroll
    for (int j = 0; j < 4; ++j) acc[i][j] = (f32x4){0.f, 0.f, 0.f, 0.f};
  for (int k0 = 0; k0 < K; k0 += 32) {
#pragma unroll
    for (int i = 0; i < 2; ++i) {
      const int off = wid * 2048 + i * 1024 + (lane << 4);  // LDS byte offset
      const int r = off >> 6;                               // tile row
      const int kb = off & 63;                              // byte within row
      gl2lds16((const char*)A + ((size_t)(row0 + r) * K + k0) * 2 + kb, (char*)As + off);
      gl2lds16((const char*)Bt + ((size_t)(col0 + r) * K + k0) * 2 + kb, (char*)Bs + off);
    }
    __syncthreads();
    short8 a[4], b[4];
#pragma unroll
    for (int mi = 0; mi < 4; ++mi)
      a[mi] = *(const short8*)&As[(wr64 + mi * 16 + fr) * 32 + fg * 8];
#pragma unroll
    for (int ni = 0; ni < 4; ++ni)
      b[ni] = *(const short8*)&Bs[(wc64 + ni * 16 + fr) * 32 + fg * 8];
#pragma unroll
    for (int mi = 0; mi < 4; ++mi)
#pragma unroll
      for (int ni = 0; ni < 4; ++ni)
        acc[mi][ni] = __builtin_amdgcn_mfma_f32_16x16x32_bf16(a[mi], b[ni], acc[mi][ni], 0, 0, 0);
    __syncthreads();
  }
#pragma unroll
  for (int mi = 0; mi < 4; ++mi) {
    const int orow = row0 + wr64 + mi * 16 + fg * 4;
#pragma unroll
    for (int ni = 0; ni < 4; ++ni) {
      const int ocol = col0 + wc64 + ni * 16 + fr;
#pragma unroll
      for (int r = 0; r < 4; ++r)
        C[(size_t)(orow + r) * N + ocol] = acc[mi][ni][r];
    }
  }
}

// ---------------------------------------------------------------------------
// Gate projections (unchanged)
// ---------------------------------------------------------------------------
__global__ __launch_bounds__(256) void gates_kernel(
    const float* __restrict__ x, const float* __restrict__ Wb,
    const float* __restrict__ Wg, const float* __restrict__ bg,
    const float* __restrict__ Wl, const float* __restrict__ bl,
    const float* __restrict__ log_temp, float* __restrict__ beta,
    float* __restrict__ wgl, float* __restrict__ pmix) {
  const int wave = threadIdx.x >> 6, lane = threadIdx.x & 63;
  const int row = (blockIdx.x << 2) + wave;
  if (row >= Bn * Ln) return;
  const float* xr = x + (size_t)row * Dn;
  float acc[20];
#pragma unroll
  for (int c = 0; c < 20; ++c) acc[c] = 0.f;
#pragma unroll
  for (int i = 0; i < 4; ++i) {
    const float4 xv = *(const float4*)&xr[(lane << 2) + (i << 8)];
    const float xa[4] = {xv.x, xv.y, xv.z, xv.w};
#pragma unroll
    for (int j = 0; j < 4; ++j) {
      const int kk = (i << 8) + (lane << 2) + j;
      const float xx = xa[j];
#pragma unroll
      for (int h = 0; h < 4; ++h) acc[h] = fmaf(xx, Wb[kk * 4 + h], acc[h]);
#pragma unroll
      for (int h = 0; h < 4; ++h) acc[4 + h] = fmaf(xx, Wg[kk * 4 + h], acc[4 + h]);
#pragma unroll
      for (int c = 0; c < 12; ++c) acc[8 + c] = fmaf(xx, Wl[kk * 12 + c], acc[8 + c]);
    }
  }
#pragma unroll
  for (int c = 0; c < 20; ++c)
    for (int off = 32; off; off >>= 1) acc[c] += __shfl_down(acc[c], off);
  if (lane == 0) {
    const int b = row >> 12, l = row & (Ln - 1);
#pragma unroll
    for (int h = 0; h < 4; ++h)
      beta[((size_t)(b * Hn + h) << 12) + l] = sigmoidf_(acc[h]);
#pragma unroll
    for (int h = 0; h < 4; ++h) wgl[row * 4 + h] = sigmoidf_(acc[4 + h] + bg[h]);
#pragma unroll
    for (int h = 0; h < 4; ++h) {
      const float it = 1.f / __expf(log_temp[h]);
      const float l0 = (acc[8 + h * 3 + 0] + bl[h * 3 + 0]) * it;
      const float l1 = (acc[8 + h * 3 + 1] + bl[h * 3 + 1]) * it;
      const float l2 = (acc[8 + h * 3 + 2] + bl[h * 3 + 2]) * it;
      const float mx = fmaxf(l0, fmaxf(l1, l2));
      const float e0 = __expf(l0 - mx), e1 = __expf(l1 - mx), e2 = __expf(l2 - mx);
      const float is = 1.f / (e0 + e1 + e2);
      pmix[row * 12 + h * 3 + 0] = e0 * is;
      pmix[row * 12 + h * 3 + 1] = e1 * is;
      pmix[row * 12 + h * 3 + 2] = e2 * is;
    }
  }
}

// ---------------------------------------------------------------------------
// Causal depthwise conv (K=4) + SiLU (+ optional l2norm). (unchanged)
// ---------------------------------------------------------------------------
template <int DO_L2>
__global__ __launch_bounds__(256) void conv_act_kernel(
    const float* __restrict__ raw, const float* __restrict__ cw,
    float* __restrict__ out) {
  const int blk = blockIdx.x;
  const int b = blk >> 12, l = blk & (Ln - 1);
  const int t = threadIdx.x;
  float vals[4];
#pragma unroll
  for (int g = 0; g < 4; ++g) {
    const int c = (g << 8) + t;
    float a = 0.f;
#pragma unroll
    for (int j = 0; j < 4; ++j) {
      const int ls = l - 3 + j;
      if (ls >= 0) a = fmaf(cw[c * 4 + j], raw[(((size_t)b << 12) + ls) * 1024 + c], a);
    }
    vals[g] = a * sigmoidf_(a);
  }
  if (DO_L2) {
    __shared__ float red[4][4];
    float ss[4];
#pragma unroll
    for (int g = 0; g < 4; ++g) ss[g] = vals[g] * vals[g];
#pragma unroll
    for (int g = 0; g < 4; ++g)
      for (int off = 32; off; off >>= 1) ss[g] += __shfl_down(ss[g], off);
    const int wave = t >> 6, lane = t & 63;
    if (lane == 0) {
#pragma unroll
      for (int g = 0; g < 4; ++g) red[wave][g] = ss[g];
    }
    __syncthreads();
#pragma unroll
    for (int g = 0; g < 4; ++g) {
      const float s = red[0][g] + red[1][g] + red[2][g] + red[3][g];
      vals[g] *= rsqrtf(s + 1e-6f);
    }
  }
#pragma unroll
  for (int g = 0; g < 4; ++g)
    out[((((size_t)(b * Hn + g)) << 12) + l) * 256 + t] = vals[g];
}

// ---------------------------------------------------------------------------
// Precomp v2 (unchanged from round 9)
// ---------------------------------------------------------------------------
__global__ __launch_bounds__(256, 2) void precomp_kernel(
    const float* __restrict__ q, const float* __restrict__ k,
    const float* __restrict__ v, const float* __restrict__ beta,
    unsigned short* __restrict__ wfrag, unsigned short* __restrict__ qfrag,
    unsigned short* __restrict__ ktfrag, unsigned short* __restrict__ afrag,
    float* __restrict__ u0frag) {
  const int blk = blockIdx.x;
  const int n = blk & 127, bh = blk >> 7;
  const size_t base = (((size_t)bh << 12) + (n << 5)) * 256;
  const size_t cid = (size_t)(bh * NCHn + n);
  __shared__ __align__(16) unsigned short ksb[32][264];
  __shared__ __align__(16) unsigned short qsb[32][264];  // later reused for w staging
  __shared__ __align__(16) unsigned short vbb[32][264];
  __shared__ float Tm[32][33], Am[32][33], bet[32];
  __shared__ __align__(16) float attn_l[32][36];
  const int t = threadIdx.x;
  const int wid = t >> 6, lane = t & 63;
  const int fr = lane & 15, fg = lane >> 4;
  if (t < 32) bet[t] = beta[((size_t)bh << 12) + (n << 5) + t];
#pragma unroll
  for (int it = 0; it < 4; ++it) {
    const int idx = t + it * 256;
    const int r = idx >> 5, c8 = (idx & 31) << 3;
    const float bv = beta[((size_t)bh << 12) + (n << 5) + r];
    const float4 q0 = *(const float4*)&q[base + r * 256 + c8];
    const float4 q1 = *(const float4*)&q[base + r * 256 + c8 + 4];
    const float4 k0 = *(const float4*)&k[base + r * 256 + c8];
    const float4 k1 = *(const float4*)&k[base + r * 256 + c8 + 4];
    const float4 v0 = *(const float4*)&v[base + r * 256 + c8];
    const float4 v1 = *(const float4*)&v[base + r * 256 + c8 + 4];
    int4 oq, ok, ov;
    oq.x = cvt_pk_bf16(q0.x, q0.y); oq.y = cvt_pk_bf16(q0.z, q0.w);
    oq.z = cvt_pk_bf16(q1.x, q1.y); oq.w = cvt_pk_bf16(q1.z, q1.w);
    ok.x = cvt_pk_bf16(k0.x, k0.y); ok.y = cvt_pk_bf16(k0.z, k0.w);
    ok.z = cvt_pk_bf16(k1.x, k1.y); ok.w = cvt_pk_bf16(k1.z, k1.w);
    ov.x = cvt_pk_bf16(v0.x * bv, v0.y * bv); ov.y = cvt_pk_bf16(v0.z * bv, v0.w * bv);
    ov.z = cvt_pk_bf16(v1.x * bv, v1.y * bv); ov.w = cvt_pk_bf16(v1.z * bv, v1.w * bv);
    *(int4*)&qsb[r][c8] = oq;
    *(int4*)&ksb[r][c8] = ok;
    *(int4*)&vbb[r][c8] = ov;
  }
  __syncthreads();
  {
    const int ti = wid >> 1, tj = wid & 1;
    f32x4 G = (f32x4){0.f, 0.f, 0.f, 0.f};
    f32x4 At = (f32x4){0.f, 0.f, 0.f, 0.f};
#pragma unroll
    for (int kw = 0; kw < 8; ++kw) {
      const short8 krow = *(const short8*)&ksb[ti * 16 + fr][kw * 32 + fg * 8];
      const short8 kcol = *(const short8*)&ksb[tj * 16 + fr][kw * 32 + fg * 8];
      const short8 qrow = *(const short8*)&qsb[ti * 16 + fr][kw * 32 + fg * 8];
      G = __builtin_amdgcn_mfma_f32_16x16x32_bf16(krow, kcol, G, 0, 0, 0);
      At = __builtin_amdgcn_mfma_f32_16x16x32_bf16(qrow, kcol, At, 0, 0, 0);
    }
#pragma unroll
    for (int r_ = 0; r_ < 4; ++r_) {
      const int i = ti * 16 + fg * 4 + r_;
      const int j = tj * 16 + fr;
      Am[i][j] = bet[i] * G[r_];
      attn_l[i][j] = (j <= i) ? At[r_] : 0.f;
    }
  }
#pragma unroll
  for (int it = 0; it < 4; ++it) {
    const int u = it * 4 + wid;
    const int mi = u >> 3, kw = u & 7;
    *(int4*)&qfrag[cid * 8192 + u * 512 + lane * 8] =
        *(const int4*)&qsb[mi * 16 + fr][kw * 32 + fg * 8];
  }
#pragma unroll
  for (int it = 0; it < 4; ++it) {
    const int mi = it * 4 + wid;
    const int dk = mi * 16 + fr;
    unsigned short e[8];
#pragma unroll
    for (int j = 0; j < 8; ++j) e[j] = ksb[fg * 8 + j][dk];
    int4 o;
    o.x = e[0] | ((unsigned)e[1] << 16);
    o.y = e[2] | ((unsigned)e[3] << 16);
    o.z = e[4] | ((unsigned)e[5] << 16);
    o.w = e[6] | ((unsigned)e[7] << 16);
    *(int4*)&ktfrag[cid * 8192 + mi * 512 + lane * 8] = o;
  }
  __syncthreads();
  if (t >= 128) {
    const int mi = (t >> 6) - 2;
    const int c = mi * 16 + fr;
    const float4 a = *(const float4*)&attn_l[c][fg * 8];
    const float4 b2 = *(const float4*)&attn_l[c][fg * 8 + 4];
    int4 o;
    o.x = f2bf(a.x) | ((unsigned)f2bf(a.y) << 16);
    o.y = f2bf(a.z) | ((unsigned)f2bf(a.w) << 16);
    o.z = f2bf(b2.x) | ((unsigned)f2bf(b2.y) << 16);
    o.w = f2bf(b2.z) | ((unsigned)f2bf(b2.w) << 16);
    *(int4*)&afrag[cid * 1024 + mi * 512 + lane * 8] = o;
  }
  if (t < 32) {
    float Tcol[32];
    Tcol[0] = (t == 0) ? 1.f : 0.f;
#pragma unroll
    for (int i = 1; i < 32; ++i) {
      float s0 = 0.f, s1 = 0.f;
      int m = 0;
#pragma unroll
      for (; m + 2 <= i; m += 2) {
        s0 = fmaf(Am[i][m], Tcol[m], s0);
        s1 = fmaf(Am[i][m + 1], Tcol[m + 1], s1);
      }
      if (m < i) s0 = fmaf(Am[i][m], Tcol[m], s0);
      Tcol[i] = ((i == t) ? 1.f : 0.f) - s0 - s1;
    }
#pragma unroll
    for (int i = 0; i < 32; ++i) Tm[i][t] = Tcol[i];
  }
  __syncthreads();
  {
    float betr[8];
#pragma unroll
    for (int j = 0; j < 8; ++j) betr[j] = bet[fg * 8 + j];
    short8 Tf[2], Tbf[2];
#pragma unroll
    for (int mi = 0; mi < 2; ++mi) {
      float tv[8];
#pragma unroll
      for (int j = 0; j < 8; ++j) tv[j] = Tm[mi * 16 + fr][fg * 8 + j];
      int4 p, pb;
      p.x = cvt_pk_bf16(tv[0], tv[1]); p.y = cvt_pk_bf16(tv[2], tv[3]);
      p.z = cvt_pk_bf16(tv[4], tv[5]); p.w = cvt_pk_bf16(tv[6], tv[7]);
      pb.x = cvt_pk_bf16(tv[0] * betr[0], tv[1] * betr[1]);
      pb.y = cvt_pk_bf16(tv[2] * betr[2], tv[3] * betr[3]);
      pb.z = cvt_pk_bf16(tv[4] * betr[4], tv[5] * betr[5]);
      pb.w = cvt_pk_bf16(tv[6] * betr[6], tv[7] * betr[7]);
      Tf[mi] = pack_i4(p);
      Tbf[mi] = pack_i4(pb);
    }
    const f32x4 zero = (f32x4){0.f, 0.f, 0.f, 0.f};
#pragma unroll
    for (int tt = 0; tt < 4; ++tt) {
      const int tjc = wid * 4 + tt;
      unsigned short ev[8], ek[8];
#pragma unroll
      for (int j = 0; j < 8; ++j) {
        ev[j] = vbb[fg * 8 + j][tjc * 16 + fr];
        ek[j] = ksb[fg * 8 + j][tjc * 16 + fr];
      }
      int4 pv, pk;
      pv.x = ev[0] | ((unsigned)ev[1] << 16); pv.y = ev[2] | ((unsigned)ev[3] << 16);
      pv.z = ev[4] | ((unsigned)ev[5] << 16); pv.w = ev[6] | ((unsigned)ev[7] << 16);
      pk.x = ek[0] | ((unsigned)ek[1] << 16); pk.y = ek[2] | ((unsigned)ek[3] << 16);
      pk.z = ek[4] | ((unsigned)ek[5] << 16); pk.w = ek[6] | ((unsigned)ek[7] << 16);
      const short8 vbf = pack_i4(pv);
      const short8 kbf = pack_i4(pk);
#pragma unroll
      for (int mi = 0; mi < 2; ++mi) {
        const f32x4 U = __builtin_amdgcn_mfma_f32_16x16x32_bf16(Tf[mi], vbf, zero, 0, 0, 0);
        *(f32x4*)&u0frag[cid * 8192 + (tjc * 2 + mi) * 256 + lane * 4] = U;
        const f32x4 W = __builtin_amdgcn_mfma_f32_16x16x32_bf16(Tbf[mi], kbf, zero, 0, 0, 0);
#pragma unroll
        for (int r_ = 0; r_ < 4; ++r_)
          qsb[mi * 16 + fg * 4 + r_][tjc * 16 + fr] = f2bf(W[r_]);
      }
    }
  }
  __syncthreads();
#pragma unroll
  for (int it = 0; it < 4; ++it) {
    const int u = it * 4 + wid;
    const int mi = u >> 3, kw = u & 7;
    *(int4*)&wfrag[cid * 8192 + u * 512 + lane * 8] =
        *(const int4*)&qsb[mi * 16 + fr][kw * 32 + fg * 8];
  }
}

// ---------------------------------------------------------------------------
// Scan v6 (unchanged)
// ---------------------------------------------------------------------------
__global__ __launch_bounds__(128, 1) void scan_mfma(
    const unsigned short* __restrict__ wfrag, const unsigned short* __restrict__ qfrag,
    const unsigned short* __restrict__ ktfrag, const unsigned short* __restrict__ afrag,
    const float* __restrict__ u0frag, float* __restrict__ dout) {
  const int bh = blockIdx.x & 7;
  const int dvs = blockIdx.x >> 3;
  const int tid = threadIdx.x;
  const int w = tid >> 6;
  const int lane = tid & 63;
  const int fr = lane & 15, fg = lane >> 4;
  const int swz = (fr & 7) << 4;
  __shared__ __align__(16) unsigned short St[2][2048];
  __shared__ __align__(16) unsigned short ut[512];
  __shared__ __align__(16) float pu1[2][256];
  __shared__ __align__(16) float po1[2][256];
  f32x4 S[8];
#pragma unroll
  for (int i = 0; i < 8; ++i) S[i] = (f32x4){0.f, 0.f, 0.f, 0.f};

  const unsigned short* wbase = wfrag + (size_t)(bh * NCHn) * 8192;
  const unsigned short* qbase = qfrag + (size_t)(bh * NCHn) * 8192;
  const unsigned short* kbase = ktfrag + (size_t)(bh * NCHn) * 8192;
  const unsigned short* abase = afrag + (size_t)(bh * NCHn) * 1024;
  const float* ubase = u0frag + (size_t)(bh * NCHn) * 8192 + dvs * 512;

  short8 wr[8], qr[8], ktr[8];
  short8 ar[2] = {};
  f32x4 u0r[2] = {};
#pragma unroll
  for (int u8 = 0; u8 < 8; ++u8) {
    const int mi = u8 >> 2, kwp = u8 & 3;
    const int u = mi * 8 + 4 * w + kwp;
    wr[u8] = *(const short8*)&wbase[u * 512 + lane * 8];
    qr[u8] = *(const short8*)&qbase[u * 512 + lane * 8];
    ktr[u8] = *(const short8*)&kbase[(8 * w + u8) * 512 + lane * 8];
  }
  if (w == 0) {
#pragma unroll
    for (int u = 0; u < 2; ++u) {
      ar[u] = *(const short8*)&abase[u * 512 + lane * 8];
      u0r[u] = *(const f32x4*)&ubase[u * 256 + lane * 4];
    }
  }

  for (int n = 0; n < NCHn; ++n) {
    const int np = (n + 1 < NCHn) ? (n + 1) : n;
#pragma unroll
    for (int mi = 0; mi < 8; ++mi) {
      const unsigned w0 = cvt_pk_bf16(S[mi][0], S[mi][1]);
      const unsigned w1 = cvt_pk_bf16(S[mi][2], S[mi][3]);
      const int a = (fr * 256 + mi * 32 + fg * 8) ^ swz;
      *(uint2*)((char*)&St[w][0] + a) = make_uint2(w0, w1);
    }
    short8 sb[4];
#pragma unroll
    for (int kwp = 0; kwp < 4; ++kwp) {
      const int a = (fr * 256 + kwp * 64 + fg * 16) ^ swz;
      sb[kwp] = *(const short8*)((const char*)&St[w][0] + a);
    }
    f32x4 up[2], oq[2];
    up[0] = up[1] = (f32x4){0.f, 0.f, 0.f, 0.f};
    oq[0] = oq[1] = (f32x4){0.f, 0.f, 0.f, 0.f};
#pragma unroll
    for (int kwp = 0; kwp < 4; ++kwp) {
#pragma unroll
      for (int mi = 0; mi < 2; ++mi) {
        up[mi] = __builtin_amdgcn_mfma_f32_16x16x32_bf16(wr[mi * 4 + kwp], sb[kwp], up[mi], 0, 0, 0);
        oq[mi] = __builtin_amdgcn_mfma_f32_16x16x32_bf16(qr[mi * 4 + kwp], sb[kwp], oq[mi], 0, 0, 0);
      }
    }
    {
      const unsigned short* wp = wbase + (size_t)np * 8192;
      const unsigned short* qp = qbase + (size_t)np * 8192;
#pragma unroll
      for (int u8 = 0; u8 < 8; ++u8) {
        const int mi = u8 >> 2, kwp = u8 & 3;
        const int u = mi * 8 + 4 * w + kwp;
        wr[u8] = *(const short8*)&wp[u * 512 + lane * 8];
        qr[u8] = *(const short8*)&qp[u * 512 + lane * 8];
      }
    }
    if (w == 1) {
#pragma unroll
      for (int mi = 0; mi < 2; ++mi) {
        *(f32x4*)&pu1[mi][lane * 4] = up[mi];
        *(f32x4*)&po1[mi][lane * 4] = oq[mi];
      }
      asm volatile("s_waitcnt lgkmcnt(0)" ::: "memory");
    }
    __builtin_amdgcn_s_barrier();
    __builtin_amdgcn_sched_barrier(0);
    f32x4 o_f[2];
    if (w == 0) {
#pragma unroll
      for (int mi = 0; mi < 2; ++mi) {
        const f32x4 p1 = *(const f32x4*)&pu1[mi][lane * 4];
        const f32x4 uu = u0r[mi] - up[mi] - p1;
        const unsigned w0 = cvt_pk_bf16(uu[0], uu[1]);
        const unsigned w1 = cvt_pk_bf16(uu[2], uu[3]);
        const int a = (fr * 64 + mi * 32 + fg * 8) ^ swz;
        *(uint2*)((char*)ut + a) = make_uint2(w0, w1);
        o_f[mi] = oq[mi] + *(const f32x4*)&po1[mi][lane * 4];
      }
      asm volatile("s_waitcnt lgkmcnt(0)" ::: "memory");
    }
    __builtin_amdgcn_s_barrier();
    __builtin_amdgcn_sched_barrier(0);
    const short8 ub = *(const short8*)((const char*)ut + ((fr * 64 + fg * 16) ^ swz));
    if (w == 0) {
#pragma unroll
      for (int mi = 0; mi < 2; ++mi)
        o_f[mi] = __builtin_amdgcn_mfma_f32_16x16x32_bf16(ar[mi], ub, o_f[mi], 0, 0, 0);
      const unsigned short* ap = abase + (size_t)np * 1024;
      const float* up_ = ubase + (size_t)np * 8192;
#pragma unroll
      for (int u = 0; u < 2; ++u) {
        ar[u] = *(const short8*)&ap[u * 512 + lane * 8];
        u0r[u] = *(const f32x4*)&up_[u * 256 + lane * 4];
      }
      const size_t cb = ((size_t)((bh << 12) + (n << 5))) * 256;
#pragma unroll
      for (int mi = 0; mi < 2; ++mi)
#pragma unroll
        for (int r = 0; r < 4; ++r)
          dout[cb + (size_t)(mi * 16 + fg * 4 + r) * 256 + dvs * 16 + fr] = o_f[mi][r];
    }
#pragma unroll
    for (int mi = 0; mi < 8; ++mi)
      S[mi] = __builtin_amdgcn_mfma_f32_16x16x32_bf16(ktr[mi], ub, S[mi], 0, 0, 0);
    {
      const unsigned short* kp = kbase + (size_t)np * 8192;
#pragma unroll
      for (int u8 = 0; u8 < 8; ++u8)
        ktr[u8] = *(const short8*)&kp[(8 * w + u8) * 512 + lane * 8];
    }
  }
}

// ---------------------------------------------------------------------------
// Mix v3: MIX_LT=16, flat vbuf[46] with all-static indexing (no spill),
// grid = 2048 (XCD-chunked). Thread = channel.
// ---------------------------------------------------------------------------
#define MIX_LT 16
__global__ __launch_bounds__(256) void mix_kernel(
    const float* __restrict__ v, const float* __restrict__ delta,
    const float* __restrict__ wgl, const float* __restrict__ pmix,
    const float* __restrict__ firs, const float* __restrict__ firl,
    const float* __restrict__ rms_w, unsigned short* __restrict__ out) {
  // 2048 blocks: XCD-chunk swizzle (256 contiguous tiles per XCD)
  const int wgid = ((int)blockIdx.x & 7) * 256 + ((int)blockIdx.x >> 3);
  const int b = wgid >> 10;
  const int h = (wgid >> 8) & 3;
  const int lt = wgid & 255;
  const int l0 = lt * MIX_LT;
  const int t = threadIdx.x;
  const int wv = t >> 6, lane = t & 63;
  const float* vcol = v + ((((size_t)(b * Hn + h)) << 12)) * 256 + t;
  const float* dcol = delta + ((((size_t)(b * Hn + h)) << 12)) * 256 + t;
  float fw[31], fs3[3];
#pragma unroll
  for (int j = 0; j < 31; ++j) fw[j] = firl[((h << 8) + t) * 31 + j];
#pragma unroll
  for (int j = 0; j < 3; ++j) fs3[j] = firs[((h << 8) + t) * 3 + j];
  const float rw = rms_w[t];
  // vbuf[j] = v[l0 - 30 + j], j = 0..45 (30 halo + 16 tile rows)
  float vbuf[46];
#pragma unroll
  for (int j = 0; j < 30; ++j) {
    const int ls = l0 - 30 + j;
    vbuf[j] = (ls >= 0) ? vcol[(size_t)ls * 256] : 0.f;
  }
#pragma unroll
  for (int i = 0; i < MIX_LT; ++i) vbuf[30 + i] = vcol[(size_t)(l0 + i) * 256];
  __shared__ float wred[MIX_LT * 4];
  float o[MIX_LT];
#pragma unroll
  for (int i = 0; i < MIX_LT; ++i) {
    const int l = l0 + i;
    const float vnew = vbuf[30 + i];
    float lo = fw[30] * vnew;
#pragma unroll
    for (int j = 0; j < 30; ++j) lo = fmaf(fw[j], vbuf[i + j], lo);
    float sh = fs3[2] * vnew;
    sh = fmaf(fs3[1], vbuf[i + 29], sh);
    sh = fmaf(fs3[0], vbuf[i + 28], sh);
    const int row = (b << 12) + l;
    const float p0 = pmix[row * 12 + h * 3 + 0];
    const float p1 = pmix[row * 12 + h * 3 + 1];
    const float p2 = pmix[row * 12 + h * 3 + 2];
    const float wg = wgl[row * 4 + h];
    const float mixv = p0 * vnew + p1 * sh + p2 * lo;
    const float oo = wg * dcol[(size_t)l * 256] + (1.f - wg) * mixv;
    o[i] = oo;
    float ss = oo * oo;
#pragma unroll
    for (int m = 1; m < 64; m <<= 1) ss += __shfl_xor(ss, m);
    if (lane == 0) wred[i * 4 + wv] = ss;
  }
  __syncthreads();
#pragma unroll
  for (int i = 0; i < MIX_LT; ++i) {
    const float sum = wred[i * 4] + wred[i * 4 + 1] + wred[i * 4 + 2] + wred[i * 4 + 3];
    const float sc = rsqrtf(sum * (1.f / 256.f) + 1e-5f);
    const int l = l0 + i;
    out[(size_t)((b << 12) + l) * 1024 + (h << 8) + t] = f2bf(o[i] * sc * rw);
  }
}

// ---------------------------------------------------------------------------
extern "C" void kernel_launch(void* const* d_in, const int* in_sizes, int n_in,
                              void* d_out, int out_size, void* d_ws, size_t ws_size,
                              hipStream_t stream) {
  const float* x = (const float*)d_in[0];
  const float* Wq = (const float*)d_in[1];
  const float* Wk = (const float*)d_in[2];
  const float* Wv = (const float*)d_in[3];
  const float* cq = (const float*)d_in[4];
  const float* ck = (const float*)d_in[5];
  const float* cv = (const float*)d_in[6];
  const float* Wb = (const float*)d_in[7];
  const float* firs = (const float*)d_in[8];
  const float* firl = (const float*)d_in[9];
  const float* Wg = (const float*)d_in[10];
  const float* bg = (const float*)d_in[11];
  const float* Wl = (const float*)d_in[12];
  const float* bl = (const float*)d_in[13];
  const float* ltemp = (const float*)d_in[14];
  const float* rmsw = (const float*)d_in[15];
  const float* Wo = (const float*)d_in[16];

  float* ws = (float*)d_ws;
  const size_t NE = (size_t)Bn * Ln * 1024;  // 8.39M floats
  float* qraw = ws;
  float* kraw = ws + NE;
  float* vraw = ws + 2 * NE;
  float* qn = ws + 3 * NE;
  float* kn = ws + 4 * NE;
  float* vn = ws + 5 * NE;
  float* beta = ws + 6 * NE;
  float* wgl = beta + (size_t)Bn * Hn * Ln;
  float* pmix = wgl + (size_t)Bn * Ln * Hn;
  float* attn_unused = pmix + (size_t)Bn * Ln * Hn * 3;
  unsigned short* Wot = (unsigned short*)(attn_unused + (size_t)Bn * Hn * NCHn * 1024);
  unsigned short* xb = (unsigned short*)qn;
  unsigned short* Wqt = (unsigned short*)(qn + 4194304);
  unsigned short* Wkt = Wqt + 1048576;
  unsigned short* Wvt = Wkt + 1048576;
  unsigned short* normed_bf = (unsigned short*)kn;  // kn dead after precomp
  unsigned short* wfrag = (unsigned short*)qraw;
  unsigned short* qfrag = wfrag + 8388608;
  unsigned short* ktfrag = (unsigned short*)kraw;
  unsigned short* afrag = ktfrag + 8388608;
  float* u0frag = qn;   // exact per-chunk slot overlay of qn
  float* dbuf = vraw;

  const dim3 wtg(32, 32);
  wt_kernel<<<wtg, 256, 0, stream>>>(Wq, Wqt, 1024, 1024);
  wt_kernel<<<wtg, 256, 0, stream>>>(Wk, Wkt, 1024, 1024);
  wt_kernel<<<wtg, 256, 0, stream>>>(Wv, Wvt, 1024, 1024);
  wt_kernel<<<wtg, 256, 0, stream>>>(Wo, Wot, 1024, 1024);
  f2bf_kernel<<<(int)(NE / 1024), 256, 0, stream>>>(x, xb, (int)NE);

  const dim3 gg(8, 64);  // N/128, M/128
  gemm_bf16<<<gg, 256, 0, stream>>>(xb, Wqt, qraw, Bn * Ln, 1024, 1024);
  gemm_bf16<<<gg, 256, 0, stream>>>(xb, Wkt, kraw, Bn * Ln, 1024, 1024);
  gemm_bf16<<<gg, 256, 0, stream>>>(xb, Wvt, vraw, Bn * Ln, 1024, 1024);
  gates_kernel<<<Bn * Ln / 4, 256, 0, stream>>>(x, Wb, Wg, bg, Wl, bl, ltemp,
                                                beta, wgl, pmix);
  conv_act_kernel<1><<<Bn * Ln, 256, 0, stream>>>(qraw, cq, qn);
  conv_act_kernel<1><<<Bn * Ln, 256, 0, stream>>>(kraw, ck, kn);
  conv_act_kernel<0><<<Bn * Ln, 256, 0, stream>>>(vraw, cv, vn);
  precomp_kernel<<<Bn * Hn * NCHn, 256, 0, stream>>>(qn, kn, vn, beta, wfrag,
                                                     qfrag, ktfrag, afrag, u0frag);
  scan_mfma<<<128, 128, 0, stream>>>(wfrag, qfrag, ktfrag, afrag, u0frag, dbuf);
  mix_kernel<<<Bn * Hn * (Ln / MIX_LT), 256, 0, stream>>>(
      vn, dbuf, wgl, pmix, firs, firl, rmsw, normed_bf);
  gemm_bf16<<<gg, 256, 0, stream>>>(normed_bf, Wot, (float*)d_out, Bn * Ln, 1024, 1024);
}